// Round 1
// baseline (4444.285 us; speedup 1.0000x reference)
//
#include <hip/hip_runtime.h>
#include <math.h>

#define NPTS 1024
#define KNBR 20
#define CH 64

// ws layout (bytes):
// [0, 5242880)          : knn  int32 [65536][20]
// [5242880, 22020096)   : fq   float [65536][64]
// [22020096, 22024192)  : wprep float[1024]
//    wp[0..255]   W1r[64][4]   (W1 rel-part folded with W_h)
//    wp[256..511] W1c[64][4]   (W1 center-part)
//    wp[512..639] Wvr[32][4]
//    wp[640..767] Wvc[32][4]
//    wp[768..895] Wkr[32][4]
//    wp[896..1023] Wkc[32][4]

__global__ __launch_bounds__(256) void k_prep(
    const float* __restrict__ Wh, const float* __restrict__ W1,
    const float* __restrict__ Wv, const float* __restrict__ Wk,
    float* __restrict__ wp) {
  int t = threadIdx.x;
  {
    int o = t >> 2, c = t & 3;
    float acc = W1[o * 40 + c];
    #pragma unroll
    for (int v = 0; v < 32; ++v) acc = fmaf(W1[o * 40 + 8 + v], Wh[v * 4 + c], acc);
    wp[t] = acc;
    wp[256 + t] = W1[o * 40 + 4 + c];
  }
  if (t < 128) {
    int d = t >> 2, c = t & 3;
    float av = Wv[d * 40 + c];
    float ak = Wk[d * 40 + c];
    #pragma unroll
    for (int u = 0; u < 32; ++u) {
      av = fmaf(Wv[d * 40 + 8 + u], Wh[u * 4 + c], av);
      ak = fmaf(Wk[d * 40 + 8 + u], Wh[u * 4 + c], ak);
    }
    wp[512 + t] = av;
    wp[640 + t] = Wv[d * 40 + 4 + c];
    wp[768 + t] = ak;
    wp[896 + t] = Wk[d * 40 + 4 + c];
  }
}

__global__ __launch_bounds__(256) void k_copy(const float4* __restrict__ src,
                                              float4* __restrict__ dst) {
  int i = blockIdx.x * 256 + threadIdx.x;
  dst[i] = src[i];
}

// ---------------- KNN: thread-per-point, top-20 by sorted insertion ----------
__global__ __launch_bounds__(256) void k_knn(const float4* __restrict__ xv,
                                             int* __restrict__ knn) {
  __shared__ float4 sx[NPTS];
  __shared__ float ssq[NPTS];
  int b = blockIdx.x >> 2, chunk = blockIdx.x & 3;
  for (int j = threadIdx.x; j < NPTS; j += 256) {
    float4 p = xv[b * NPTS + j];
    sx[j] = p;
    ssq[j] = p.x * p.x + p.y * p.y + p.z * p.z + p.w * p.w;
  }
  __syncthreads();
  int n = chunk * 256 + threadIdx.x;
  float4 c = sx[n];
  float sqn = ssq[n];
  unsigned kd[KNBR];
  int ki[KNBR];
  #pragma unroll
  for (int s = 0; s < KNBR; ++s) { kd[s] = 0xFFFFFFFFu; ki[s] = 0; }
  for (int j = 0; j < NPTS; ++j) {
    float4 q = sx[j];
    float dot = c.x * q.x + c.y * q.y + c.z * q.z + c.w * q.w;
    float d = fmaf(-2.f, dot, sqn + ssq[j]);
    unsigned u = __float_as_uint(d);
    u = ((int)u < 0) ? ~u : (u | 0x80000000u);
    // strict < keeps insertion stable => ties resolved to lower index (matches top_k)
    if (u < kd[KNBR - 1]) {
      unsigned ck = u;
      int ci = j;
      #pragma unroll
      for (int s = 0; s < KNBR; ++s) {
        unsigned tk = kd[s];
        int ti = ki[s];
        bool lt = ck < tk;
        kd[s] = lt ? ck : tk;
        ki[s] = lt ? ci : ti;
        ck = lt ? tk : ck;
        ci = lt ? ti : ci;
      }
    }
  }
  int gid = b * NPTS + n;
  #pragma unroll
  for (int s = 0; s < KNBR; ++s) knn[gid * KNBR + s] = ki[s];
}

// ---------------- fq: two-layer MLP + maxpool over k -------------------------
// thread = (point, half-of-o2); half is wave-uniform so W2/g/b reads scalarize.
__global__ __launch_bounds__(256) void k_fq(
    const float4* __restrict__ xv, const int* __restrict__ knn,
    const float* __restrict__ wp,
    const float* __restrict__ g1, const float* __restrict__ b1,
    const float* __restrict__ W2,
    const float* __restrict__ g2, const float* __restrict__ b2,
    float* __restrict__ fq) {
  __shared__ float4 sx[NPTS];
  int b = blockIdx.x >> 3, chunk = blockIdx.x & 7;
  for (int j = threadIdx.x; j < NPTS; j += 256) sx[j] = xv[b * NPTS + j];
  __syncthreads();
  int half = __builtin_amdgcn_readfirstlane((int)(threadIdx.x >> 7));  // wave-uniform
  int nloc = chunk * 128 + (threadIdx.x & 127);
  int gid = b * NPTS + nloc;
  float4 ctr = sx[nloc];
  const float* W1r = wp;
  const float* W1c = wp + 256;
  float fmaxv[32];
  #pragma unroll
  for (int i = 0; i < 32; ++i) fmaxv[i] = 0.f;  // post-relu values are >= 0
  #pragma unroll 1
  for (int k = 0; k < KNBR; ++k) {
    int nb = knn[gid * KNBR + k];
    float4 nx = sx[nb];
    float rx = nx.x - ctr.x, ry = nx.y - ctr.y, rz = nx.z - ctr.z, rw = nx.w - ctr.w;
    float h1[CH];
    #pragma unroll
    for (int o = 0; o < CH; ++o) {
      float a = W1r[o * 4 + 0] * rx;
      a = fmaf(W1r[o * 4 + 1], ry, a);
      a = fmaf(W1r[o * 4 + 2], rz, a);
      a = fmaf(W1r[o * 4 + 3], rw, a);
      a = fmaf(W1c[o * 4 + 0], ctr.x, a);
      a = fmaf(W1c[o * 4 + 1], ctr.y, a);
      a = fmaf(W1c[o * 4 + 2], ctr.z, a);
      a = fmaf(W1c[o * 4 + 3], ctr.w, a);
      h1[o] = fmaxf(fmaf(g1[o], a, b1[o]), 0.f);
    }
    #pragma unroll
    for (int r = 0; r < 32; ++r) {
      int o2 = half * 32 + r;  // wave-uniform
      const float* w2row = W2 + o2 * CH;
      float acc = 0.f;
      #pragma unroll
      for (int o = 0; o < CH; ++o) acc = fmaf(w2row[o], h1[o], acc);
      float val = fmaxf(fmaf(g2[o2], acc, b2[o2]), 0.f);
      fmaxv[r] = fmaxf(fmaxv[r], val);
    }
  }
  #pragma unroll
  for (int r = 0; r < 32; ++r) fq[gid * CH + half * 32 + r] = fmaxv[r];
}

// ---------------- attention: block = 8 points, staged phases in LDS ----------
__global__ __launch_bounds__(256) void k_attn(
    const float4* __restrict__ xv, const int* __restrict__ knn,
    const float* __restrict__ fqg, const float* __restrict__ wp,
    const float* __restrict__ Wq, const float* __restrict__ gq,
    const float* __restrict__ bq, const float* __restrict__ gv,
    const float* __restrict__ bv, float* __restrict__ o1) {
  __shared__ __align__(16) float s_w[512];   // Wvr,Wvc,Wkr,Wkc
  __shared__ float4 s_ctr[8];
  __shared__ __align__(16) float s_fq[512];  // [8][64]
  __shared__ float4 s_rel[160];              // [8][20]
  __shared__ float s_qT[2080];               // [8][260]: (d*8+h), 1/sum folded in
  __shared__ float s_e[5280];                // [8][20][33] exp(kk)
  __shared__ float s_v[5280];                // [8][20][33]
  __shared__ float s_a[1280];                // [8][8][20]
  float* s_out = s_e;                        // reuse after a-phase

  int t = threadIdx.x;
  int gbase = blockIdx.x * 8;
  int b = gbase >> 10;
  int n0 = gbase & 1023;

  // ---- P0: stage ctr, fq, weights, rel ----
  if (t < 8) s_ctr[t] = xv[b * NPTS + n0 + t];
  for (int idx = t; idx < 512; idx += 256) {
    int p = idx >> 6, o = idx & 63;
    s_fq[p * 64 + o] = fqg[(gbase + p) * CH + o];
    s_w[idx] = wp[512 + idx];
  }
  {
    int p = t >> 5, kk_ = t & 31;
    if (kk_ < KNBR) {
      int nb = knn[(gbase + p) * KNBR + kk_];
      float4 nx = xv[b * NPTS + nb];
      float4 ct = xv[b * NPTS + n0 + p];
      s_rel[p * KNBR + kk_] =
          make_float4(nx.x - ct.x, nx.y - ct.y, nx.z - ct.z, nx.w - ct.w);
    }
  }
  __syncthreads();

  // ---- q-phase: thread j computes q[p][j] for all 8 p ----
  {
    int j = t;
    float4 row4[16];
    const float4* wqv = (const float4*)(Wq + j * CH);
    #pragma unroll
    for (int o4 = 0; o4 < 16; ++o4) row4[o4] = wqv[o4];
    float gqj = gq[j], bqj = bq[j];
    #pragma unroll 1
    for (int p = 0; p < 8; ++p) {
      const float4* fv = (const float4*)(s_fq + p * 64);
      float acc = 0.f;
      #pragma unroll
      for (int o4 = 0; o4 < 16; ++o4) {
        float4 f = fv[o4];
        float4 w = row4[o4];
        acc = fmaf(w.x, f.x, acc);
        acc = fmaf(w.y, f.y, acc);
        acc = fmaf(w.z, f.z, acc);
        acc = fmaf(w.w, f.w, acc);
      }
      float qv = fmaxf(fmaf(gqj, acc, bqj), 0.f);
      s_qT[p * 260 + (j & 31) * 8 + (j >> 5)] = qv;
    }
  }

  // ---- ev-phase: thread (p,d): e=exp(kk) and v over all k ----
  {
    int d = t & 31, p = t >> 5;
    float4 ct = s_ctr[p];
    float4 wr = *(const float4*)(s_w + 256 + d * 4);  // Wkr
    float4 wc = *(const float4*)(s_w + 384 + d * 4);  // Wkc
    float cb = fmaf(wc.x, ct.x, fmaf(wc.y, ct.y, fmaf(wc.z, ct.z, wc.w * ct.w)));
    #pragma unroll
    for (int k = 0; k < KNBR; ++k) {
      float4 r = s_rel[p * KNBR + k];
      float kkv = fmaf(wr.x, r.x, fmaf(wr.y, r.y, fmaf(wr.z, r.z, fmaf(wr.w, r.w, cb))));
      s_e[p * 660 + k * 33 + d] = __expf(kkv);
    }
    float4 vr_ = *(const float4*)(s_w + 0 + d * 4);    // Wvr
    float4 vc_ = *(const float4*)(s_w + 128 + d * 4);  // Wvc
    float cbv = fmaf(vc_.x, ct.x, fmaf(vc_.y, ct.y, fmaf(vc_.z, ct.z, vc_.w * ct.w)));
    float gvd = gv[d], bvd = bv[d];
    #pragma unroll
    for (int k = 0; k < KNBR; ++k) {
      float4 r = s_rel[p * KNBR + k];
      float vv = fmaf(vr_.x, r.x, fmaf(vr_.y, r.y, fmaf(vr_.z, r.z, fmaf(vr_.w, r.w, cbv))));
      s_v[p * 660 + k * 33 + d] = fmaf(gvd, vv, bvd);
    }
  }
  __syncthreads();

  // ---- scale-phase: fold softmax denominator into q ----
  {
    int d = t & 31, p = t >> 5;
    float s = 0.f;
    #pragma unroll
    for (int k = 0; k < KNBR; ++k) s += s_e[p * 660 + k * 33 + d];
    float rs = 1.0f / s;
    #pragma unroll
    for (int h = 0; h < 8; ++h) s_qT[p * 260 + d * 8 + h] *= rs;
  }
  __syncthreads();

  // ---- a-phase: a[p][h][k] = sum_d q'[p][h][d] * e[p][k][d] ----
  {
    int p = t >> 5, h = (t >> 2) & 7, kh = t & 3;
    float qr[32];
    #pragma unroll
    for (int d = 0; d < 32; ++d) qr[d] = s_qT[p * 260 + d * 8 + h];
    #pragma unroll
    for (int i = 0; i < 5; ++i) {
      int k = kh * 5 + i;
      float acc = 0.f;
      #pragma unroll
      for (int d = 0; d < 32; ++d) acc = fmaf(qr[d], s_e[p * 660 + k * 33 + d], acc);
      s_a[(p * 8 + h) * KNBR + k] = acc;
    }
  }
  __syncthreads();

  // ---- out-phase: out[p][h][v] = sum_k a[p][h][k] * v[p][k][v] ----
  {
    int p = t >> 5, v = t & 31;
    float vr[KNBR];
    #pragma unroll
    for (int k = 0; k < KNBR; ++k) vr[k] = s_v[p * 660 + k * 33 + v];
    #pragma unroll
    for (int h = 0; h < 8; ++h) {
      float acc = 0.f;
      #pragma unroll
      for (int k = 0; k < KNBR; ++k) acc = fmaf(s_a[(p * 8 + h) * KNBR + k], vr[k], acc);
      s_out[(h * 32 + v) * 8 + p] = acc;
    }
  }
  __syncthreads();

  // ---- epilogue: coalesced-ish store ----
  for (int idx = t; idx < 2048; idx += 256) {
    int hv = idx >> 3, pp = idx & 7;
    o1[b * 262144 + hv * 1024 + n0 + pp] = s_out[idx];
  }
}

extern "C" void kernel_launch(void* const* d_in, const int* in_sizes, int n_in,
                              void* d_out, int out_size, void* d_ws, size_t ws_size,
                              hipStream_t stream) {
  const float* x = (const float*)d_in[0];
  const float* Wh = (const float*)d_in[1];
  const float* W1 = (const float*)d_in[2];
  const float* g1 = (const float*)d_in[3];
  const float* b1 = (const float*)d_in[4];
  const float* W2 = (const float*)d_in[5];
  const float* g2 = (const float*)d_in[6];
  const float* b2 = (const float*)d_in[7];
  const float* Wv = (const float*)d_in[8];
  const float* gv = (const float*)d_in[9];
  const float* bv = (const float*)d_in[10];
  const float* Wk = (const float*)d_in[11];
  const float* Wq = (const float*)d_in[12];
  const float* gq = (const float*)d_in[13];
  const float* bq = (const float*)d_in[14];
  float* out = (float*)d_out;

  int* knn = (int*)d_ws;
  float* fq = (float*)((char*)d_ws + 5242880);
  float* wp = (float*)((char*)d_ws + 22020096);

  hipLaunchKernelGGL(k_prep, dim3(1), dim3(256), 0, stream, Wh, W1, Wv, Wk, wp);
  hipLaunchKernelGGL(k_copy, dim3(256), dim3(256), 0, stream, (const float4*)x,
                     (float4*)out);
  hipLaunchKernelGGL(k_knn, dim3(256), dim3(256), 0, stream, (const float4*)x, knn);
  hipLaunchKernelGGL(k_fq, dim3(512), dim3(256), 0, stream, (const float4*)x, knn, wp,
                     g1, b1, W2, g2, b2, fq);
  hipLaunchKernelGGL(k_attn, dim3(8192), dim3(256), 0, stream, (const float4*)x, knn,
                     fq, wp, Wq, gq, bq, gv, bv, out + 262144);
}

// Round 2
// 633.736 us; speedup vs baseline: 7.0128x; 7.0128x over previous
//
#include <hip/hip_runtime.h>
#include <math.h>

#define NPTS 1024
#define KNBR 20
#define CH 64

// ws layout (bytes):
// [0, 5242880)          : knn  int32 [65536][20]
// [5242880, 22020096)   : fq   float [65536][64]
// [22020096, 22024192)  : wp   float[1024]
//    wp[0..255]   W1rg[64][4]  (W1 rel-part folded with W_h, times g1)
//    wp[256..511] W1cg[64][4]  (W1 center-part, times g1)
//    wp[512..639] Wvr[32][4]
//    wp[640..767] Wvc[32][4]
//    wp[768..895] Wkr[32][4]
//    wp[896..1023] Wkc[32][4]
// [22024192, 22032384)  : W2 bf16 [64][64] (row-major, ushort)

typedef __attribute__((ext_vector_type(8))) short s16x8;
typedef __attribute__((ext_vector_type(4))) float f32x4;

static __device__ __forceinline__ ushort f2bf(float f) {
  uint u = __float_as_uint(f);
  uint r = (u + 0x7FFFu + ((u >> 16) & 1u)) >> 16;
  return (ushort)r;
}

__global__ __launch_bounds__(256) void k_prep(
    const float* __restrict__ Wh, const float* __restrict__ W1,
    const float* __restrict__ g1, const float* __restrict__ Wv,
    const float* __restrict__ Wk, const float* __restrict__ W2,
    float* __restrict__ wp, ushort* __restrict__ w2b) {
  int t = threadIdx.x;
  {
    int o = t >> 2, c = t & 3;
    float acc = W1[o * 40 + c];
    #pragma unroll
    for (int v = 0; v < 32; ++v) acc = fmaf(W1[o * 40 + 8 + v], Wh[v * 4 + c], acc);
    float g = g1[o];
    wp[t] = g * acc;
    wp[256 + t] = g * W1[o * 40 + 4 + c];
  }
  if (t < 128) {
    int d = t >> 2, c = t & 3;
    float av = Wv[d * 40 + c];
    float ak = Wk[d * 40 + c];
    #pragma unroll
    for (int u = 0; u < 32; ++u) {
      av = fmaf(Wv[d * 40 + 8 + u], Wh[u * 4 + c], av);
      ak = fmaf(Wk[d * 40 + 8 + u], Wh[u * 4 + c], ak);
    }
    wp[512 + t] = av;
    wp[640 + t] = Wv[d * 40 + 4 + c];
    wp[768 + t] = ak;
    wp[896 + t] = Wk[d * 40 + 4 + c];
  }
  #pragma unroll
  for (int i = 0; i < 16; ++i) w2b[t * 16 + i] = f2bf(W2[t * 16 + i]);
}

__global__ __launch_bounds__(256) void k_copy(const float4* __restrict__ src,
                                              float4* __restrict__ dst) {
  int i = blockIdx.x * 256 + threadIdx.x;
  dst[i] = src[i];
}

// ---------------- KNN: thread-per-point, top-20 by sorted insertion ----------
__global__ __launch_bounds__(256) void k_knn(const float4* __restrict__ xv,
                                             int* __restrict__ knn) {
  __shared__ float4 sx[NPTS];
  __shared__ float ssq[NPTS];
  int b = blockIdx.x >> 2, chunk = blockIdx.x & 3;
  for (int j = threadIdx.x; j < NPTS; j += 256) {
    float4 p = xv[b * NPTS + j];
    sx[j] = p;
    ssq[j] = p.x * p.x + p.y * p.y + p.z * p.z + p.w * p.w;
  }
  __syncthreads();
  int n = chunk * 256 + threadIdx.x;
  float4 c = sx[n];
  float sqn = ssq[n];
  unsigned kd[KNBR];
  int ki[KNBR];
  #pragma unroll
  for (int s = 0; s < KNBR; ++s) { kd[s] = 0xFFFFFFFFu; ki[s] = 0; }
  for (int j = 0; j < NPTS; ++j) {
    float4 q = sx[j];
    float dot = c.x * q.x + c.y * q.y + c.z * q.z + c.w * q.w;
    float d = fmaf(-2.f, dot, sqn + ssq[j]);
    unsigned u = __float_as_uint(d);
    u = ((int)u < 0) ? ~u : (u | 0x80000000u);
    if (u < kd[KNBR - 1]) {
      unsigned ck = u;
      int ci = j;
      #pragma unroll
      for (int s = 0; s < KNBR; ++s) {
        unsigned tk = kd[s];
        int ti = ki[s];
        bool lt = ck < tk;
        kd[s] = lt ? ck : tk;
        ki[s] = lt ? ci : ti;
        ck = lt ? tk : ck;
        ci = lt ? ti : ci;
      }
    }
  }
  int gid = b * NPTS + n;
  #pragma unroll
  for (int s = 0; s < KNBR; ++s) knn[gid * KNBR + s] = ki[s];
}

// ---------------- fq: MFMA version ------------------------------------------
// block = 16 points, 320 cols (col = k*16 + p), 4 waves.
// h1 bf16 tile in LDS [col][64ch], XOR-swizzled; W2 as MFMA A from global bf16.
// wave w owns all 64 output rows for k-tiles w*5..w*5+4; maxpool in regs;
// cross-wave max via padded LDS.
__global__ __launch_bounds__(256) void k_fq(
    const float4* __restrict__ xv, const int* __restrict__ knn,
    const float* __restrict__ wp, const float* __restrict__ b1,
    const ushort* __restrict__ w2b, const float* __restrict__ g2,
    const float* __restrict__ b2, float* __restrict__ fq) {
  __shared__ ushort s_h1[320 * 64];      // 40960 B
  __shared__ float s_w1[576];            // W1rg[256], W1cg[256], b1[64]
  __shared__ float s_base[16 * 65];      // padded stride 65
  __shared__ float s_pmax[4 * 16 * 65];  // per-wave partial max, padded

  int t = threadIdx.x;
  int gid0 = blockIdx.x * 16;
  int bbase = (gid0 >> 10) << 10;  // b * 1024

  // stage weights
  for (int i = t; i < 576; i += 256) s_w1[i] = (i < 512) ? wp[i] : b1[i - 512];
  __syncthreads();

  // per-point center affine term: base[p][o] = b1 + W1cg[o].ctr
  for (int i = t; i < 1024; i += 256) {
    int p = i >> 6, o = i & 63;
    float4 ct = xv[gid0 + p];
    float v = s_w1[512 + o];
    v = fmaf(s_w1[256 + o * 4 + 0], ct.x, v);
    v = fmaf(s_w1[256 + o * 4 + 1], ct.y, v);
    v = fmaf(s_w1[256 + o * 4 + 2], ct.z, v);
    v = fmaf(s_w1[256 + o * 4 + 3], ct.w, v);
    s_base[p * 65 + o] = v;
  }
  __syncthreads();

  int w = t >> 6, l = t & 63;

  // h1 phase: wave w computes cols w*80 .. w*80+79
  for (int j = l; j < 80; j += 64) {
    int cc = w * 80 + j;
    int kk = cc >> 4, p = cc & 15;
    int gid = gid0 + p;
    int nb = knn[gid * KNBR + kk];
    float4 nx = xv[bbase + nb];
    float4 ct = xv[gid];
    float rx = nx.x - ct.x, ry = nx.y - ct.y, rz = nx.z - ct.z, rw = nx.w - ct.w;
    int rowbyte = cc * 128;
    int swz = (cc & 7) << 4;
    #pragma unroll
    for (int o8 = 0; o8 < 8; ++o8) {
      uint pk[4];
      #pragma unroll
      for (int jj = 0; jj < 4; ++jj) {
        int o = o8 * 8 + jj * 2;
        float a0 = fmaf(s_w1[o * 4 + 0], rx, s_base[p * 65 + o]);
        a0 = fmaf(s_w1[o * 4 + 1], ry, a0);
        a0 = fmaf(s_w1[o * 4 + 2], rz, a0);
        a0 = fmaf(s_w1[o * 4 + 3], rw, a0);
        float a1 = fmaf(s_w1[o * 4 + 4], rx, s_base[p * 65 + o + 1]);
        a1 = fmaf(s_w1[o * 4 + 5], ry, a1);
        a1 = fmaf(s_w1[o * 4 + 6], rz, a1);
        a1 = fmaf(s_w1[o * 4 + 7], rw, a1);
        a0 = fmaxf(a0, 0.f);
        a1 = fmaxf(a1, 0.f);
        pk[jj] = (uint)f2bf(a0) | ((uint)f2bf(a1) << 16);
      }
      uint4 val;
      val.x = pk[0]; val.y = pk[1]; val.z = pk[2]; val.w = pk[3];
      *(uint4*)((char*)s_h1 + ((rowbyte + o8 * 16) ^ swz)) = val;
    }
  }
  __syncthreads();

  // MFMA phase
  {
    int g = l >> 4;      // 0..3
    int lane16 = l & 15;
    // A frags: W2[row][ch], row = m*16 + lane16, ch = s*32 + g*8 + j
    s16x8 af[4][2];
    #pragma unroll
    for (int m = 0; m < 4; ++m) {
      int row = m * 16 + lane16;
      af[m][0] = *(const s16x8*)(w2b + row * 64 + 0 * 32 + g * 8);
      af[m][1] = *(const s16x8*)(w2b + row * 64 + 1 * 32 + g * 8);
    }
    float g2r[4][4], b2r[4][4];
    #pragma unroll
    for (int m = 0; m < 4; ++m)
      #pragma unroll
      for (int r = 0; r < 4; ++r) {
        int row = m * 16 + g * 4 + r;
        g2r[m][r] = g2[row];
        b2r[m][r] = b2[row];
      }
    float mx[4][4];
    #pragma unroll
    for (int m = 0; m < 4; ++m)
      #pragma unroll
      for (int r = 0; r < 4; ++r) mx[m][r] = 0.f;  // post-relu >= 0

    #pragma unroll
    for (int i = 0; i < 5; ++i) {
      int kt = w * 5 + i;
      int col = kt * 16 + lane16;
      int rowbyte = col * 128;
      int swz = (col & 7) << 4;
      s16x8 bf0 = *(const s16x8*)((char*)s_h1 + ((rowbyte + g * 16) ^ swz));
      s16x8 bf1 = *(const s16x8*)((char*)s_h1 + ((rowbyte + 64 + g * 16) ^ swz));
      #pragma unroll
      for (int m = 0; m < 4; ++m) {
        f32x4 acc = {0.f, 0.f, 0.f, 0.f};
        acc = __builtin_amdgcn_mfma_f32_16x16x32_bf16(af[m][0], bf0, acc, 0, 0, 0);
        acc = __builtin_amdgcn_mfma_f32_16x16x32_bf16(af[m][1], bf1, acc, 0, 0, 0);
        #pragma unroll
        for (int r = 0; r < 4; ++r) {
          float val = fmaxf(fmaf(g2r[m][r], acc[r], b2r[m][r]), 0.f);
          mx[m][r] = fmaxf(mx[m][r], val);
        }
      }
    }
    // write per-wave partials
    #pragma unroll
    for (int m = 0; m < 4; ++m)
      #pragma unroll
      for (int r = 0; r < 4; ++r) {
        int o2 = m * 16 + g * 4 + r;
        s_pmax[(w * 16 + lane16) * 65 + o2] = mx[m][r];
      }
  }
  __syncthreads();

  // cross-wave max + coalesced store
  for (int idx = t; idx < 1024; idx += 256) {
    int p = idx >> 6, o = idx & 63;
    float v = s_pmax[p * 65 + o];
    v = fmaxf(v, s_pmax[(16 + p) * 65 + o]);
    v = fmaxf(v, s_pmax[(32 + p) * 65 + o]);
    v = fmaxf(v, s_pmax[(48 + p) * 65 + o]);
    fq[(gid0 + p) * 64 + o] = v;
  }
}

// ---------------- attention: block = 8 points, staged phases in LDS ----------
__global__ __launch_bounds__(256) void k_attn(
    const float4* __restrict__ xv, const int* __restrict__ knn,
    const float* __restrict__ fqg, const float* __restrict__ wp,
    const float* __restrict__ Wq, const float* __restrict__ gq,
    const float* __restrict__ bq, const float* __restrict__ gv,
    const float* __restrict__ bv, float* __restrict__ o1) {
  __shared__ __align__(16) float s_w[512];   // Wvr,Wvc,Wkr,Wkc
  __shared__ float4 s_ctr[8];
  __shared__ __align__(16) float s_fq[512];  // [8][64]
  __shared__ float4 s_rel[160];              // [8][20]
  __shared__ float s_qT[2080];               // [8][260]: (d*8+h), 1/sum folded in
  __shared__ float s_e[5280];                // [8][20][33] exp(kk)
  __shared__ float s_v[5280];                // [8][20][33]
  __shared__ float s_a[1280];                // [8][8][20]
  float* s_out = s_e;                        // reuse after a-phase

  int t = threadIdx.x;
  int gbase = blockIdx.x * 8;
  int b = gbase >> 10;
  int n0 = gbase & 1023;

  if (t < 8) s_ctr[t] = xv[b * NPTS + n0 + t];
  for (int idx = t; idx < 512; idx += 256) {
    int p = idx >> 6, o = idx & 63;
    s_fq[p * 64 + o] = fqg[(gbase + p) * CH + o];
    s_w[idx] = wp[512 + idx];
  }
  {
    int p = t >> 5, kk_ = t & 31;
    if (kk_ < KNBR) {
      int nb = knn[(gbase + p) * KNBR + kk_];
      float4 nx = xv[b * NPTS + nb];
      float4 ct = xv[b * NPTS + n0 + p];
      s_rel[p * KNBR + kk_] =
          make_float4(nx.x - ct.x, nx.y - ct.y, nx.z - ct.z, nx.w - ct.w);
    }
  }
  __syncthreads();

  {
    int j = t;
    float4 row4[16];
    const float4* wqv = (const float4*)(Wq + j * CH);
    #pragma unroll
    for (int o4 = 0; o4 < 16; ++o4) row4[o4] = wqv[o4];
    float gqj = gq[j], bqj = bq[j];
    #pragma unroll 1
    for (int p = 0; p < 8; ++p) {
      const float4* fv = (const float4*)(s_fq + p * 64);
      float acc = 0.f;
      #pragma unroll
      for (int o4 = 0; o4 < 16; ++o4) {
        float4 f = fv[o4];
        float4 w = row4[o4];
        acc = fmaf(w.x, f.x, acc);
        acc = fmaf(w.y, f.y, acc);
        acc = fmaf(w.z, f.z, acc);
        acc = fmaf(w.w, f.w, acc);
      }
      float qv = fmaxf(fmaf(gqj, acc, bqj), 0.f);
      s_qT[p * 260 + (j & 31) * 8 + (j >> 5)] = qv;
    }
  }

  {
    int d = t & 31, p = t >> 5;
    float4 ct = s_ctr[p];
    float4 wr = *(const float4*)(s_w + 256 + d * 4);
    float4 wc = *(const float4*)(s_w + 384 + d * 4);
    float cb = fmaf(wc.x, ct.x, fmaf(wc.y, ct.y, fmaf(wc.z, ct.z, wc.w * ct.w)));
    #pragma unroll
    for (int k = 0; k < KNBR; ++k) {
      float4 r = s_rel[p * KNBR + k];
      float kkv = fmaf(wr.x, r.x, fmaf(wr.y, r.y, fmaf(wr.z, r.z, fmaf(wr.w, r.w, cb))));
      s_e[p * 660 + k * 33 + d] = __expf(kkv);
    }
    float4 vr_ = *(const float4*)(s_w + 0 + d * 4);
    float4 vc_ = *(const float4*)(s_w + 128 + d * 4);
    float cbv = fmaf(vc_.x, ct.x, fmaf(vc_.y, ct.y, fmaf(vc_.z, ct.z, vc_.w * ct.w)));
    float gvd = gv[d], bvd = bv[d];
    #pragma unroll
    for (int k = 0; k < KNBR; ++k) {
      float4 r = s_rel[p * KNBR + k];
      float vv = fmaf(vr_.x, r.x, fmaf(vr_.y, r.y, fmaf(vr_.z, r.z, fmaf(vr_.w, r.w, cbv))));
      s_v[p * 660 + k * 33 + d] = fmaf(gvd, vv, bvd);
    }
  }
  __syncthreads();

  {
    int d = t & 31, p = t >> 5;
    float s = 0.f;
    #pragma unroll
    for (int k = 0; k < KNBR; ++k) s += s_e[p * 660 + k * 33 + d];
    float rs = 1.0f / s;
    #pragma unroll
    for (int h = 0; h < 8; ++h) s_qT[p * 260 + d * 8 + h] *= rs;
  }
  __syncthreads();

  {
    int p = t >> 5, h = (t >> 2) & 7, kh = t & 3;
    float qr[32];
    #pragma unroll
    for (int d = 0; d < 32; ++d) qr[d] = s_qT[p * 260 + d * 8 + h];
    #pragma unroll
    for (int i = 0; i < 5; ++i) {
      int k = kh * 5 + i;
      float acc = 0.f;
      #pragma unroll
      for (int d = 0; d < 32; ++d) acc = fmaf(qr[d], s_e[p * 660 + k * 33 + d], acc);
      s_a[(p * 8 + h) * KNBR + k] = acc;
    }
  }
  __syncthreads();

  {
    int p = t >> 5, v = t & 31;
    float vr[KNBR];
    #pragma unroll
    for (int k = 0; k < KNBR; ++k) vr[k] = s_v[p * 660 + k * 33 + v];
    #pragma unroll
    for (int h = 0; h < 8; ++h) {
      float acc = 0.f;
      #pragma unroll
      for (int k = 0; k < KNBR; ++k) acc = fmaf(s_a[(p * 8 + h) * KNBR + k], vr[k], acc);
      s_out[(h * 32 + v) * 8 + p] = acc;
    }
  }
  __syncthreads();

  for (int idx = t; idx < 2048; idx += 256) {
    int hv = idx >> 3, pp = idx & 7;
    o1[b * 262144 + hv * 1024 + n0 + pp] = s_out[idx];
  }
}

extern "C" void kernel_launch(void* const* d_in, const int* in_sizes, int n_in,
                              void* d_out, int out_size, void* d_ws, size_t ws_size,
                              hipStream_t stream) {
  const float* x = (const float*)d_in[0];
  const float* Wh = (const float*)d_in[1];
  const float* W1 = (const float*)d_in[2];
  const float* g1 = (const float*)d_in[3];
  const float* b1 = (const float*)d_in[4];
  const float* W2 = (const float*)d_in[5];
  const float* g2 = (const float*)d_in[6];
  const float* b2 = (const float*)d_in[7];
  const float* Wv = (const float*)d_in[8];
  const float* gv = (const float*)d_in[9];
  const float* bv = (const float*)d_in[10];
  const float* Wk = (const float*)d_in[11];
  const float* Wq = (const float*)d_in[12];
  const float* gq = (const float*)d_in[13];
  const float* bq = (const float*)d_in[14];
  float* out = (float*)d_out;

  int* knn = (int*)d_ws;
  float* fq = (float*)((char*)d_ws + 5242880);
  float* wp = (float*)((char*)d_ws + 22020096);
  ushort* w2b = (ushort*)((char*)d_ws + 22024192);

  hipLaunchKernelGGL(k_prep, dim3(1), dim3(256), 0, stream, Wh, W1, g1, Wv, Wk, W2,
                     wp, w2b);
  hipLaunchKernelGGL(k_copy, dim3(256), dim3(256), 0, stream, (const float4*)x,
                     (float4*)out);
  hipLaunchKernelGGL(k_knn, dim3(256), dim3(256), 0, stream, (const float4*)x, knn);
  hipLaunchKernelGGL(k_fq, dim3(4096), dim3(256), 0, stream, (const float4*)x, knn,
                     wp, b1, w2b, g2, b2, fq);
  hipLaunchKernelGGL(k_attn, dim3(8192), dim3(256), 0, stream, (const float4*)x, knn,
                     fq, wp, Wq, gq, bq, gv, bv, out + 262144);
}

// Round 3
// 505.514 us; speedup vs baseline: 8.7916x; 1.2536x over previous
//
#include <hip/hip_runtime.h>
#include <math.h>

#define NPTS 1024
#define KNBR 20
#define CH 64

// ws layout (bytes):
// [0, 5242880)          : knn  int32 [65536][20]
// [5242880, 22020096)   : fq   float [65536][64]
// [22020096, 22024192)  : wp   float[1024]
//    wp[0..255]   W1rg[64][4]  (W1 rel-part folded with W_h, times g1)
//    wp[256..511] W1cg[64][4]  (W1 center-part, times g1)
//    wp[512..639] Wvr[32][4]
//    wp[640..767] Wvc[32][4]
//    wp[768..895] Wkr[32][4]
//    wp[896..1023] Wkc[32][4]
// [22024192, 22032384)  : W2 bf16 [64][64] (row-major, ushort)

typedef __attribute__((ext_vector_type(8))) short s16x8;
typedef __attribute__((ext_vector_type(4))) float f32x4;

static __device__ __forceinline__ ushort f2bf(float f) {
  uint u = __float_as_uint(f);
  uint r = (u + 0x7FFFu + ((u >> 16) & 1u)) >> 16;
  return (ushort)r;
}

__global__ __launch_bounds__(256) void k_prep(
    const float* __restrict__ Wh, const float* __restrict__ W1,
    const float* __restrict__ g1, const float* __restrict__ Wv,
    const float* __restrict__ Wk, const float* __restrict__ W2,
    float* __restrict__ wp, ushort* __restrict__ w2b) {
  int t = threadIdx.x;
  {
    int o = t >> 2, c = t & 3;
    float acc = W1[o * 40 + c];
    #pragma unroll
    for (int v = 0; v < 32; ++v) acc = fmaf(W1[o * 40 + 8 + v], Wh[v * 4 + c], acc);
    float g = g1[o];
    wp[t] = g * acc;
    wp[256 + t] = g * W1[o * 40 + 4 + c];
  }
  if (t < 128) {
    int d = t >> 2, c = t & 3;
    float av = Wv[d * 40 + c];
    float ak = Wk[d * 40 + c];
    #pragma unroll
    for (int u = 0; u < 32; ++u) {
      av = fmaf(Wv[d * 40 + 8 + u], Wh[u * 4 + c], av);
      ak = fmaf(Wk[d * 40 + 8 + u], Wh[u * 4 + c], ak);
    }
    wp[512 + t] = av;
    wp[640 + t] = Wv[d * 40 + 4 + c];
    wp[768 + t] = ak;
    wp[896 + t] = Wk[d * 40 + 4 + c];
  }
  #pragma unroll
  for (int i = 0; i < 16; ++i) w2b[t * 16 + i] = f2bf(W2[t * 16 + i]);
}

__global__ __launch_bounds__(256) void k_copy(const float4* __restrict__ src,
                                              float4* __restrict__ dst) {
  int i = blockIdx.x * 256 + threadIdx.x;
  dst[i] = src[i];
}

// ---------------- KNN v2: append-buffer + deferred compaction ---------------
// Grid 512: block = (batch b, group of 128 centers); thread = (center, half).
// Hot loop: key + stale-threshold filter + LDS append (~13 insts).
// Shift-insert runs only in synchronized compactions (buffer full) — exact.
__device__ __forceinline__ void insert20(float kd[KNBR], int ki[KNBR], float ck,
                                         int ci) {
  if (ck < kd[KNBR - 1]) {
    #pragma unroll
    for (int s = 0; s < KNBR; ++s) {
      float tk = kd[s];
      int ti = ki[s];
      bool lt = ck < tk;
      kd[s] = lt ? ck : tk;
      ki[s] = lt ? ci : ti;
      ck = lt ? tk : ck;
      ci = lt ? ti : ci;
    }
  }
}

__global__ __launch_bounds__(256) void k_knn(const float4* __restrict__ xv,
                                             int* __restrict__ knn) {
  __shared__ float4 sx[NPTS];        // 16 KB
  __shared__ float ssq[NPTS];        // 4 KB
  __shared__ float s_bk[KNBR][256];  // 20 KB append buffer keys
  __shared__ ushort s_bi[KNBR][256]; // 10 KB append buffer idx

  int t = threadIdx.x;
  int b = blockIdx.x >> 3, grp = blockIdx.x & 7;
  for (int j = t; j < NPTS; j += 256) {
    float4 p = xv[b * NPTS + j];
    sx[j] = p;
    ssq[j] = p.x * p.x + p.y * p.y + p.z * p.z + p.w * p.w;
  }
  __syncthreads();

  int cloc = grp * 128 + (t & 127);
  int half = t >> 7;  // wave-uniform (waves 0,1 = half 0; waves 2,3 = half 1)
  float4 c = sx[cloc];

  float kd[KNBR];
  int ki[KNBR];
  #pragma unroll
  for (int s = 0; s < KNBR; ++s) { kd[s] = __builtin_inff(); ki[s] = 0; }

  int wp = 0;
  int j0 = half * 512;
  for (int j = j0; j < j0 + 512; ++j) {
    float4 q = sx[j];
    float dot = c.x * q.x;
    dot = fmaf(c.y, q.y, dot);
    dot = fmaf(c.z, q.z, dot);
    dot = fmaf(c.w, q.w, dot);
    float key = fmaf(-2.f, dot, ssq[j]);  // dist - |c|^2 (monotone)
    if (key < kd[KNBR - 1]) {
      s_bk[wp][t] = key;
      s_bi[wp][t] = (ushort)j;
      ++wp;
    }
    if (__any(wp >= KNBR)) {
      for (int i = 0;; ++i) {
        if (!__any(i < wp)) break;
        if (i < wp) insert20(kd, ki, s_bk[i][t], (int)s_bi[i][t]);
      }
      wp = 0;
    }
  }
  // final compaction
  for (int i = 0;; ++i) {
    if (!__any(i < wp)) break;
    if (i < wp) insert20(kd, ki, s_bk[i][t], (int)s_bi[i][t]);
  }

  // stage per-half sorted lists into the (now free) buffer
  #pragma unroll
  for (int s = 0; s < KNBR; ++s) {
    s_bk[s][t] = kd[s];
    s_bi[s][t] = (ushort)ki[s];
  }
  __syncthreads();

  // exact stable 2-way merge (half0 indices all < half1 => tie -> half0)
  if (t < 128) {
    int gid = b * NPTS + grp * 128 + t;
    int i0 = 0, i1 = 0;
    #pragma unroll
    for (int s = 0; s < KNBR; ++s) {
      float k0 = s_bk[i0][t];
      float k1 = s_bk[i1][t + 128];
      bool take0 = (k0 <= k1);
      int idx = take0 ? (int)s_bi[i0][t] : (int)s_bi[i1][t + 128];
      knn[gid * KNBR + s] = idx;
      i0 += take0 ? 1 : 0;
      i1 += take0 ? 0 : 1;
    }
  }
}

// ---------------- fq: MFMA version ------------------------------------------
__global__ __launch_bounds__(256) void k_fq(
    const float4* __restrict__ xv, const int* __restrict__ knn,
    const float* __restrict__ wp, const float* __restrict__ b1,
    const ushort* __restrict__ w2b, const float* __restrict__ g2,
    const float* __restrict__ b2, float* __restrict__ fq) {
  __shared__ ushort s_h1[320 * 64];      // 40960 B
  __shared__ float s_w1[576];            // W1rg[256], W1cg[256], b1[64]
  __shared__ float s_base[16 * 65];      // padded stride 65
  __shared__ float s_pmax[4 * 16 * 65];  // per-wave partial max, padded

  int t = threadIdx.x;
  int gid0 = blockIdx.x * 16;
  int bbase = (gid0 >> 10) << 10;  // b * 1024

  for (int i = t; i < 576; i += 256) s_w1[i] = (i < 512) ? wp[i] : b1[i - 512];
  __syncthreads();

  for (int i = t; i < 1024; i += 256) {
    int p = i >> 6, o = i & 63;
    float4 ct = xv[gid0 + p];
    float v = s_w1[512 + o];
    v = fmaf(s_w1[256 + o * 4 + 0], ct.x, v);
    v = fmaf(s_w1[256 + o * 4 + 1], ct.y, v);
    v = fmaf(s_w1[256 + o * 4 + 2], ct.z, v);
    v = fmaf(s_w1[256 + o * 4 + 3], ct.w, v);
    s_base[p * 65 + o] = v;
  }
  __syncthreads();

  int w = t >> 6, l = t & 63;

  for (int j = l; j < 80; j += 64) {
    int cc = w * 80 + j;
    int kk = cc >> 4, p = cc & 15;
    int gid = gid0 + p;
    int nb = knn[gid * KNBR + kk];
    float4 nx = xv[bbase + nb];
    float4 ct = xv[gid];
    float rx = nx.x - ct.x, ry = nx.y - ct.y, rz = nx.z - ct.z, rw = nx.w - ct.w;
    int rowbyte = cc * 128;
    int swz = (cc & 7) << 4;
    #pragma unroll
    for (int o8 = 0; o8 < 8; ++o8) {
      uint pk[4];
      #pragma unroll
      for (int jj = 0; jj < 4; ++jj) {
        int o = o8 * 8 + jj * 2;
        float a0 = fmaf(s_w1[o * 4 + 0], rx, s_base[p * 65 + o]);
        a0 = fmaf(s_w1[o * 4 + 1], ry, a0);
        a0 = fmaf(s_w1[o * 4 + 2], rz, a0);
        a0 = fmaf(s_w1[o * 4 + 3], rw, a0);
        float a1 = fmaf(s_w1[o * 4 + 4], rx, s_base[p * 65 + o + 1]);
        a1 = fmaf(s_w1[o * 4 + 5], ry, a1);
        a1 = fmaf(s_w1[o * 4 + 6], rz, a1);
        a1 = fmaf(s_w1[o * 4 + 7], rw, a1);
        a0 = fmaxf(a0, 0.f);
        a1 = fmaxf(a1, 0.f);
        pk[jj] = (uint)f2bf(a0) | ((uint)f2bf(a1) << 16);
      }
      uint4 val;
      val.x = pk[0]; val.y = pk[1]; val.z = pk[2]; val.w = pk[3];
      *(uint4*)((char*)s_h1 + ((rowbyte + o8 * 16) ^ swz)) = val;
    }
  }
  __syncthreads();

  {
    int g = l >> 4;
    int lane16 = l & 15;
    s16x8 af[4][2];
    #pragma unroll
    for (int m = 0; m < 4; ++m) {
      int row = m * 16 + lane16;
      af[m][0] = *(const s16x8*)(w2b + row * 64 + 0 * 32 + g * 8);
      af[m][1] = *(const s16x8*)(w2b + row * 64 + 1 * 32 + g * 8);
    }
    float g2r[4][4], b2r[4][4];
    #pragma unroll
    for (int m = 0; m < 4; ++m)
      #pragma unroll
      for (int r = 0; r < 4; ++r) {
        int row = m * 16 + g * 4 + r;
        g2r[m][r] = g2[row];
        b2r[m][r] = b2[row];
      }
    float mx[4][4];
    #pragma unroll
    for (int m = 0; m < 4; ++m)
      #pragma unroll
      for (int r = 0; r < 4; ++r) mx[m][r] = 0.f;

    #pragma unroll
    for (int i = 0; i < 5; ++i) {
      int kt = w * 5 + i;
      int col = kt * 16 + lane16;
      int rowbyte = col * 128;
      int swz = (col & 7) << 4;
      s16x8 bf0 = *(const s16x8*)((char*)s_h1 + ((rowbyte + g * 16) ^ swz));
      s16x8 bf1 = *(const s16x8*)((char*)s_h1 + ((rowbyte + 64 + g * 16) ^ swz));
      #pragma unroll
      for (int m = 0; m < 4; ++m) {
        f32x4 acc = {0.f, 0.f, 0.f, 0.f};
        acc = __builtin_amdgcn_mfma_f32_16x16x32_bf16(af[m][0], bf0, acc, 0, 0, 0);
        acc = __builtin_amdgcn_mfma_f32_16x16x32_bf16(af[m][1], bf1, acc, 0, 0, 0);
        #pragma unroll
        for (int r = 0; r < 4; ++r) {
          float val = fmaxf(fmaf(g2r[m][r], acc[r], b2r[m][r]), 0.f);
          mx[m][r] = fmaxf(mx[m][r], val);
        }
      }
    }
    #pragma unroll
    for (int m = 0; m < 4; ++m)
      #pragma unroll
      for (int r = 0; r < 4; ++r) {
        int o2 = m * 16 + g * 4 + r;
        s_pmax[(w * 16 + lane16) * 65 + o2] = mx[m][r];
      }
  }
  __syncthreads();

  for (int idx = t; idx < 1024; idx += 256) {
    int p = idx >> 6, o = idx & 63;
    float v = s_pmax[p * 65 + o];
    v = fmaxf(v, s_pmax[(16 + p) * 65 + o]);
    v = fmaxf(v, s_pmax[(32 + p) * 65 + o]);
    v = fmaxf(v, s_pmax[(48 + p) * 65 + o]);
    fq[(gid0 + p) * 64 + o] = v;
  }
}

// ---------------- attention: block = 8 points, staged phases in LDS ----------
__global__ __launch_bounds__(256) void k_attn(
    const float4* __restrict__ xv, const int* __restrict__ knn,
    const float* __restrict__ fqg, const float* __restrict__ wp,
    const float* __restrict__ Wq, const float* __restrict__ gq,
    const float* __restrict__ bq, const float* __restrict__ gv,
    const float* __restrict__ bv, float* __restrict__ o1) {
  __shared__ __align__(16) float s_w[512];
  __shared__ float4 s_ctr[8];
  __shared__ __align__(16) float s_fq[512];
  __shared__ float4 s_rel[160];
  __shared__ float s_qT[2080];
  __shared__ float s_e[5280];
  __shared__ float s_v[5280];
  __shared__ float s_a[1280];
  float* s_out = s_e;

  int t = threadIdx.x;
  int gbase = blockIdx.x * 8;
  int b = gbase >> 10;
  int n0 = gbase & 1023;

  if (t < 8) s_ctr[t] = xv[b * NPTS + n0 + t];
  for (int idx = t; idx < 512; idx += 256) {
    int p = idx >> 6, o = idx & 63;
    s_fq[p * 64 + o] = fqg[(gbase + p) * CH + o];
    s_w[idx] = wp[512 + idx];
  }
  {
    int p = t >> 5, kk_ = t & 31;
    if (kk_ < KNBR) {
      int nb = knn[(gbase + p) * KNBR + kk_];
      float4 nx = xv[b * NPTS + nb];
      float4 ct = xv[b * NPTS + n0 + p];
      s_rel[p * KNBR + kk_] =
          make_float4(nx.x - ct.x, nx.y - ct.y, nx.z - ct.z, nx.w - ct.w);
    }
  }
  __syncthreads();

  {
    int j = t;
    float4 row4[16];
    const float4* wqv = (const float4*)(Wq + j * CH);
    #pragma unroll
    for (int o4 = 0; o4 < 16; ++o4) row4[o4] = wqv[o4];
    float gqj = gq[j], bqj = bq[j];
    #pragma unroll 1
    for (int p = 0; p < 8; ++p) {
      const float4* fv = (const float4*)(s_fq + p * 64);
      float acc = 0.f;
      #pragma unroll
      for (int o4 = 0; o4 < 16; ++o4) {
        float4 f = fv[o4];
        float4 w = row4[o4];
        acc = fmaf(w.x, f.x, acc);
        acc = fmaf(w.y, f.y, acc);
        acc = fmaf(w.z, f.z, acc);
        acc = fmaf(w.w, f.w, acc);
      }
      float qv = fmaxf(fmaf(gqj, acc, bqj), 0.f);
      s_qT[p * 260 + (j & 31) * 8 + (j >> 5)] = qv;
    }
  }

  {
    int d = t & 31, p = t >> 5;
    float4 ct = s_ctr[p];
    float4 wr = *(const float4*)(s_w + 256 + d * 4);
    float4 wc = *(const float4*)(s_w + 384 + d * 4);
    float cb = fmaf(wc.x, ct.x, fmaf(wc.y, ct.y, fmaf(wc.z, ct.z, wc.w * ct.w)));
    #pragma unroll
    for (int k = 0; k < KNBR; ++k) {
      float4 r = s_rel[p * KNBR + k];
      float kkv = fmaf(wr.x, r.x, fmaf(wr.y, r.y, fmaf(wr.z, r.z, fmaf(wr.w, r.w, cb))));
      s_e[p * 660 + k * 33 + d] = __expf(kkv);
    }
    float4 vr_ = *(const float4*)(s_w + 0 + d * 4);
    float4 vc_ = *(const float4*)(s_w + 128 + d * 4);
    float cbv = fmaf(vc_.x, ct.x, fmaf(vc_.y, ct.y, fmaf(vc_.z, ct.z, vc_.w * ct.w)));
    float gvd = gv[d], bvd = bv[d];
    #pragma unroll
    for (int k = 0; k < KNBR; ++k) {
      float4 r = s_rel[p * KNBR + k];
      float vv = fmaf(vr_.x, r.x, fmaf(vr_.y, r.y, fmaf(vr_.z, r.z, fmaf(vr_.w, r.w, cbv))));
      s_v[p * 660 + k * 33 + d] = fmaf(gvd, vv, bvd);
    }
  }
  __syncthreads();

  {
    int d = t & 31, p = t >> 5;
    float s = 0.f;
    #pragma unroll
    for (int k = 0; k < KNBR; ++k) s += s_e[p * 660 + k * 33 + d];
    float rs = 1.0f / s;
    #pragma unroll
    for (int h = 0; h < 8; ++h) s_qT[p * 260 + d * 8 + h] *= rs;
  }
  __syncthreads();

  {
    int p = t >> 5, h = (t >> 2) & 7, kh = t & 3;
    float qr[32];
    #pragma unroll
    for (int d = 0; d < 32; ++d) qr[d] = s_qT[p * 260 + d * 8 + h];
    #pragma unroll
    for (int i = 0; i < 5; ++i) {
      int k = kh * 5 + i;
      float acc = 0.f;
      #pragma unroll
      for (int d = 0; d < 32; ++d) acc = fmaf(qr[d], s_e[p * 660 + k * 33 + d], acc);
      s_a[(p * 8 + h) * KNBR + k] = acc;
    }
  }
  __syncthreads();

  {
    int p = t >> 5, v = t & 31;
    float vr[KNBR];
    #pragma unroll
    for (int k = 0; k < KNBR; ++k) vr[k] = s_v[p * 660 + k * 33 + v];
    #pragma unroll
    for (int h = 0; h < 8; ++h) {
      float acc = 0.f;
      #pragma unroll
      for (int k = 0; k < KNBR; ++k) acc = fmaf(s_a[(p * 8 + h) * KNBR + k], vr[k], acc);
      s_out[(h * 32 + v) * 8 + p] = acc;
    }
  }
  __syncthreads();

  for (int idx = t; idx < 2048; idx += 256) {
    int hv = idx >> 3, pp = idx & 7;
    o1[b * 262144 + hv * 1024 + n0 + pp] = s_out[idx];
  }
}

extern "C" void kernel_launch(void* const* d_in, const int* in_sizes, int n_in,
                              void* d_out, int out_size, void* d_ws, size_t ws_size,
                              hipStream_t stream) {
  const float* x = (const float*)d_in[0];
  const float* Wh = (const float*)d_in[1];
  const float* W1 = (const float*)d_in[2];
  const float* g1 = (const float*)d_in[3];
  const float* b1 = (const float*)d_in[4];
  const float* W2 = (const float*)d_in[5];
  const float* g2 = (const float*)d_in[6];
  const float* b2 = (const float*)d_in[7];
  const float* Wv = (const float*)d_in[8];
  const float* gv = (const float*)d_in[9];
  const float* bv = (const float*)d_in[10];
  const float* Wk = (const float*)d_in[11];
  const float* Wq = (const float*)d_in[12];
  const float* gq = (const float*)d_in[13];
  const float* bq = (const float*)d_in[14];
  float* out = (float*)d_out;

  int* knn = (int*)d_ws;
  float* fq = (float*)((char*)d_ws + 5242880);
  float* wp = (float*)((char*)d_ws + 22020096);
  ushort* w2b = (ushort*)((char*)d_ws + 22024192);

  hipLaunchKernelGGL(k_prep, dim3(1), dim3(256), 0, stream, Wh, W1, g1, Wv, Wk, W2,
                     wp, w2b);
  hipLaunchKernelGGL(k_copy, dim3(256), dim3(256), 0, stream, (const float4*)x,
                     (float4*)out);
  hipLaunchKernelGGL(k_knn, dim3(512), dim3(256), 0, stream, (const float4*)x, knn);
  hipLaunchKernelGGL(k_fq, dim3(4096), dim3(256), 0, stream, (const float4*)x, knn,
                     wp, b1, w2b, g2, b2, fq);
  hipLaunchKernelGGL(k_attn, dim3(8192), dim3(256), 0, stream, (const float4*)x, knn,
                     fq, wp, Wq, gq, bq, gv, bv, out + 262144);
}

// Round 4
// 427.954 us; speedup vs baseline: 10.3850x; 1.1812x over previous
//
#include <hip/hip_runtime.h>
#include <math.h>

#define NPTS 1024
#define KNBR 20
#define CH 64

// ws layout (bytes), proven budget: ws_size >= 22,032,384 (used in R1/R2)
// [0, 2621440)          : knn  ushort [65536][20]
// [2621440, 19398656)   : fq   float [65536][64]
// [19398656, 19402752)  : wp   float[1024]
//    wp[0..255]   W1rg[64][4], wp[256..511] W1cg[64][4]
//    wp[512..639] Wvr, wp[640..767] Wvc, wp[768..895] Wkr, wp[896..1023] Wkc
// [19402752, 19410944)  : W2 bf16 [64][64]
// [19410944, 19443712)  : Wq bf16 [256][64]

typedef __attribute__((ext_vector_type(8))) short s16x8;
typedef __attribute__((ext_vector_type(4))) float f32x4;

static __device__ __forceinline__ ushort f2bf(float f) {
  uint u = __float_as_uint(f);
  uint r = (u + 0x7FFFu + ((u >> 16) & 1u)) >> 16;
  return (ushort)r;
}

__global__ __launch_bounds__(256) void k_prep(
    const float* __restrict__ Wh, const float* __restrict__ W1,
    const float* __restrict__ g1, const float* __restrict__ Wv,
    const float* __restrict__ Wk, const float* __restrict__ W2,
    const float* __restrict__ Wq, float* __restrict__ wp,
    ushort* __restrict__ w2b, ushort* __restrict__ wqb) {
  int t = threadIdx.x;
  {
    int o = t >> 2, c = t & 3;
    float acc = W1[o * 40 + c];
    #pragma unroll
    for (int v = 0; v < 32; ++v) acc = fmaf(W1[o * 40 + 8 + v], Wh[v * 4 + c], acc);
    float g = g1[o];
    wp[t] = g * acc;
    wp[256 + t] = g * W1[o * 40 + 4 + c];
  }
  if (t < 128) {
    int d = t >> 2, c = t & 3;
    float av = Wv[d * 40 + c];
    float ak = Wk[d * 40 + c];
    #pragma unroll
    for (int u = 0; u < 32; ++u) {
      av = fmaf(Wv[d * 40 + 8 + u], Wh[u * 4 + c], av);
      ak = fmaf(Wk[d * 40 + 8 + u], Wh[u * 4 + c], ak);
    }
    wp[512 + t] = av;
    wp[640 + t] = Wv[d * 40 + 4 + c];
    wp[768 + t] = ak;
    wp[896 + t] = Wk[d * 40 + 4 + c];
  }
  #pragma unroll
  for (int i = 0; i < 16; ++i) w2b[t * 16 + i] = f2bf(W2[t * 16 + i]);
  for (int i = 0; i < 64; ++i) wqb[t * 64 + i] = f2bf(Wq[t * 64 + i]);
}

__global__ __launch_bounds__(256) void k_copy(const float4* __restrict__ src,
                                              float4* __restrict__ dst) {
  int i = blockIdx.x * 256 + threadIdx.x;
  dst[i] = src[i];
}

// ---------------- KNN: append-buffer + deferred compaction ------------------
__device__ __forceinline__ void insert20(float kd[KNBR], int ki[KNBR], float ck,
                                         int ci) {
  if (ck < kd[KNBR - 1]) {
    #pragma unroll
    for (int s = 0; s < KNBR; ++s) {
      float tk = kd[s];
      int ti = ki[s];
      bool lt = ck < tk;
      kd[s] = lt ? ck : tk;
      ki[s] = lt ? ci : ti;
      ck = lt ? tk : ck;
      ci = lt ? ti : ci;
    }
  }
}

__global__ __launch_bounds__(256) void k_knn(const float4* __restrict__ xv,
                                             ushort* __restrict__ knn) {
  __shared__ float4 sx[NPTS];
  __shared__ float ssq[NPTS];
  __shared__ float s_bk[KNBR][256];
  __shared__ ushort s_bi[KNBR][256];

  int t = threadIdx.x;
  int b = blockIdx.x >> 3, grp = blockIdx.x & 7;
  for (int j = t; j < NPTS; j += 256) {
    float4 p = xv[b * NPTS + j];
    sx[j] = p;
    ssq[j] = p.x * p.x + p.y * p.y + p.z * p.z + p.w * p.w;
  }
  __syncthreads();

  int cloc = grp * 128 + (t & 127);
  int half = t >> 7;
  float4 c = sx[cloc];

  float kd[KNBR];
  int ki[KNBR];
  #pragma unroll
  for (int s = 0; s < KNBR; ++s) { kd[s] = __builtin_inff(); ki[s] = 0; }

  int wp = 0;
  int j0 = half * 512;
  for (int j = j0; j < j0 + 512; ++j) {
    float4 q = sx[j];
    float dot = c.x * q.x;
    dot = fmaf(c.y, q.y, dot);
    dot = fmaf(c.z, q.z, dot);
    dot = fmaf(c.w, q.w, dot);
    float key = fmaf(-2.f, dot, ssq[j]);
    if (key < kd[KNBR - 1]) {
      s_bk[wp][t] = key;
      s_bi[wp][t] = (ushort)j;
      ++wp;
    }
    if (__any(wp >= KNBR)) {
      for (int i = 0;; ++i) {
        if (!__any(i < wp)) break;
        if (i < wp) insert20(kd, ki, s_bk[i][t], (int)s_bi[i][t]);
      }
      wp = 0;
    }
  }
  for (int i = 0;; ++i) {
    if (!__any(i < wp)) break;
    if (i < wp) insert20(kd, ki, s_bk[i][t], (int)s_bi[i][t]);
  }

  #pragma unroll
  for (int s = 0; s < KNBR; ++s) {
    s_bk[s][t] = kd[s];
    s_bi[s][t] = (ushort)ki[s];
  }
  __syncthreads();

  if (t < 128) {
    int gid = b * NPTS + grp * 128 + t;
    int i0 = 0, i1 = 0;
    #pragma unroll
    for (int s = 0; s < KNBR; ++s) {
      float k0 = s_bk[i0][t];
      float k1 = s_bk[i1][t + 128];
      bool take0 = (k0 <= k1);
      int idx = take0 ? (int)s_bi[i0][t] : (int)s_bi[i1][t + 128];
      knn[gid * KNBR + s] = (ushort)idx;
      i0 += take0 ? 1 : 0;
      i1 += take0 ? 0 : 1;
    }
  }
}

// ---------------- fq: MFMA version ------------------------------------------
__global__ __launch_bounds__(256) void k_fq(
    const float4* __restrict__ xv, const ushort* __restrict__ knn,
    const float* __restrict__ wp, const float* __restrict__ b1,
    const ushort* __restrict__ w2b, const float* __restrict__ g2,
    const float* __restrict__ b2, float* __restrict__ fq) {
  __shared__ ushort s_h1[320 * 64];
  __shared__ float s_w1[576];
  __shared__ float s_base[16 * 65];
  __shared__ float s_pmax[4 * 16 * 65];

  int t = threadIdx.x;
  int gid0 = blockIdx.x * 16;
  int bbase = (gid0 >> 10) << 10;

  for (int i = t; i < 576; i += 256) s_w1[i] = (i < 512) ? wp[i] : b1[i - 512];
  __syncthreads();

  for (int i = t; i < 1024; i += 256) {
    int p = i >> 6, o = i & 63;
    float4 ct = xv[gid0 + p];
    float v = s_w1[512 + o];
    v = fmaf(s_w1[256 + o * 4 + 0], ct.x, v);
    v = fmaf(s_w1[256 + o * 4 + 1], ct.y, v);
    v = fmaf(s_w1[256 + o * 4 + 2], ct.z, v);
    v = fmaf(s_w1[256 + o * 4 + 3], ct.w, v);
    s_base[p * 65 + o] = v;
  }
  __syncthreads();

  int w = t >> 6, l = t & 63;

  for (int j = l; j < 80; j += 64) {
    int cc = w * 80 + j;
    int kk = cc >> 4, p = cc & 15;
    int gid = gid0 + p;
    int nb = knn[gid * KNBR + kk];
    float4 nx = xv[bbase + nb];
    float4 ct = xv[gid];
    float rx = nx.x - ct.x, ry = nx.y - ct.y, rz = nx.z - ct.z, rw = nx.w - ct.w;
    int rowbyte = cc * 128;
    int swz = (cc & 7) << 4;
    #pragma unroll
    for (int o8 = 0; o8 < 8; ++o8) {
      uint pk[4];
      #pragma unroll
      for (int jj = 0; jj < 4; ++jj) {
        int o = o8 * 8 + jj * 2;
        float a0 = fmaf(s_w1[o * 4 + 0], rx, s_base[p * 65 + o]);
        a0 = fmaf(s_w1[o * 4 + 1], ry, a0);
        a0 = fmaf(s_w1[o * 4 + 2], rz, a0);
        a0 = fmaf(s_w1[o * 4 + 3], rw, a0);
        float a1 = fmaf(s_w1[o * 4 + 4], rx, s_base[p * 65 + o + 1]);
        a1 = fmaf(s_w1[o * 4 + 5], ry, a1);
        a1 = fmaf(s_w1[o * 4 + 6], rz, a1);
        a1 = fmaf(s_w1[o * 4 + 7], rw, a1);
        a0 = fmaxf(a0, 0.f);
        a1 = fmaxf(a1, 0.f);
        pk[jj] = (uint)f2bf(a0) | ((uint)f2bf(a1) << 16);
      }
      uint4 val;
      val.x = pk[0]; val.y = pk[1]; val.z = pk[2]; val.w = pk[3];
      *(uint4*)((char*)s_h1 + ((rowbyte + o8 * 16) ^ swz)) = val;
    }
  }
  __syncthreads();

  {
    int g = l >> 4;
    int lane16 = l & 15;
    s16x8 af[4][2];
    #pragma unroll
    for (int m = 0; m < 4; ++m) {
      int row = m * 16 + lane16;
      af[m][0] = *(const s16x8*)(w2b + row * 64 + 0 * 32 + g * 8);
      af[m][1] = *(const s16x8*)(w2b + row * 64 + 1 * 32 + g * 8);
    }
    float g2r[4][4], b2r[4][4];
    #pragma unroll
    for (int m = 0; m < 4; ++m)
      #pragma unroll
      for (int r = 0; r < 4; ++r) {
        int row = m * 16 + g * 4 + r;
        g2r[m][r] = g2[row];
        b2r[m][r] = b2[row];
      }
    float mx[4][4];
    #pragma unroll
    for (int m = 0; m < 4; ++m)
      #pragma unroll
      for (int r = 0; r < 4; ++r) mx[m][r] = 0.f;

    #pragma unroll
    for (int i = 0; i < 5; ++i) {
      int kt = w * 5 + i;
      int col = kt * 16 + lane16;
      int rowbyte = col * 128;
      int swz = (col & 7) << 4;
      s16x8 bf0 = *(const s16x8*)((char*)s_h1 + ((rowbyte + g * 16) ^ swz));
      s16x8 bf1 = *(const s16x8*)((char*)s_h1 + ((rowbyte + 64 + g * 16) ^ swz));
      #pragma unroll
      for (int m = 0; m < 4; ++m) {
        f32x4 acc = {0.f, 0.f, 0.f, 0.f};
        acc = __builtin_amdgcn_mfma_f32_16x16x32_bf16(af[m][0], bf0, acc, 0, 0, 0);
        acc = __builtin_amdgcn_mfma_f32_16x16x32_bf16(af[m][1], bf1, acc, 0, 0, 0);
        #pragma unroll
        for (int r = 0; r < 4; ++r) {
          float val = fmaxf(fmaf(g2r[m][r], acc[r], b2r[m][r]), 0.f);
          mx[m][r] = fmaxf(mx[m][r], val);
        }
      }
    }
    #pragma unroll
    for (int m = 0; m < 4; ++m)
      #pragma unroll
      for (int r = 0; r < 4; ++r) {
        int o2 = m * 16 + g * 4 + r;
        s_pmax[(w * 16 + lane16) * 65 + o2] = mx[m][r];
      }
  }
  __syncthreads();

  for (int idx = t; idx < 1024; idx += 256) {
    int p = idx >> 6, o = idx & 63;
    float v = s_pmax[p * 65 + o];
    v = fmaxf(v, s_pmax[(16 + p) * 65 + o]);
    v = fmaxf(v, s_pmax[(32 + p) * 65 + o]);
    v = fmaxf(v, s_pmax[(48 + p) * 65 + o]);
    fq[(gid0 + p) * 64 + o] = v;
  }
}

// ---------------- attention: q via MFMA, padded-stride LDS ------------------
__global__ __launch_bounds__(256) void k_attn(
    const float4* __restrict__ xv, const ushort* __restrict__ knn,
    const float* __restrict__ fqg, const float* __restrict__ wp,
    const ushort* __restrict__ wqb, const float* __restrict__ gq,
    const float* __restrict__ bq, const float* __restrict__ gv,
    const float* __restrict__ bv, float* __restrict__ o1) {
  __shared__ __align__(16) float s_w[512];    // Wvr,Wvc,Wkr,Wkc
  __shared__ float4 s_ctr[8];
  __shared__ __align__(16) float s_fq[8 * 68];  // padded stride 68
  __shared__ float s_gq[256];
  __shared__ float s_bq[256];
  __shared__ float4 s_rel[160];
  __shared__ float s_q[8 * 264];  // [p][h*33+d]
  __shared__ float s_e[8 * 660];  // [p][k*33+d]
  __shared__ float s_v[8 * 660];
  __shared__ float s_a[8 * 160];  // [p][h*20+k]
  float* s_out = s_e;             // alias, used after a-phase

  int t = threadIdx.x;
  int gbase = blockIdx.x * 8;
  int b = gbase >> 10;
  int n0 = gbase & 1023;

  // ---- stage ----
  if (t < 8) s_ctr[t] = xv[b * NPTS + n0 + t];
  for (int idx = t; idx < 512; idx += 256) {
    int p = idx >> 6, o = idx & 63;
    s_fq[p * 68 + o] = fqg[(gbase + p) * CH + o];
    s_w[idx] = wp[512 + idx];
  }
  s_gq[t] = gq[t];
  s_bq[t] = bq[t];
  {
    int p = t >> 5, kk_ = t & 31;
    if (kk_ < KNBR) {
      int nb = knn[(gbase + p) * KNBR + kk_];
      float4 nx = xv[b * NPTS + nb];
      float4 ct = xv[b * NPTS + n0 + p];
      s_rel[p * KNBR + kk_] =
          make_float4(nx.x - ct.x, nx.y - ct.y, nx.z - ct.z, nx.w - ct.w);
    }
  }
  int w = t >> 6, l = t & 63;
  int lane16 = l & 15, g = l >> 4;
  // Wq A-frags from global (L2/L3-cached), pre-barrier
  s16x8 af[4][2];
  #pragma unroll
  for (int mm = 0; mm < 4; ++mm) {
    int row = w * 64 + mm * 16 + lane16;
    af[mm][0] = *(const s16x8*)(wqb + row * 64 + g * 8);
    af[mm][1] = *(const s16x8*)(wqb + row * 64 + 32 + g * 8);
  }
  __syncthreads();

  // ---- q-MFMA: q[p][row] = relu(gq*acc+bq), row = h*32+d ----
  {
    int p8 = l & 7;
    s16x8 bf[2];
    #pragma unroll
    for (int ks = 0; ks < 2; ++ks) {
      const float4* fp = (const float4*)(s_fq + p8 * 68 + ks * 32 + g * 8);
      float4 f0 = fp[0], f1 = fp[1];
      union { uint4 u; s16x8 s; } cv;
      cv.u.x = (uint)f2bf(f0.x) | ((uint)f2bf(f0.y) << 16);
      cv.u.y = (uint)f2bf(f0.z) | ((uint)f2bf(f0.w) << 16);
      cv.u.z = (uint)f2bf(f1.x) | ((uint)f2bf(f1.y) << 16);
      cv.u.w = (uint)f2bf(f1.z) | ((uint)f2bf(f1.w) << 16);
      bf[ks] = cv.s;
    }
    bool active = (lane16 < 8);
    #pragma unroll
    for (int mm = 0; mm < 4; ++mm) {
      f32x4 acc = {0.f, 0.f, 0.f, 0.f};
      acc = __builtin_amdgcn_mfma_f32_16x16x32_bf16(af[mm][0], bf[0], acc, 0, 0, 0);
      acc = __builtin_amdgcn_mfma_f32_16x16x32_bf16(af[mm][1], bf[1], acc, 0, 0, 0);
      if (active) {
        #pragma unroll
        for (int r = 0; r < 4; ++r) {
          int row = w * 64 + mm * 16 + g * 4 + r;
          float val = fmaxf(fmaf(s_gq[row], acc[r], s_bq[row]), 0.f);
          s_q[lane16 * 264 + (row >> 5) * 33 + (row & 31)] = val;
        }
      }
    }
  }

  // ---- ev-phase: thread (p,d) ----
  {
    int d = t & 31, p = t >> 5;
    float4 ct = s_ctr[p];
    float4 wr = *(const float4*)(s_w + 256 + d * 4);
    float4 wc = *(const float4*)(s_w + 384 + d * 4);
    float cb = fmaf(wc.x, ct.x, fmaf(wc.y, ct.y, fmaf(wc.z, ct.z, wc.w * ct.w)));
    #pragma unroll
    for (int k = 0; k < KNBR; ++k) {
      float4 r = s_rel[p * KNBR + k];
      float kkv = fmaf(wr.x, r.x, fmaf(wr.y, r.y, fmaf(wr.z, r.z, fmaf(wr.w, r.w, cb))));
      s_e[p * 660 + k * 33 + d] = __expf(kkv);
    }
    float4 vr_ = *(const float4*)(s_w + 0 + d * 4);
    float4 vc_ = *(const float4*)(s_w + 128 + d * 4);
    float cbv = fmaf(vc_.x, ct.x, fmaf(vc_.y, ct.y, fmaf(vc_.z, ct.z, vc_.w * ct.w)));
    float gvd = gv[d], bvd = bv[d];
    #pragma unroll
    for (int k = 0; k < KNBR; ++k) {
      float4 r = s_rel[p * KNBR + k];
      float vv = fmaf(vr_.x, r.x, fmaf(vr_.y, r.y, fmaf(vr_.z, r.z, fmaf(vr_.w, r.w, cbv))));
      s_v[p * 660 + k * 33 + d] = fmaf(gvd, vv, bvd);
    }
  }
  __syncthreads();

  // ---- scale-phase: fold softmax denom into e ----
  {
    int d = t & 31, p = t >> 5;
    float s = 0.f;
    #pragma unroll
    for (int k = 0; k < KNBR; ++k) s += s_e[p * 660 + k * 33 + d];
    float rs = 1.0f / s;
    #pragma unroll
    for (int k = 0; k < KNBR; ++k) s_e[p * 660 + k * 33 + d] *= rs;
  }
  __syncthreads();

  // ---- a-phase: a[p][h][k] = sum_d q[p][h][d] * e'[p][k][d] ----
  {
    int p = t >> 5, h = (t >> 2) & 7, kh = t & 3;
    float qr[32];
    #pragma unroll
    for (int d = 0; d < 32; ++d) qr[d] = s_q[p * 264 + h * 33 + d];
    #pragma unroll
    for (int i = 0; i < 5; ++i) {
      int k = kh * 5 + i;
      float acc = 0.f;
      #pragma unroll
      for (int d = 0; d < 32; ++d) acc = fmaf(qr[d], s_e[p * 660 + k * 33 + d], acc);
      s_a[p * 160 + h * 20 + k] = acc;
    }
  }
  __syncthreads();

  // ---- out-phase: out[p][h][v] = sum_k a * v; padded stride 9 ----
  {
    int p = t >> 5, v = t & 31;
    float vr[KNBR];
    #pragma unroll
    for (int k = 0; k < KNBR; ++k) vr[k] = s_v[p * 660 + k * 33 + v];
    #pragma unroll
    for (int h = 0; h < 8; ++h) {
      float acc = 0.f;
      #pragma unroll
      for (int k = 0; k < KNBR; ++k)
        acc = fmaf(s_a[p * 160 + h * 20 + k], vr[k], acc);
      s_out[(h * 32 + v) * 9 + p] = acc;
    }
  }
  __syncthreads();

  for (int idx = t; idx < 2048; idx += 256) {
    int hv = idx >> 3, pp = idx & 7;
    o1[b * 262144 + hv * 1024 + n0 + pp] = s_out[hv * 9 + pp];
  }
}

extern "C" void kernel_launch(void* const* d_in, const int* in_sizes, int n_in,
                              void* d_out, int out_size, void* d_ws, size_t ws_size,
                              hipStream_t stream) {
  const float* x = (const float*)d_in[0];
  const float* Wh = (const float*)d_in[1];
  const float* W1 = (const float*)d_in[2];
  const float* g1 = (const float*)d_in[3];
  const float* b1 = (const float*)d_in[4];
  const float* W2 = (const float*)d_in[5];
  const float* g2 = (const float*)d_in[6];
  const float* b2 = (const float*)d_in[7];
  const float* Wv = (const float*)d_in[8];
  const float* gv = (const float*)d_in[9];
  const float* bv = (const float*)d_in[10];
  const float* Wk = (const float*)d_in[11];
  const float* Wq = (const float*)d_in[12];
  const float* gq = (const float*)d_in[13];
  const float* bq = (const float*)d_in[14];
  float* out = (float*)d_out;

  ushort* knn = (ushort*)d_ws;
  float* fq = (float*)((char*)d_ws + 2621440);
  float* wp = (float*)((char*)d_ws + 19398656);
  ushort* w2b = (ushort*)((char*)d_ws + 19402752);
  ushort* wqb = (ushort*)((char*)d_ws + 19410944);

  hipLaunchKernelGGL(k_prep, dim3(1), dim3(256), 0, stream, Wh, W1, g1, Wv, Wk, W2,
                     Wq, wp, w2b, wqb);
  hipLaunchKernelGGL(k_copy, dim3(256), dim3(256), 0, stream, (const float4*)x,
                     (float4*)out);
  hipLaunchKernelGGL(k_knn, dim3(512), dim3(256), 0, stream, (const float4*)x, knn);
  hipLaunchKernelGGL(k_fq, dim3(4096), dim3(256), 0, stream, (const float4*)x, knn,
                     wp, b1, w2b, g2, b2, fq);
  hipLaunchKernelGGL(k_attn, dim3(8192), dim3(256), 0, stream, (const float4*)x, knn,
                     fq, wp, wqb, gq, bq, gv, bv, out + 262144);
}

// Round 5
// 427.799 us; speedup vs baseline: 10.3887x; 1.0004x over previous
//
#include <hip/hip_runtime.h>
#include <math.h>

#define NPTS 1024
#define KNBR 20
#define CH 64

// ws layout (bytes), proven budget: ws_size >= 22,032,384 (used in R1/R2)
// [0, 2621440)          : knn  ushort [65536][20]
// [2621440, 19398656)   : fq   float [65536][64]
// [19398656, 19402752)  : wp   float[1024]
// [19402752, 19410944)  : W2 bf16 [64][64]
// [19410944, 19443712)  : Wq bf16 [256][64]

typedef __attribute__((ext_vector_type(8))) short s16x8;
typedef __attribute__((ext_vector_type(4))) float f32x4;

static __device__ __forceinline__ ushort f2bf(float f) {
  uint u = __float_as_uint(f);
  uint r = (u + 0x7FFFu + ((u >> 16) & 1u)) >> 16;
  return (ushort)r;
}

__global__ __launch_bounds__(256) void k_prep(
    const float* __restrict__ Wh, const float* __restrict__ W1,
    const float* __restrict__ g1, const float* __restrict__ Wv,
    const float* __restrict__ Wk, const float* __restrict__ W2,
    const float* __restrict__ Wq, float* __restrict__ wp,
    ushort* __restrict__ w2b, ushort* __restrict__ wqb) {
  int t = threadIdx.x;
  {
    int o = t >> 2, c = t & 3;
    float acc = W1[o * 40 + c];
    #pragma unroll
    for (int v = 0; v < 32; ++v) acc = fmaf(W1[o * 40 + 8 + v], Wh[v * 4 + c], acc);
    float g = g1[o];
    wp[t] = g * acc;
    wp[256 + t] = g * W1[o * 40 + 4 + c];
  }
  if (t < 128) {
    int d = t >> 2, c = t & 3;
    float av = Wv[d * 40 + c];
    float ak = Wk[d * 40 + c];
    #pragma unroll
    for (int u = 0; u < 32; ++u) {
      av = fmaf(Wv[d * 40 + 8 + u], Wh[u * 4 + c], av);
      ak = fmaf(Wk[d * 40 + 8 + u], Wh[u * 4 + c], ak);
    }
    wp[512 + t] = av;
    wp[640 + t] = Wv[d * 40 + 4 + c];
    wp[768 + t] = ak;
    wp[896 + t] = Wk[d * 40 + 4 + c];
  }
  #pragma unroll
  for (int i = 0; i < 16; ++i) w2b[t * 16 + i] = f2bf(W2[t * 16 + i]);
  for (int i = 0; i < 64; ++i) wqb[t * 64 + i] = f2bf(Wq[t * 64 + i]);
}

// ---------------- KNN v3: 4-way split + append buffer + exact merge ---------
__device__ __forceinline__ void insert20(float kd[KNBR], int ki[KNBR], float ck,
                                         int ci) {
  if (ck < kd[KNBR - 1]) {
    #pragma unroll
    for (int s = 0; s < KNBR; ++s) {
      float tk = kd[s];
      int ti = ki[s];
      bool lt = ck < tk;
      kd[s] = lt ? ck : tk;
      ki[s] = lt ? ci : ti;
      ck = lt ? tk : ck;
      ci = lt ? ti : ci;
    }
  }
}

// block = 64 centers x 4 quarter-scans; grid = 64*16 = 1024 blocks.
// smem phases: [scan: sx|ssq|buf12] then [merge: mk20|mi20] (aliased).
__global__ __launch_bounds__(256) void k_knn(const float4* __restrict__ xv,
                                             ushort* __restrict__ knn,
                                             float4* __restrict__ outx) {
  __shared__ __align__(16) char smem[38912];
  float4* sx = (float4*)smem;                   // [1024] 16384 B
  float* ssq = (float*)(smem + 16384);          // [1024]  4096 B
  float* bk = (float*)(smem + 20480);           // [12][256] 12288 B
  ushort* bi = (ushort*)(smem + 32768);         // [12][256]  6144 B
  float* mk = (float*)smem;                     // [20][256] 20480 B (phase 2)
  ushort* mi = (ushort*)(smem + 20480);         // [20][256] 10240 B (phase 2)

  int t = threadIdx.x;
  int b = blockIdx.x >> 4, grp = blockIdx.x & 15;
  for (int j = t; j < NPTS; j += 256) {
    float4 p = xv[b * NPTS + j];
    sx[j] = p;
    ssq[j] = p.x * p.x + p.y * p.y + p.z * p.z + p.w * p.w;
    if (grp == 0) outx[b * NPTS + j] = p;  // folded k_copy (out0 = x)
  }
  __syncthreads();

  int cc = t & 63;
  int quarter = t >> 6;  // = wave id, wave-uniform
  int cloc = grp * 64 + cc;
  float4 c = sx[cloc];

  float kd[KNBR];
  int ki[KNBR];
  #pragma unroll
  for (int s = 0; s < KNBR; ++s) { kd[s] = __builtin_inff(); ki[s] = 0; }

  int wp = 0;
  int j0 = quarter * 256;
  #pragma unroll 1
  for (int jj = 0; jj < 128; ++jj) {
    int j = j0 + jj * 2;
    #pragma unroll
    for (int u = 0; u < 2; ++u) {
      float4 q = sx[j + u];
      float dot = c.x * q.x;
      dot = fmaf(c.y, q.y, dot);
      dot = fmaf(c.z, q.z, dot);
      dot = fmaf(c.w, q.w, dot);
      float key = fmaf(-2.f, dot, ssq[j + u]);  // dist - |c|^2 (monotone)
      if (key < kd[KNBR - 1]) {
        bk[wp * 256 + t] = key;
        bi[wp * 256 + t] = (ushort)(j + u);
        ++wp;
      }
    }
    if (__any(wp >= 11)) {
      for (int i = 0;; ++i) {
        if (!__any(i < wp)) break;
        if (i < wp) insert20(kd, ki, bk[i * 256 + t], (int)bi[i * 256 + t]);
      }
      wp = 0;
    }
  }
  for (int i = 0;; ++i) {
    if (!__any(i < wp)) break;
    if (i < wp) insert20(kd, ki, bk[i * 256 + t], (int)bi[i * 256 + t]);
  }
  __syncthreads();  // everyone done with sx/ssq/buf before aliasing

  #pragma unroll
  for (int s = 0; s < KNBR; ++s) {
    mk[s * 256 + t] = kd[s];
    mi[s * 256 + t] = (ushort)ki[s];
  }
  __syncthreads();

  // exact 4-way merge; quarter q's indices all in [256q, 256q+256) -> tie
  // breaks to lower q = lower index (strict < cascade prefers earlier q).
  if (t < 64) {
    int gid = b * NPTS + grp * 64 + t;
    int ip[4] = {0, 0, 0, 0};
    float hk[4];
    int hi_[4];
    #pragma unroll
    for (int q = 0; q < 4; ++q) {
      hk[q] = mk[0 * 256 + t + 64 * q];
      hi_[q] = (int)mi[0 * 256 + t + 64 * q];
    }
    #pragma unroll 1
    for (int s = 0; s < KNBR; ++s) {
      // cascade min, strict < so earlier quarter wins ties
      float k01 = hk[0]; int i01 = hi_[0]; int q01 = 0;
      if (hk[1] < k01) { k01 = hk[1]; i01 = hi_[1]; q01 = 1; }
      float k23 = hk[2]; int i23 = hi_[2]; int q23 = 2;
      if (hk[3] < k23) { k23 = hk[3]; i23 = hi_[3]; q23 = 3; }
      float ks = k01; int is = i01; int qs = q01;
      if (k23 < ks) { ks = k23; is = i23; qs = q23; }
      knn[gid * KNBR + s] = (ushort)is;
      // advance selected quarter; branchless per-q update
      #pragma unroll
      for (int q = 0; q < 4; ++q) {
        bool adv = (qs == q);
        ip[q] += adv ? 1 : 0;
        int row = ip[q] < KNBR ? ip[q] : (KNBR - 1);
        float nk = mk[row * 256 + t + 64 * q];
        int ni = (int)mi[row * 256 + t + 64 * q];
        if (adv) {
          hk[q] = (ip[q] < KNBR) ? nk : __builtin_inff();
          hi_[q] = ni;
        }
      }
    }
  }
}

// ---------------- fq: MFMA version ------------------------------------------
__global__ __launch_bounds__(256) void k_fq(
    const float4* __restrict__ xv, const ushort* __restrict__ knn,
    const float* __restrict__ wp, const float* __restrict__ b1,
    const ushort* __restrict__ w2b, const float* __restrict__ g2,
    const float* __restrict__ b2, float* __restrict__ fq) {
  __shared__ ushort s_h1[320 * 64];
  __shared__ float s_w1[576];
  __shared__ float s_base[16 * 65];
  __shared__ float s_pmax[4 * 16 * 65];

  int t = threadIdx.x;
  int gid0 = blockIdx.x * 16;
  int bbase = (gid0 >> 10) << 10;

  for (int i = t; i < 576; i += 256) s_w1[i] = (i < 512) ? wp[i] : b1[i - 512];
  __syncthreads();

  for (int i = t; i < 1024; i += 256) {
    int p = i >> 6, o = i & 63;
    float4 ct = xv[gid0 + p];
    float v = s_w1[512 + o];
    v = fmaf(s_w1[256 + o * 4 + 0], ct.x, v);
    v = fmaf(s_w1[256 + o * 4 + 1], ct.y, v);
    v = fmaf(s_w1[256 + o * 4 + 2], ct.z, v);
    v = fmaf(s_w1[256 + o * 4 + 3], ct.w, v);
    s_base[p * 65 + o] = v;
  }
  __syncthreads();

  int w = t >> 6, l = t & 63;

  for (int j = l; j < 80; j += 64) {
    int cc = w * 80 + j;
    int kk = cc >> 4, p = cc & 15;
    int gid = gid0 + p;
    int nb = knn[gid * KNBR + kk];
    float4 nx = xv[bbase + nb];
    float4 ct = xv[gid];
    float rx = nx.x - ct.x, ry = nx.y - ct.y, rz = nx.z - ct.z, rw = nx.w - ct.w;
    int rowbyte = cc * 128;
    int swz = (cc & 7) << 4;
    #pragma unroll
    for (int o8 = 0; o8 < 8; ++o8) {
      uint pk[4];
      #pragma unroll
      for (int jj = 0; jj < 4; ++jj) {
        int o = o8 * 8 + jj * 2;
        float a0 = fmaf(s_w1[o * 4 + 0], rx, s_base[p * 65 + o]);
        a0 = fmaf(s_w1[o * 4 + 1], ry, a0);
        a0 = fmaf(s_w1[o * 4 + 2], rz, a0);
        a0 = fmaf(s_w1[o * 4 + 3], rw, a0);
        float a1 = fmaf(s_w1[o * 4 + 4], rx, s_base[p * 65 + o + 1]);
        a1 = fmaf(s_w1[o * 4 + 5], ry, a1);
        a1 = fmaf(s_w1[o * 4 + 6], rz, a1);
        a1 = fmaf(s_w1[o * 4 + 7], rw, a1);
        a0 = fmaxf(a0, 0.f);
        a1 = fmaxf(a1, 0.f);
        pk[jj] = (uint)f2bf(a0) | ((uint)f2bf(a1) << 16);
      }
      uint4 val;
      val.x = pk[0]; val.y = pk[1]; val.z = pk[2]; val.w = pk[3];
      *(uint4*)((char*)s_h1 + ((rowbyte + o8 * 16) ^ swz)) = val;
    }
  }
  __syncthreads();

  {
    int g = l >> 4;
    int lane16 = l & 15;
    s16x8 af[4][2];
    #pragma unroll
    for (int m = 0; m < 4; ++m) {
      int row = m * 16 + lane16;
      af[m][0] = *(const s16x8*)(w2b + row * 64 + 0 * 32 + g * 8);
      af[m][1] = *(const s16x8*)(w2b + row * 64 + 1 * 32 + g * 8);
    }
    float g2r[4][4], b2r[4][4];
    #pragma unroll
    for (int m = 0; m < 4; ++m)
      #pragma unroll
      for (int r = 0; r < 4; ++r) {
        int row = m * 16 + g * 4 + r;
        g2r[m][r] = g2[row];
        b2r[m][r] = b2[row];
      }
    float mx[4][4];
    #pragma unroll
    for (int m = 0; m < 4; ++m)
      #pragma unroll
      for (int r = 0; r < 4; ++r) mx[m][r] = 0.f;

    #pragma unroll
    for (int i = 0; i < 5; ++i) {
      int kt = w * 5 + i;
      int col = kt * 16 + lane16;
      int rowbyte = col * 128;
      int swz = (col & 7) << 4;
      s16x8 bf0 = *(const s16x8*)((char*)s_h1 + ((rowbyte + g * 16) ^ swz));
      s16x8 bf1 = *(const s16x8*)((char*)s_h1 + ((rowbyte + 64 + g * 16) ^ swz));
      #pragma unroll
      for (int m = 0; m < 4; ++m) {
        f32x4 acc = {0.f, 0.f, 0.f, 0.f};
        acc = __builtin_amdgcn_mfma_f32_16x16x32_bf16(af[m][0], bf0, acc, 0, 0, 0);
        acc = __builtin_amdgcn_mfma_f32_16x16x32_bf16(af[m][1], bf1, acc, 0, 0, 0);
        #pragma unroll
        for (int r = 0; r < 4; ++r) {
          float val = fmaxf(fmaf(g2r[m][r], acc[r], b2r[m][r]), 0.f);
          mx[m][r] = fmaxf(mx[m][r], val);
        }
      }
    }
    #pragma unroll
    for (int m = 0; m < 4; ++m)
      #pragma unroll
      for (int r = 0; r < 4; ++r) {
        int o2 = m * 16 + g * 4 + r;
        s_pmax[(w * 16 + lane16) * 65 + o2] = mx[m][r];
      }
  }
  __syncthreads();

  for (int idx = t; idx < 1024; idx += 256) {
    int p = idx >> 6, o = idx & 63;
    float v = s_pmax[p * 65 + o];
    v = fmaxf(v, s_pmax[(16 + p) * 65 + o]);
    v = fmaxf(v, s_pmax[(32 + p) * 65 + o]);
    v = fmaxf(v, s_pmax[(48 + p) * 65 + o]);
    fq[(gid0 + p) * 64 + o] = v;
  }
}

// ---------------- attention: q via MFMA, padded-stride LDS ------------------
__global__ __launch_bounds__(256) void k_attn(
    const float4* __restrict__ xv, const ushort* __restrict__ knn,
    const float* __restrict__ fqg, const float* __restrict__ wp,
    const ushort* __restrict__ wqb, const float* __restrict__ gq,
    const float* __restrict__ bq, const float* __restrict__ gv,
    const float* __restrict__ bv, float* __restrict__ o1) {
  __shared__ __align__(16) float s_w[512];
  __shared__ float4 s_ctr[8];
  __shared__ __align__(16) float s_fq[8 * 68];
  __shared__ float s_gq[256];
  __shared__ float s_bq[256];
  __shared__ float4 s_rel[160];
  __shared__ float s_q[8 * 264];
  __shared__ float s_e[8 * 660];
  __shared__ float s_v[8 * 660];
  __shared__ float s_a[8 * 160];
  float* s_out = s_e;

  int t = threadIdx.x;
  int gbase = blockIdx.x * 8;
  int b = gbase >> 10;
  int n0 = gbase & 1023;

  if (t < 8) s_ctr[t] = xv[b * NPTS + n0 + t];
  for (int idx = t; idx < 512; idx += 256) {
    int p = idx >> 6, o = idx & 63;
    s_fq[p * 68 + o] = fqg[(gbase + p) * CH + o];
    s_w[idx] = wp[512 + idx];
  }
  s_gq[t] = gq[t];
  s_bq[t] = bq[t];
  {
    int p = t >> 5, kk_ = t & 31;
    if (kk_ < KNBR) {
      int nb = knn[(gbase + p) * KNBR + kk_];
      float4 nx = xv[b * NPTS + nb];
      float4 ct = xv[b * NPTS + n0 + p];
      s_rel[p * KNBR + kk_] =
          make_float4(nx.x - ct.x, nx.y - ct.y, nx.z - ct.z, nx.w - ct.w);
    }
  }
  int w = t >> 6, l = t & 63;
  int lane16 = l & 15, g = l >> 4;
  s16x8 af[4][2];
  #pragma unroll
  for (int mm = 0; mm < 4; ++mm) {
    int row = w * 64 + mm * 16 + lane16;
    af[mm][0] = *(const s16x8*)(wqb + row * 64 + g * 8);
    af[mm][1] = *(const s16x8*)(wqb + row * 64 + 32 + g * 8);
  }
  __syncthreads();

  {
    int p8 = l & 7;
    s16x8 bf[2];
    #pragma unroll
    for (int ks = 0; ks < 2; ++ks) {
      const float4* fp = (const float4*)(s_fq + p8 * 68 + ks * 32 + g * 8);
      float4 f0 = fp[0], f1 = fp[1];
      union { uint4 u; s16x8 s; } cv;
      cv.u.x = (uint)f2bf(f0.x) | ((uint)f2bf(f0.y) << 16);
      cv.u.y = (uint)f2bf(f0.z) | ((uint)f2bf(f0.w) << 16);
      cv.u.z = (uint)f2bf(f1.x) | ((uint)f2bf(f1.y) << 16);
      cv.u.w = (uint)f2bf(f1.z) | ((uint)f2bf(f1.w) << 16);
      bf[ks] = cv.s;
    }
    bool active = (lane16 < 8);
    #pragma unroll
    for (int mm = 0; mm < 4; ++mm) {
      f32x4 acc = {0.f, 0.f, 0.f, 0.f};
      acc = __builtin_amdgcn_mfma_f32_16x16x32_bf16(af[mm][0], bf[0], acc, 0, 0, 0);
      acc = __builtin_amdgcn_mfma_f32_16x16x32_bf16(af[mm][1], bf[1], acc, 0, 0, 0);
      if (active) {
        #pragma unroll
        for (int r = 0; r < 4; ++r) {
          int row = w * 64 + mm * 16 + g * 4 + r;
          float val = fmaxf(fmaf(s_gq[row], acc[r], s_bq[row]), 0.f);
          s_q[lane16 * 264 + (row >> 5) * 33 + (row & 31)] = val;
        }
      }
    }
  }

  {
    int d = t & 31, p = t >> 5;
    float4 ct = s_ctr[p];
    float4 wr = *(const float4*)(s_w + 256 + d * 4);
    float4 wc = *(const float4*)(s_w + 384 + d * 4);
    float cb = fmaf(wc.x, ct.x, fmaf(wc.y, ct.y, fmaf(wc.z, ct.z, wc.w * ct.w)));
    #pragma unroll
    for (int k = 0; k < KNBR; ++k) {
      float4 r = s_rel[p * KNBR + k];
      float kkv = fmaf(wr.x, r.x, fmaf(wr.y, r.y, fmaf(wr.z, r.z, fmaf(wr.w, r.w, cb))));
      s_e[p * 660 + k * 33 + d] = __expf(kkv);
    }
    float4 vr_ = *(const float4*)(s_w + 0 + d * 4);
    float4 vc_ = *(const float4*)(s_w + 128 + d * 4);
    float cbv = fmaf(vc_.x, ct.x, fmaf(vc_.y, ct.y, fmaf(vc_.z, ct.z, vc_.w * ct.w)));
    float gvd = gv[d], bvd = bv[d];
    #pragma unroll
    for (int k = 0; k < KNBR; ++k) {
      float4 r = s_rel[p * KNBR + k];
      float vv = fmaf(vr_.x, r.x, fmaf(vr_.y, r.y, fmaf(vr_.z, r.z, fmaf(vr_.w, r.w, cbv))));
      s_v[p * 660 + k * 33 + d] = fmaf(gvd, vv, bvd);
    }
  }
  __syncthreads();

  {
    int d = t & 31, p = t >> 5;
    float s = 0.f;
    #pragma unroll
    for (int k = 0; k < KNBR; ++k) s += s_e[p * 660 + k * 33 + d];
    float rs = 1.0f / s;
    #pragma unroll
    for (int k = 0; k < KNBR; ++k) s_e[p * 660 + k * 33 + d] *= rs;
  }
  __syncthreads();

  {
    int p = t >> 5, h = (t >> 2) & 7, kh = t & 3;
    float qr[32];
    #pragma unroll
    for (int d = 0; d < 32; ++d) qr[d] = s_q[p * 264 + h * 33 + d];
    #pragma unroll
    for (int i = 0; i < 5; ++i) {
      int k = kh * 5 + i;
      float acc = 0.f;
      #pragma unroll
      for (int d = 0; d < 32; ++d) acc = fmaf(qr[d], s_e[p * 660 + k * 33 + d], acc);
      s_a[p * 160 + h * 20 + k] = acc;
    }
  }
  __syncthreads();

  {
    int p = t >> 5, v = t & 31;
    float vr[KNBR];
    #pragma unroll
    for (int k = 0; k < KNBR; ++k) vr[k] = s_v[p * 660 + k * 33 + v];
    #pragma unroll
    for (int h = 0; h < 8; ++h) {
      float acc = 0.f;
      #pragma unroll
      for (int k = 0; k < KNBR; ++k)
        acc = fmaf(s_a[p * 160 + h * 20 + k], vr[k], acc);
      s_out[(h * 32 + v) * 9 + p] = acc;
    }
  }
  __syncthreads();

  for (int idx = t; idx < 2048; idx += 256) {
    int hv = idx >> 3, pp = idx & 7;
    o1[b * 262144 + hv * 1024 + n0 + pp] = s_out[hv * 9 + pp];
  }
}

extern "C" void kernel_launch(void* const* d_in, const int* in_sizes, int n_in,
                              void* d_out, int out_size, void* d_ws, size_t ws_size,
                              hipStream_t stream) {
  const float* x = (const float*)d_in[0];
  const float* Wh = (const float*)d_in[1];
  const float* W1 = (const float*)d_in[2];
  const float* g1 = (const float*)d_in[3];
  const float* b1 = (const float*)d_in[4];
  const float* W2 = (const float*)d_in[5];
  const float* g2 = (const float*)d_in[6];
  const float* b2 = (const float*)d_in[7];
  const float* Wv = (const float*)d_in[8];
  const float* gv = (const float*)d_in[9];
  const float* bv = (const float*)d_in[10];
  const float* Wk = (const float*)d_in[11];
  const float* Wq = (const float*)d_in[12];
  const float* gq = (const float*)d_in[13];
  const float* bq = (const float*)d_in[14];
  float* out = (float*)d_out;

  ushort* knn = (ushort*)d_ws;
  float* fq = (float*)((char*)d_ws + 2621440);
  float* wp = (float*)((char*)d_ws + 19398656);
  ushort* w2b = (ushort*)((char*)d_ws + 19402752);
  ushort* wqb = (ushort*)((char*)d_ws + 19410944);

  hipLaunchKernelGGL(k_prep, dim3(1), dim3(256), 0, stream, Wh, W1, g1, Wv, Wk, W2,
                     Wq, wp, w2b, wqb);
  hipLaunchKernelGGL(k_knn, dim3(1024), dim3(256), 0, stream, (const float4*)x, knn,
                     (float4*)out);
  hipLaunchKernelGGL(k_fq, dim3(4096), dim3(256), 0, stream, (const float4*)x, knn,
                     wp, b1, w2b, g2, b2, fq);
  hipLaunchKernelGGL(k_attn, dim3(8192), dim3(256), 0, stream, (const float4*)x, knn,
                     fq, wp, wqb, gq, bq, gv, bv, out + 262144);
}

// Round 6
// 334.276 us; speedup vs baseline: 13.2953x; 1.2798x over previous
//
#include <hip/hip_runtime.h>
#include <math.h>

#define NPTS 1024
#define KNBR 20
#define CH 64

// ws layout (bytes), proven budget: ws_size >= 22,032,384 (used in R1/R2)
// [0, 2621440)          : knn  ushort [65536][20]
// [2621440, 19398656)   : fq   float [65536][64]
// [19398656, 19402752)  : wp   float[1024]
// [19402752, 19410944)  : W2 bf16 [64][64]
// [19410944, 19443712)  : Wq bf16 [256][64]

typedef __attribute__((ext_vector_type(8))) short s16x8;
typedef __attribute__((ext_vector_type(4))) float f32x4;

static __device__ __forceinline__ ushort f2bf(float f) {
  uint u = __float_as_uint(f);
  uint r = (u + 0x7FFFu + ((u >> 16) & 1u)) >> 16;
  return (ushort)r;
}

static __device__ __forceinline__ int mbcnt64(unsigned long long m) {
  return __builtin_amdgcn_mbcnt_hi((uint)(m >> 32),
                                   __builtin_amdgcn_mbcnt_lo((uint)m, 0));
}

__global__ __launch_bounds__(256) void k_prep(
    const float* __restrict__ Wh, const float* __restrict__ W1,
    const float* __restrict__ g1, const float* __restrict__ Wv,
    const float* __restrict__ Wk, const float* __restrict__ W2,
    const float* __restrict__ Wq, float* __restrict__ wp,
    ushort* __restrict__ w2b, ushort* __restrict__ wqb) {
  int t = threadIdx.x;
  {
    int o = t >> 2, c = t & 3;
    float acc = W1[o * 40 + c];
    #pragma unroll
    for (int v = 0; v < 32; ++v) acc = fmaf(W1[o * 40 + 8 + v], Wh[v * 4 + c], acc);
    float g = g1[o];
    wp[t] = g * acc;
    wp[256 + t] = g * W1[o * 40 + 4 + c];
  }
  if (t < 128) {
    int d = t >> 2, c = t & 3;
    float av = Wv[d * 40 + c];
    float ak = Wk[d * 40 + c];
    #pragma unroll
    for (int u = 0; u < 32; ++u) {
      av = fmaf(Wv[d * 40 + 8 + u], Wh[u * 4 + c], av);
      ak = fmaf(Wk[d * 40 + 8 + u], Wh[u * 4 + c], ak);
    }
    wp[512 + t] = av;
    wp[640 + t] = Wv[d * 40 + 4 + c];
    wp[768 + t] = ak;
    wp[896 + t] = Wk[d * 40 + 4 + c];
  }
  #pragma unroll
  for (int i = 0; i < 16; ++i) w2b[t * 16 + i] = f2bf(W2[t * 16 + i]);
  for (int i = 0; i < 64; ++i) wqb[t * 64 + i] = f2bf(Wq[t * 64 + i]);
}

// ---------------- KNN v4: ballot radix-select, wave-per-center --------------
// Lane l holds keys for j = s*64+l (s=0..15) in registers.
// T0 = 20th-smallest lane-min (upper bound on global 20th) -> survivor
// compact -> exact 20-of-<=64 select with index tie-break. Exact fallback
// (full-set bisect) if survivors > 64. Output order unsorted (downstream is
// order-invariant: maxpool/softmax/sums over k).
__global__ __launch_bounds__(256) void k_knn(const float4* __restrict__ xv,
                                             ushort* __restrict__ knn,
                                             float4* __restrict__ outx) {
  __shared__ float4 sx[NPTS];       // 16 KB
  __shared__ float ssq[NPTS];       // 4 KB
  __shared__ uint s_sk[4][64];      // per-wave survivor keys
  __shared__ ushort s_sj[4][64];    // per-wave survivor indices

  int t = threadIdx.x;
  int b = blockIdx.x >> 4, grp = blockIdx.x & 15;
  for (int j = t; j < NPTS; j += 256) {
    float4 p = xv[b * NPTS + j];
    sx[j] = p;
    ssq[j] = p.x * p.x + p.y * p.y + p.z * p.z + p.w * p.w;
    if (grp == 0) outx[b * NPTS + j] = p;  // folded k_copy (out0 = x)
  }
  __syncthreads();

  int w = t >> 6, l = t & 63;

  #pragma unroll 1
  for (int i = 0; i < 16; ++i) {
    int cloc = grp * 64 + w * 16 + i;
    int gid20 = (b * NPTS + cloc) * KNBR;
    float4 c = sx[cloc];
    uint u[16];
    uint mn = 0xFFFFFFFFu;
    #pragma unroll
    for (int s = 0; s < 16; ++s) {
      int j = s * 64 + l;
      float4 q = sx[j];
      float dot = c.x * q.x;
      dot = fmaf(c.y, q.y, dot);
      dot = fmaf(c.z, q.z, dot);
      dot = fmaf(c.w, q.w, dot);
      float key = fmaf(-2.f, dot, ssq[j]);  // dist - |c|^2 (monotone)
      uint uu = __float_as_uint(key);
      uu = ((int)uu < 0) ? ~uu : (uu | 0x80000000u);
      u[s] = uu;
      mn = min(mn, uu);
    }

    // T0 = 20th-smallest lane-min: largest T with #{mn < T} < 20
    uint T0 = 0;
    #pragma unroll
    for (int bit = 31; bit >= 0; --bit) {
      uint cand = T0 | (1u << bit);
      if (__popcll(__ballot(mn < cand)) < 20) T0 = cand;
    }

    // survivor count (>= 20 by construction)
    int scnt = 0;
    #pragma unroll
    for (int s = 0; s < 16; ++s) scnt += (int)__popcll(__ballot(u[s] <= T0));

    if (scnt <= 64) {
      // compact survivors into per-wave LDS
      int base = 0;
      #pragma unroll
      for (int s = 0; s < 16; ++s) {
        unsigned long long mask = __ballot(u[s] <= T0);
        if (u[s] <= T0) {
          int off = base + mbcnt64(mask);
          s_sk[w][off] = u[s];
          s_sj[w][off] = (ushort)(s * 64 + l);
        }
        base += (int)__popcll(mask);
      }
      asm volatile("s_waitcnt lgkmcnt(0)" ::: "memory");
      __builtin_amdgcn_sched_barrier(0);
      uint uk = (l < scnt) ? s_sk[w][l] : 0xFFFFFFFFu;
      uint uj = (l < scnt) ? (uint)s_sj[w][l] : 0xFFFFu;

      // u20 = 20th smallest survivor key (with multiplicity)
      uint u20 = 0;
      #pragma unroll
      for (int bit = 31; bit >= 0; --bit) {
        uint cand = u20 | (1u << bit);
        if (__popcll(__ballot(uk < cand)) < 20) u20 = cand;
      }
      int m = (int)__popcll(__ballot(uk < u20));  // <= 19
      int r = 20 - m;                              // >= 1
      // jr = r-th smallest j among keys == u20 (j unique)
      uint jr = 0;
      #pragma unroll
      for (int bit = 10; bit >= 0; --bit) {
        uint cand = jr | (1u << bit);
        if (__popcll(__ballot((uk == u20) && (uj < cand))) < r) jr = cand;
      }
      bool sel = (uk < u20) || ((uk == u20) && (uj <= jr));
      unsigned long long smask = __ballot(sel);
      int off = mbcnt64(smask);
      if (sel) knn[gid20 + off] = (ushort)uj;
    } else {
      // exact fallback: bisect on the full per-lane key set
      uint u20 = 0;
      #pragma unroll 1
      for (int bit = 31; bit >= 0; --bit) {
        uint cand = u20 | (1u << bit);
        int cnt = 0;
        #pragma unroll
        for (int s = 0; s < 16; ++s)
          cnt += (int)__popcll(__ballot(u[s] < cand));
        if (cnt < 20) u20 = cand;
      }
      int base = 0;
      #pragma unroll
      for (int s = 0; s < 16; ++s) {
        unsigned long long mask = __ballot(u[s] < u20);
        if (u[s] < u20) knn[gid20 + base + mbcnt64(mask)] = (ushort)(s * 64 + l);
        base += (int)__popcll(mask);
      }
      int r = 20 - base;  // >= 1
      #pragma unroll
      for (int s = 0; s < 16; ++s) {
        unsigned long long mask = __ballot(u[s] == u20);
        int pos = mbcnt64(mask);
        int cntm = (int)__popcll(mask);
        int take = (r < cntm) ? r : cntm;
        if ((u[s] == u20) && (pos < take))
          knn[gid20 + base + pos] = (ushort)(s * 64 + l);
        base += take;
        r -= take;
      }
    }
  }
}

// ---------------- fq: MFMA version ------------------------------------------
__global__ __launch_bounds__(256) void k_fq(
    const float4* __restrict__ xv, const ushort* __restrict__ knn,
    const float* __restrict__ wp, const float* __restrict__ b1,
    const ushort* __restrict__ w2b, const float* __restrict__ g2,
    const float* __restrict__ b2, float* __restrict__ fq) {
  __shared__ ushort s_h1[320 * 64];
  __shared__ float s_w1[576];
  __shared__ float s_base[16 * 65];
  __shared__ float s_pmax[4 * 16 * 65];

  int t = threadIdx.x;
  int gid0 = blockIdx.x * 16;
  int bbase = (gid0 >> 10) << 10;

  for (int i = t; i < 576; i += 256) s_w1[i] = (i < 512) ? wp[i] : b1[i - 512];
  __syncthreads();

  for (int i = t; i < 1024; i += 256) {
    int p = i >> 6, o = i & 63;
    float4 ct = xv[gid0 + p];
    float v = s_w1[512 + o];
    v = fmaf(s_w1[256 + o * 4 + 0], ct.x, v);
    v = fmaf(s_w1[256 + o * 4 + 1], ct.y, v);
    v = fmaf(s_w1[256 + o * 4 + 2], ct.z, v);
    v = fmaf(s_w1[256 + o * 4 + 3], ct.w, v);
    s_base[p * 65 + o] = v;
  }
  __syncthreads();

  int w = t >> 6, l = t & 63;

  for (int j = l; j < 80; j += 64) {
    int cc = w * 80 + j;
    int kk = cc >> 4, p = cc & 15;
    int gid = gid0 + p;
    int nb = knn[gid * KNBR + kk];
    float4 nx = xv[bbase + nb];
    float4 ct = xv[gid];
    float rx = nx.x - ct.x, ry = nx.y - ct.y, rz = nx.z - ct.z, rw = nx.w - ct.w;
    int rowbyte = cc * 128;
    int swz = (cc & 7) << 4;
    #pragma unroll
    for (int o8 = 0; o8 < 8; ++o8) {
      uint pk[4];
      #pragma unroll
      for (int jj = 0; jj < 4; ++jj) {
        int o = o8 * 8 + jj * 2;
        float a0 = fmaf(s_w1[o * 4 + 0], rx, s_base[p * 65 + o]);
        a0 = fmaf(s_w1[o * 4 + 1], ry, a0);
        a0 = fmaf(s_w1[o * 4 + 2], rz, a0);
        a0 = fmaf(s_w1[o * 4 + 3], rw, a0);
        float a1 = fmaf(s_w1[o * 4 + 4], rx, s_base[p * 65 + o + 1]);
        a1 = fmaf(s_w1[o * 4 + 5], ry, a1);
        a1 = fmaf(s_w1[o * 4 + 6], rz, a1);
        a1 = fmaf(s_w1[o * 4 + 7], rw, a1);
        a0 = fmaxf(a0, 0.f);
        a1 = fmaxf(a1, 0.f);
        pk[jj] = (uint)f2bf(a0) | ((uint)f2bf(a1) << 16);
      }
      uint4 val;
      val.x = pk[0]; val.y = pk[1]; val.z = pk[2]; val.w = pk[3];
      *(uint4*)((char*)s_h1 + ((rowbyte + o8 * 16) ^ swz)) = val;
    }
  }
  __syncthreads();

  {
    int g = l >> 4;
    int lane16 = l & 15;
    s16x8 af[4][2];
    #pragma unroll
    for (int m = 0; m < 4; ++m) {
      int row = m * 16 + lane16;
      af[m][0] = *(const s16x8*)(w2b + row * 64 + 0 * 32 + g * 8);
      af[m][1] = *(const s16x8*)(w2b + row * 64 + 1 * 32 + g * 8);
    }
    float g2r[4][4], b2r[4][4];
    #pragma unroll
    for (int m = 0; m < 4; ++m)
      #pragma unroll
      for (int r = 0; r < 4; ++r) {
        int row = m * 16 + g * 4 + r;
        g2r[m][r] = g2[row];
        b2r[m][r] = b2[row];
      }
    float mx[4][4];
    #pragma unroll
    for (int m = 0; m < 4; ++m)
      #pragma unroll
      for (int r = 0; r < 4; ++r) mx[m][r] = 0.f;

    #pragma unroll
    for (int i = 0; i < 5; ++i) {
      int kt = w * 5 + i;
      int col = kt * 16 + lane16;
      int rowbyte = col * 128;
      int swz = (col & 7) << 4;
      s16x8 bf0 = *(const s16x8*)((char*)s_h1 + ((rowbyte + g * 16) ^ swz));
      s16x8 bf1 = *(const s16x8*)((char*)s_h1 + ((rowbyte + 64 + g * 16) ^ swz));
      #pragma unroll
      for (int m = 0; m < 4; ++m) {
        f32x4 acc = {0.f, 0.f, 0.f, 0.f};
        acc = __builtin_amdgcn_mfma_f32_16x16x32_bf16(af[m][0], bf0, acc, 0, 0, 0);
        acc = __builtin_amdgcn_mfma_f32_16x16x32_bf16(af[m][1], bf1, acc, 0, 0, 0);
        #pragma unroll
        for (int r = 0; r < 4; ++r) {
          float val = fmaxf(fmaf(g2r[m][r], acc[r], b2r[m][r]), 0.f);
          mx[m][r] = fmaxf(mx[m][r], val);
        }
      }
    }
    #pragma unroll
    for (int m = 0; m < 4; ++m)
      #pragma unroll
      for (int r = 0; r < 4; ++r) {
        int o2 = m * 16 + g * 4 + r;
        s_pmax[(w * 16 + lane16) * 65 + o2] = mx[m][r];
      }
  }
  __syncthreads();

  for (int idx = t; idx < 1024; idx += 256) {
    int p = idx >> 6, o = idx & 63;
    float v = s_pmax[p * 65 + o];
    v = fmaxf(v, s_pmax[(16 + p) * 65 + o]);
    v = fmaxf(v, s_pmax[(32 + p) * 65 + o]);
    v = fmaxf(v, s_pmax[(48 + p) * 65 + o]);
    fq[(gid0 + p) * 64 + o] = v;
  }
}

// ---------------- attention: q via MFMA, padded-stride LDS ------------------
__global__ __launch_bounds__(256) void k_attn(
    const float4* __restrict__ xv, const ushort* __restrict__ knn,
    const float* __restrict__ fqg, const float* __restrict__ wp,
    const ushort* __restrict__ wqb, const float* __restrict__ gq,
    const float* __restrict__ bq, const float* __restrict__ gv,
    const float* __restrict__ bv, float* __restrict__ o1) {
  __shared__ __align__(16) float s_w[512];
  __shared__ float4 s_ctr[8];
  __shared__ __align__(16) float s_fq[8 * 68];
  __shared__ float s_gq[256];
  __shared__ float s_bq[256];
  __shared__ float4 s_rel[160];
  __shared__ float s_q[8 * 264];
  __shared__ float s_e[8 * 660];
  __shared__ float s_v[8 * 660];
  __shared__ float s_a[8 * 160];
  float* s_out = s_e;

  int t = threadIdx.x;
  int gbase = blockIdx.x * 8;
  int b = gbase >> 10;
  int n0 = gbase & 1023;

  if (t < 8) s_ctr[t] = xv[b * NPTS + n0 + t];
  for (int idx = t; idx < 512; idx += 256) {
    int p = idx >> 6, o = idx & 63;
    s_fq[p * 68 + o] = fqg[(gbase + p) * CH + o];
    s_w[idx] = wp[512 + idx];
  }
  s_gq[t] = gq[t];
  s_bq[t] = bq[t];
  {
    int p = t >> 5, kk_ = t & 31;
    if (kk_ < KNBR) {
      int nb = knn[(gbase + p) * KNBR + kk_];
      float4 nx = xv[b * NPTS + nb];
      float4 ct = xv[b * NPTS + n0 + p];
      s_rel[p * KNBR + kk_] =
          make_float4(nx.x - ct.x, nx.y - ct.y, nx.z - ct.z, nx.w - ct.w);
    }
  }
  int w = t >> 6, l = t & 63;
  int lane16 = l & 15, g = l >> 4;
  s16x8 af[4][2];
  #pragma unroll
  for (int mm = 0; mm < 4; ++mm) {
    int row = w * 64 + mm * 16 + lane16;
    af[mm][0] = *(const s16x8*)(wqb + row * 64 + g * 8);
    af[mm][1] = *(const s16x8*)(wqb + row * 64 + 32 + g * 8);
  }
  __syncthreads();

  {
    int p8 = l & 7;
    s16x8 bf[2];
    #pragma unroll
    for (int ks = 0; ks < 2; ++ks) {
      const float4* fp = (const float4*)(s_fq + p8 * 68 + ks * 32 + g * 8);
      float4 f0 = fp[0], f1 = fp[1];
      union { uint4 u; s16x8 s; } cv;
      cv.u.x = (uint)f2bf(f0.x) | ((uint)f2bf(f0.y) << 16);
      cv.u.y = (uint)f2bf(f0.z) | ((uint)f2bf(f0.w) << 16);
      cv.u.z = (uint)f2bf(f1.x) | ((uint)f2bf(f1.y) << 16);
      cv.u.w = (uint)f2bf(f1.z) | ((uint)f2bf(f1.w) << 16);
      bf[ks] = cv.s;
    }
    bool active = (lane16 < 8);
    #pragma unroll
    for (int mm = 0; mm < 4; ++mm) {
      f32x4 acc = {0.f, 0.f, 0.f, 0.f};
      acc = __builtin_amdgcn_mfma_f32_16x16x32_bf16(af[mm][0], bf[0], acc, 0, 0, 0);
      acc = __builtin_amdgcn_mfma_f32_16x16x32_bf16(af[mm][1], bf[1], acc, 0, 0, 0);
      if (active) {
        #pragma unroll
        for (int r = 0; r < 4; ++r) {
          int row = w * 64 + mm * 16 + g * 4 + r;
          float val = fmaxf(fmaf(s_gq[row], acc[r], s_bq[row]), 0.f);
          s_q[lane16 * 264 + (row >> 5) * 33 + (row & 31)] = val;
        }
      }
    }
  }

  {
    int d = t & 31, p = t >> 5;
    float4 ct = s_ctr[p];
    float4 wr = *(const float4*)(s_w + 256 + d * 4);
    float4 wc = *(const float4*)(s_w + 384 + d * 4);
    float cb = fmaf(wc.x, ct.x, fmaf(wc.y, ct.y, fmaf(wc.z, ct.z, wc.w * ct.w)));
    #pragma unroll
    for (int k = 0; k < KNBR; ++k) {
      float4 r = s_rel[p * KNBR + k];
      float kkv = fmaf(wr.x, r.x, fmaf(wr.y, r.y, fmaf(wr.z, r.z, fmaf(wr.w, r.w, cb))));
      s_e[p * 660 + k * 33 + d] = __expf(kkv);
    }
    float4 vr_ = *(const float4*)(s_w + 0 + d * 4);
    float4 vc_ = *(const float4*)(s_w + 128 + d * 4);
    float cbv = fmaf(vc_.x, ct.x, fmaf(vc_.y, ct.y, fmaf(vc_.z, ct.z, vc_.w * ct.w)));
    float gvd = gv[d], bvd = bv[d];
    #pragma unroll
    for (int k = 0; k < KNBR; ++k) {
      float4 r = s_rel[p * KNBR + k];
      float vv = fmaf(vr_.x, r.x, fmaf(vr_.y, r.y, fmaf(vr_.z, r.z, fmaf(vr_.w, r.w, cbv))));
      s_v[p * 660 + k * 33 + d] = fmaf(gvd, vv, bvd);
    }
  }
  __syncthreads();

  {
    int d = t & 31, p = t >> 5;
    float s = 0.f;
    #pragma unroll
    for (int k = 0; k < KNBR; ++k) s += s_e[p * 660 + k * 33 + d];
    float rs = 1.0f / s;
    #pragma unroll
    for (int k = 0; k < KNBR; ++k) s_e[p * 660 + k * 33 + d] *= rs;
  }
  __syncthreads();

  {
    int p = t >> 5, h = (t >> 2) & 7, kh = t & 3;
    float qr[32];
    #pragma unroll
    for (int d = 0; d < 32; ++d) qr[d] = s_q[p * 264 + h * 33 + d];
    #pragma unroll
    for (int i = 0; i < 5; ++i) {
      int k = kh * 5 + i;
      float acc = 0.f;
      #pragma unroll
      for (int d = 0; d < 32; ++d) acc = fmaf(qr[d], s_e[p * 660 + k * 33 + d], acc);
      s_a[p * 160 + h * 20 + k] = acc;
    }
  }
  __syncthreads();

  {
    int p = t >> 5, v = t & 31;
    float vr[KNBR];
    #pragma unroll
    for (int k = 0; k < KNBR; ++k) vr[k] = s_v[p * 660 + k * 33 + v];
    #pragma unroll
    for (int h = 0; h < 8; ++h) {
      float acc = 0.f;
      #pragma unroll
      for (int k = 0; k < KNBR; ++k)
        acc = fmaf(s_a[p * 160 + h * 20 + k], vr[k], acc);
      s_out[(h * 32 + v) * 9 + p] = acc;
    }
  }
  __syncthreads();

  for (int idx = t; idx < 2048; idx += 256) {
    int hv = idx >> 3, pp = idx & 7;
    o1[b * 262144 + hv * 1024 + n0 + pp] = s_out[hv * 9 + pp];
  }
}

extern "C" void kernel_launch(void* const* d_in, const int* in_sizes, int n_in,
                              void* d_out, int out_size, void* d_ws, size_t ws_size,
                              hipStream_t stream) {
  const float* x = (const float*)d_in[0];
  const float* Wh = (const float*)d_in[1];
  const float* W1 = (const float*)d_in[2];
  const float* g1 = (const float*)d_in[3];
  const float* b1 = (const float*)d_in[4];
  const float* W2 = (const float*)d_in[5];
  const float* g2 = (const float*)d_in[6];
  const float* b2 = (const float*)d_in[7];
  const float* Wv = (const float*)d_in[8];
  const float* gv = (const float*)d_in[9];
  const float* bv = (const float*)d_in[10];
  const float* Wk = (const float*)d_in[11];
  const float* Wq = (const float*)d_in[12];
  const float* gq = (const float*)d_in[13];
  const float* bq = (const float*)d_in[14];
  float* out = (float*)d_out;

  ushort* knn = (ushort*)d_ws;
  float* fq = (float*)((char*)d_ws + 2621440);
  float* wp = (float*)((char*)d_ws + 19398656);
  ushort* w2b = (ushort*)((char*)d_ws + 19402752);
  ushort* wqb = (ushort*)((char*)d_ws + 19410944);

  hipLaunchKernelGGL(k_prep, dim3(1), dim3(256), 0, stream, Wh, W1, g1, Wv, Wk, W2,
                     Wq, wp, w2b, wqb);
  hipLaunchKernelGGL(k_knn, dim3(1024), dim3(256), 0, stream, (const float4*)x, knn,
                     (float4*)out);
  hipLaunchKernelGGL(k_fq, dim3(4096), dim3(256), 0, stream, (const float4*)x, knn,
                     wp, b1, w2b, g2, b2, fq);
  hipLaunchKernelGGL(k_attn, dim3(8192), dim3(256), 0, stream, (const float4*)x, knn,
                     fq, wp, wqb, gq, bq, gv, bv, out + 262144);
}

// Round 7
// 286.388 us; speedup vs baseline: 15.5184x; 1.1672x over previous
//
#include <hip/hip_runtime.h>
#include <math.h>

#define NPTS 1024
#define KNBR 20
#define CH 64

// ws layout (bytes), proven budget: ws_size >= 22,032,384 (used in R1/R2)
// [0, 2621440)          : knn  ushort [65536][20]
// [2621440, 19398656)   : fq   float [65536][64]
// [19398656, 19402752)  : wp   float[1024]
// [19402752, 19410944)  : W2 bf16 [64][64]
// [19410944, 19443712)  : Wq bf16 [256][64]

typedef __attribute__((ext_vector_type(8))) short s16x8;
typedef __attribute__((ext_vector_type(4))) float f32x4;

static __device__ __forceinline__ ushort f2bf(float f) {
  uint u = __float_as_uint(f);
  uint r = (u + 0x7FFFu + ((u >> 16) & 1u)) >> 16;
  return (ushort)r;
}

static __device__ __forceinline__ int mbcnt64(unsigned long long m) {
  return __builtin_amdgcn_mbcnt_hi((uint)(m >> 32),
                                   __builtin_amdgcn_mbcnt_lo((uint)m, 0));
}

__global__ __launch_bounds__(256) void k_prep(
    const float* __restrict__ Wh, const float* __restrict__ W1,
    const float* __restrict__ g1, const float* __restrict__ Wv,
    const float* __restrict__ Wk, const float* __restrict__ W2,
    const float* __restrict__ Wq, float* __restrict__ wp,
    ushort* __restrict__ w2b, ushort* __restrict__ wqb) {
  int t = threadIdx.x;
  {
    int o = t >> 2, c = t & 3;
    float acc = W1[o * 40 + c];
    #pragma unroll
    for (int v = 0; v < 32; ++v) acc = fmaf(W1[o * 40 + 8 + v], Wh[v * 4 + c], acc);
    float g = g1[o];
    wp[t] = g * acc;
    wp[256 + t] = g * W1[o * 40 + 4 + c];
  }
  if (t < 128) {
    int d = t >> 2, c = t & 3;
    float av = Wv[d * 40 + c];
    float ak = Wk[d * 40 + c];
    #pragma unroll
    for (int u = 0; u < 32; ++u) {
      av = fmaf(Wv[d * 40 + 8 + u], Wh[u * 4 + c], av);
      ak = fmaf(Wk[d * 40 + 8 + u], Wh[u * 4 + c], ak);
    }
    wp[512 + t] = av;
    wp[640 + t] = Wv[d * 40 + 4 + c];
    wp[768 + t] = ak;
    wp[896 + t] = Wk[d * 40 + 4 + c];
  }
  #pragma unroll
  for (int i = 0; i < 16; ++i) w2b[t * 16 + i] = f2bf(W2[t * 16 + i]);
  for (int i = 0; i < 64; ++i) wqb[t * 64 + i] = f2bf(Wq[t * 64 + i]);
}

// ---------------- KNN v4: ballot radix-select, wave-per-center --------------
__global__ __launch_bounds__(256) void k_knn(const float4* __restrict__ xv,
                                             ushort* __restrict__ knn,
                                             float4* __restrict__ outx) {
  __shared__ float4 sx[NPTS];
  __shared__ float ssq[NPTS];
  __shared__ uint s_sk[4][64];
  __shared__ ushort s_sj[4][64];

  int t = threadIdx.x;
  int b = blockIdx.x >> 4, grp = blockIdx.x & 15;
  for (int j = t; j < NPTS; j += 256) {
    float4 p = xv[b * NPTS + j];
    sx[j] = p;
    ssq[j] = p.x * p.x + p.y * p.y + p.z * p.z + p.w * p.w;
    if (grp == 0) outx[b * NPTS + j] = p;  // folded k_copy (out0 = x)
  }
  __syncthreads();

  int w = t >> 6, l = t & 63;

  #pragma unroll 1
  for (int i = 0; i < 16; ++i) {
    int cloc = grp * 64 + w * 16 + i;
    int gid20 = (b * NPTS + cloc) * KNBR;
    float4 c = sx[cloc];
    uint u[16];
    uint mn = 0xFFFFFFFFu;
    #pragma unroll
    for (int s = 0; s < 16; ++s) {
      int j = s * 64 + l;
      float4 q = sx[j];
      float dot = c.x * q.x;
      dot = fmaf(c.y, q.y, dot);
      dot = fmaf(c.z, q.z, dot);
      dot = fmaf(c.w, q.w, dot);
      float key = fmaf(-2.f, dot, ssq[j]);
      uint uu = __float_as_uint(key);
      uu = ((int)uu < 0) ? ~uu : (uu | 0x80000000u);
      u[s] = uu;
      mn = min(mn, uu);
    }

    uint T0 = 0;
    #pragma unroll
    for (int bit = 31; bit >= 0; --bit) {
      uint cand = T0 | (1u << bit);
      if (__popcll(__ballot(mn < cand)) < 20) T0 = cand;
    }

    int scnt = 0;
    #pragma unroll
    for (int s = 0; s < 16; ++s) scnt += (int)__popcll(__ballot(u[s] <= T0));

    if (scnt <= 64) {
      int base = 0;
      #pragma unroll
      for (int s = 0; s < 16; ++s) {
        unsigned long long mask = __ballot(u[s] <= T0);
        if (u[s] <= T0) {
          int off = base + mbcnt64(mask);
          s_sk[w][off] = u[s];
          s_sj[w][off] = (ushort)(s * 64 + l);
        }
        base += (int)__popcll(mask);
      }
      asm volatile("s_waitcnt lgkmcnt(0)" ::: "memory");
      __builtin_amdgcn_sched_barrier(0);
      uint uk = (l < scnt) ? s_sk[w][l] : 0xFFFFFFFFu;
      uint uj = (l < scnt) ? (uint)s_sj[w][l] : 0xFFFFu;

      uint u20 = 0;
      #pragma unroll
      for (int bit = 31; bit >= 0; --bit) {
        uint cand = u20 | (1u << bit);
        if (__popcll(__ballot(uk < cand)) < 20) u20 = cand;
      }
      int m = (int)__popcll(__ballot(uk < u20));
      int r = 20 - m;
      uint jr = 0;
      #pragma unroll
      for (int bit = 10; bit >= 0; --bit) {
        uint cand = jr | (1u << bit);
        if (__popcll(__ballot((uk == u20) && (uj < cand))) < r) jr = cand;
      }
      bool sel = (uk < u20) || ((uk == u20) && (uj <= jr));
      unsigned long long smask = __ballot(sel);
      int off = mbcnt64(smask);
      if (sel) knn[gid20 + off] = (ushort)uj;
    } else {
      uint u20 = 0;
      #pragma unroll 1
      for (int bit = 31; bit >= 0; --bit) {
        uint cand = u20 | (1u << bit);
        int cnt = 0;
        #pragma unroll
        for (int s = 0; s < 16; ++s)
          cnt += (int)__popcll(__ballot(u[s] < cand));
        if (cnt < 20) u20 = cand;
      }
      int base = 0;
      #pragma unroll
      for (int s = 0; s < 16; ++s) {
        unsigned long long mask = __ballot(u[s] < u20);
        if (u[s] < u20) knn[gid20 + base + mbcnt64(mask)] = (ushort)(s * 64 + l);
        base += (int)__popcll(mask);
      }
      int r = 20 - base;
      #pragma unroll
      for (int s = 0; s < 16; ++s) {
        unsigned long long mask = __ballot(u[s] == u20);
        int pos = mbcnt64(mask);
        int cntm = (int)__popcll(mask);
        int take = (r < cntm) ? r : cntm;
        if ((u[s] == u20) && (pos < take))
          knn[gid20 + base + pos] = (ushort)(s * 64 + l);
        base += take;
        r -= take;
      }
    }
  }
}

// ---------------- fq: MFMA, wave-owns-rows (no cross-wave combine) ----------
// LDS ~48KB -> 3 blocks/CU. wave w computes rows w*16..w*16+15 over all 20
// k-tiles; maxpool completes in-wave; direct float4 store.
__global__ __launch_bounds__(256) void k_fq(
    const float4* __restrict__ xv, const ushort* __restrict__ knn,
    const float* __restrict__ wp, const float* __restrict__ b1,
    const ushort* __restrict__ w2b, const float* __restrict__ g2,
    const float* __restrict__ b2, float* __restrict__ fq) {
  __shared__ ushort s_h1[320 * 64];          // 40960 B
  __shared__ float s_w1[576];                // 2304 B
  __shared__ float s_base[16 * 65];          // 4160 B
  __shared__ __align__(16) ushort s_knn[320];  // 640 B

  int t = threadIdx.x;
  int gid0 = blockIdx.x * 16;
  int bbase = (gid0 >> 10) << 10;

  for (int i = t; i < 576; i += 256) s_w1[i] = (i < 512) ? wp[i] : b1[i - 512];
  if (t < 160) ((uint*)s_knn)[t] = ((const uint*)(knn + (size_t)gid0 * KNBR))[t];
  __syncthreads();

  for (int i = t; i < 1024; i += 256) {
    int p = i >> 6, o = i & 63;
    float4 ct = xv[gid0 + p];
    float v = s_w1[512 + o];
    v = fmaf(s_w1[256 + o * 4 + 0], ct.x, v);
    v = fmaf(s_w1[256 + o * 4 + 1], ct.y, v);
    v = fmaf(s_w1[256 + o * 4 + 2], ct.z, v);
    v = fmaf(s_w1[256 + o * 4 + 3], ct.w, v);
    s_base[p * 65 + o] = v;
  }
  __syncthreads();

  int w = t >> 6, l = t & 63;

  // h1 phase: wave w computes cols w*80 .. w*80+79
  for (int j = l; j < 80; j += 64) {
    int cc = w * 80 + j;
    int kk = cc >> 4, p = cc & 15;
    int nb = (int)s_knn[p * KNBR + kk];
    float4 nx = xv[bbase + nb];
    float4 ct = xv[gid0 + p];
    float rx = nx.x - ct.x, ry = nx.y - ct.y, rz = nx.z - ct.z, rw = nx.w - ct.w;
    int rowbyte = cc * 128;
    int swz = (cc & 7) << 4;
    #pragma unroll
    for (int o8 = 0; o8 < 8; ++o8) {
      uint pk[4];
      #pragma unroll
      for (int jj = 0; jj < 4; ++jj) {
        int o = o8 * 8 + jj * 2;
        float a0 = fmaf(s_w1[o * 4 + 0], rx, s_base[p * 65 + o]);
        a0 = fmaf(s_w1[o * 4 + 1], ry, a0);
        a0 = fmaf(s_w1[o * 4 + 2], rz, a0);
        a0 = fmaf(s_w1[o * 4 + 3], rw, a0);
        float a1 = fmaf(s_w1[o * 4 + 4], rx, s_base[p * 65 + o + 1]);
        a1 = fmaf(s_w1[o * 4 + 5], ry, a1);
        a1 = fmaf(s_w1[o * 4 + 6], rz, a1);
        a1 = fmaf(s_w1[o * 4 + 7], rw, a1);
        a0 = fmaxf(a0, 0.f);
        a1 = fmaxf(a1, 0.f);
        pk[jj] = (uint)f2bf(a0) | ((uint)f2bf(a1) << 16);
      }
      uint4 val;
      val.x = pk[0]; val.y = pk[1]; val.z = pk[2]; val.w = pk[3];
      *(uint4*)((char*)s_h1 + ((rowbyte + o8 * 16) ^ swz)) = val;
    }
  }
  __syncthreads();

  // MFMA phase: wave w owns m-tile w (rows w*16..w*16+15), all 20 k-tiles
  {
    int g = l >> 4;
    int l16 = l & 15;
    int row0 = w * 16 + g * 4;
    s16x8 af0 = *(const s16x8*)(w2b + (w * 16 + l16) * 64 + g * 8);
    s16x8 af1 = *(const s16x8*)(w2b + (w * 16 + l16) * 64 + 32 + g * 8);
    float4 g2v = *(const float4*)(g2 + row0);
    float4 b2v = *(const float4*)(b2 + row0);
    float mx0 = 0.f, mx1 = 0.f, mx2 = 0.f, mx3 = 0.f;  // post-relu >= 0
    #pragma unroll 4
    for (int kt = 0; kt < 20; ++kt) {
      int col = kt * 16 + l16;
      int rowbyte = col * 128;
      int swz = (col & 7) << 4;
      s16x8 bf0 = *(const s16x8*)((char*)s_h1 + ((rowbyte + g * 16) ^ swz));
      s16x8 bf1 = *(const s16x8*)((char*)s_h1 + ((rowbyte + 64 + g * 16) ^ swz));
      f32x4 acc = {0.f, 0.f, 0.f, 0.f};
      acc = __builtin_amdgcn_mfma_f32_16x16x32_bf16(af0, bf0, acc, 0, 0, 0);
      acc = __builtin_amdgcn_mfma_f32_16x16x32_bf16(af1, bf1, acc, 0, 0, 0);
      mx0 = fmaxf(mx0, fmaxf(fmaf(g2v.x, acc[0], b2v.x), 0.f));
      mx1 = fmaxf(mx1, fmaxf(fmaf(g2v.y, acc[1], b2v.y), 0.f));
      mx2 = fmaxf(mx2, fmaxf(fmaf(g2v.z, acc[2], b2v.z), 0.f));
      mx3 = fmaxf(mx3, fmaxf(fmaf(g2v.w, acc[3], b2v.w), 0.f));
    }
    float4 o4 = make_float4(mx0, mx1, mx2, mx3);
    *(float4*)(fq + (size_t)(gid0 + l16) * 64 + row0) = o4;
  }
}

// ---------------- attention: v-in-regs, fused scale, 4 barriers -------------
__global__ __launch_bounds__(256) void k_attn(
    const float4* __restrict__ xv, const ushort* __restrict__ knn,
    const float* __restrict__ fqg, const float* __restrict__ wp,
    const ushort* __restrict__ wqb, const float* __restrict__ gq,
    const float* __restrict__ bq, const float* __restrict__ gv,
    const float* __restrict__ bv, float* __restrict__ o1) {
  __shared__ __align__(16) float s_w[512];
  __shared__ float4 s_ctr[8];
  __shared__ __align__(16) float s_fq[8 * 68];
  __shared__ float s_gq[256];
  __shared__ float s_bq[256];
  __shared__ float4 s_rel[160];
  __shared__ float s_q[8 * 264];   // [p][h*33+d]
  __shared__ float s_e[8 * 660];   // [p][k*33+d], softmax-scaled
  __shared__ float s_a[8 * 164];   // [p][h*20+k], stride 164 (bank spread)
  float* s_out = s_e;              // alias, used after a-phase

  int t = threadIdx.x;
  int gbase = blockIdx.x * 8;
  int b = gbase >> 10;
  int n0 = gbase & 1023;

  if (t < 8) s_ctr[t] = xv[b * NPTS + n0 + t];
  for (int idx = t; idx < 512; idx += 256) {
    int p = idx >> 6, o = idx & 63;
    s_fq[p * 68 + o] = fqg[(gbase + p) * CH + o];
    s_w[idx] = wp[512 + idx];
  }
  s_gq[t] = gq[t];
  s_bq[t] = bq[t];
  {
    int p = t >> 5, kk_ = t & 31;
    if (kk_ < KNBR) {
      int nb = knn[(gbase + p) * KNBR + kk_];
      float4 nx = xv[b * NPTS + nb];
      float4 ct = xv[b * NPTS + n0 + p];
      s_rel[p * KNBR + kk_] =
          make_float4(nx.x - ct.x, nx.y - ct.y, nx.z - ct.z, nx.w - ct.w);
    }
  }
  int w = t >> 6, l = t & 63;
  int lane16 = l & 15, g = l >> 4;
  s16x8 af[4][2];
  #pragma unroll
  for (int mm = 0; mm < 4; ++mm) {
    int row = w * 64 + mm * 16 + lane16;
    af[mm][0] = *(const s16x8*)(wqb + row * 64 + g * 8);
    af[mm][1] = *(const s16x8*)(wqb + row * 64 + 32 + g * 8);
  }
  __syncthreads();

  // ---- phase 2a: q-MFMA ----
  {
    int p8 = l & 7;
    s16x8 bf[2];
    #pragma unroll
    for (int ks = 0; ks < 2; ++ks) {
      const float4* fp = (const float4*)(s_fq + p8 * 68 + ks * 32 + g * 8);
      float4 f0 = fp[0], f1 = fp[1];
      union { uint4 u; s16x8 s; } cv;
      cv.u.x = (uint)f2bf(f0.x) | ((uint)f2bf(f0.y) << 16);
      cv.u.y = (uint)f2bf(f0.z) | ((uint)f2bf(f0.w) << 16);
      cv.u.z = (uint)f2bf(f1.x) | ((uint)f2bf(f1.y) << 16);
      cv.u.w = (uint)f2bf(f1.z) | ((uint)f2bf(f1.w) << 16);
      bf[ks] = cv.s;
    }
    bool active = (lane16 < 8);
    #pragma unroll
    for (int mm = 0; mm < 4; ++mm) {
      f32x4 acc = {0.f, 0.f, 0.f, 0.f};
      acc = __builtin_amdgcn_mfma_f32_16x16x32_bf16(af[mm][0], bf[0], acc, 0, 0, 0);
      acc = __builtin_amdgcn_mfma_f32_16x16x32_bf16(af[mm][1], bf[1], acc, 0, 0, 0);
      if (active) {
        #pragma unroll
        for (int r = 0; r < 4; ++r) {
          int row = w * 64 + mm * 16 + g * 4 + r;
          float val = fmaxf(fmaf(s_gq[row], acc[r], s_bq[row]), 0.f);
          s_q[lane16 * 264 + (row >> 5) * 33 + (row & 31)] = val;
        }
      }
    }
  }

  // ---- phase 2b: ev (e scaled in-reg, v stays in regs) ----
  float vv[KNBR];
  {
    int d = t & 31, p = t >> 5;
    float4 ct = s_ctr[p];
    float4 wr = *(const float4*)(s_w + 256 + d * 4);
    float4 wc = *(const float4*)(s_w + 384 + d * 4);
    float cb = fmaf(wc.x, ct.x, fmaf(wc.y, ct.y, fmaf(wc.z, ct.z, wc.w * ct.w)));
    float ev[KNBR];
    float sum = 0.f;
    #pragma unroll
    for (int k = 0; k < KNBR; ++k) {
      float4 r = s_rel[p * KNBR + k];
      float kkv = fmaf(wr.x, r.x, fmaf(wr.y, r.y, fmaf(wr.z, r.z, fmaf(wr.w, r.w, cb))));
      ev[k] = __expf(kkv);
      sum += ev[k];
    }
    float4 vr_ = *(const float4*)(s_w + 0 + d * 4);
    float4 vc_ = *(const float4*)(s_w + 128 + d * 4);
    float cbv = fmaf(vc_.x, ct.x, fmaf(vc_.y, ct.y, fmaf(vc_.z, ct.z, vc_.w * ct.w)));
    float gvd = gv[d], bvd = bv[d];
    #pragma unroll
    for (int k = 0; k < KNBR; ++k) {
      float4 r = s_rel[p * KNBR + k];
      float raw = fmaf(vr_.x, r.x, fmaf(vr_.y, r.y, fmaf(vr_.z, r.z, fmaf(vr_.w, r.w, cbv))));
      vv[k] = fmaf(gvd, raw, bvd);
    }
    float rs = 1.0f / sum;
    #pragma unroll
    for (int k = 0; k < KNBR; ++k) s_e[p * 660 + k * 33 + d] = ev[k] * rs;
  }
  __syncthreads();

  // ---- a-phase: a[p][h][k] = sum_d q[p][h][d] * e'[p][k][d] ----
  {
    int p = t >> 5, h = (t >> 2) & 7, kh = t & 3;
    float qr[32];
    #pragma unroll
    for (int d = 0; d < 32; ++d) qr[d] = s_q[p * 264 + h * 33 + d];
    #pragma unroll
    for (int i = 0; i < 5; ++i) {
      int k = kh * 5 + i;
      float acc = 0.f;
      #pragma unroll
      for (int d = 0; d < 32; ++d) acc = fmaf(qr[d], s_e[p * 660 + k * 33 + d], acc);
      s_a[p * 164 + h * 20 + k] = acc;
    }
  }
  __syncthreads();

  // ---- out-phase: out[p][h][v] = sum_k a[p][h][k] * vv[k] (v = t&31) ----
  {
    int p = t >> 5, v = t & 31;
    #pragma unroll
    for (int h = 0; h < 8; ++h) {
      float acc = 0.f;
      #pragma unroll
      for (int k = 0; k < KNBR; ++k)
        acc = fmaf(s_a[p * 164 + h * 20 + k], vv[k], acc);
      s_out[(h * 32 + v) * 9 + p] = acc;
    }
  }
  __syncthreads();

  for (int idx = t; idx < 2048; idx += 256) {
    int hv = idx >> 3, pp = idx & 7;
    o1[b * 262144 + hv * 1024 + n0 + pp] = s_out[hv * 9 + pp];
  }
}

extern "C" void kernel_launch(void* const* d_in, const int* in_sizes, int n_in,
                              void* d_out, int out_size, void* d_ws, size_t ws_size,
                              hipStream_t stream) {
  const float* x = (const float*)d_in[0];
  const float* Wh = (const float*)d_in[1];
  const float* W1 = (const float*)d_in[2];
  const float* g1 = (const float*)d_in[3];
  const float* b1 = (const float*)d_in[4];
  const float* W2 = (const float*)d_in[5];
  const float* g2 = (const float*)d_in[6];
  const float* b2 = (const float*)d_in[7];
  const float* Wv = (const float*)d_in[8];
  const float* gv = (const float*)d_in[9];
  const float* bv = (const float*)d_in[10];
  const float* Wk = (const float*)d_in[11];
  const float* Wq = (const float*)d_in[12];
  const float* gq = (const float*)d_in[13];
  const float* bq = (const float*)d_in[14];
  float* out = (float*)d_out;

  ushort* knn = (ushort*)d_ws;
  float* fq = (float*)((char*)d_ws + 2621440);
  float* wp = (float*)((char*)d_ws + 19398656);
  ushort* w2b = (ushort*)((char*)d_ws + 19402752);
  ushort* wqb = (ushort*)((char*)d_ws + 19410944);

  hipLaunchKernelGGL(k_prep, dim3(1), dim3(256), 0, stream, Wh, W1, g1, Wv, Wk, W2,
                     Wq, wp, w2b, wqb);
  hipLaunchKernelGGL(k_knn, dim3(1024), dim3(256), 0, stream, (const float4*)x, knn,
                     (float4*)out);
  hipLaunchKernelGGL(k_fq, dim3(4096), dim3(256), 0, stream, (const float4*)x, knn,
                     wp, b1, w2b, g2, b2, fq);
  hipLaunchKernelGGL(k_attn, dim3(8192), dim3(256), 0, stream, (const float4*)x, knn,
                     fq, wp, wqb, gq, bq, gv, bv, out + 262144);
}

// Round 8
// 209.065 us; speedup vs baseline: 21.2579x; 1.3698x over previous
//
#include <hip/hip_runtime.h>
#include <math.h>

#define NPTS 1024
#define KNBR 20
#define CH 64

// ws layout (bytes), proven budget: ws_size >= 22,032,384 (used in R1/R2)
// [0, 2621440)          : knn  ushort [65536][20]
// [2621440, 19398656)   : fq   float [65536][64]
// [19398656, 19402752)  : wp   float[1024]
// [19402752, 19410944)  : W2 bf16 [64][64]
// [19410944, 19443712)  : Wq bf16 [256][64]
// [19443712, 19447808)  : w1b bf16 [64][32]  (h1 MFMA A: [g1W1r|g1W1c|b1|0..])

typedef __attribute__((ext_vector_type(8))) short s16x8;
typedef __attribute__((ext_vector_type(4))) float f32x4;

static __device__ __forceinline__ ushort f2bf(float f) {
  uint u = __float_as_uint(f);
  uint r = (u + 0x7FFFu + ((u >> 16) & 1u)) >> 16;
  return (ushort)r;
}

// pack two floats to bf16x2 (round-half-up) in 3 ops
static __device__ __forceinline__ uint pkbf(float a, float b) {
  uint ua = __float_as_uint(a) + 0x8000u;
  uint ub = __float_as_uint(b) + 0x8000u;
  return __builtin_amdgcn_perm(ub, ua, 0x07060302);
}

static __device__ __forceinline__ int mbcnt64(unsigned long long m) {
  return __builtin_amdgcn_mbcnt_hi((uint)(m >> 32),
                                   __builtin_amdgcn_mbcnt_lo((uint)m, 0));
}

__global__ __launch_bounds__(256) void k_prep(
    const float* __restrict__ Wh, const float* __restrict__ W1,
    const float* __restrict__ g1, const float* __restrict__ b1,
    const float* __restrict__ Wv, const float* __restrict__ Wk,
    const float* __restrict__ W2, const float* __restrict__ Wq,
    float* __restrict__ wp, ushort* __restrict__ w2b,
    ushort* __restrict__ wqb, ushort* __restrict__ w1b) {
  int t = threadIdx.x;
  {
    int o = t >> 2, c = t & 3;
    float acc = W1[o * 40 + c];
    #pragma unroll
    for (int v = 0; v < 32; ++v) acc = fmaf(W1[o * 40 + 8 + v], Wh[v * 4 + c], acc);
    float g = g1[o];
    wp[t] = g * acc;
    wp[256 + t] = g * W1[o * 40 + 4 + c];
  }
  if (t < 128) {
    int d = t >> 2, c = t & 3;
    float av = Wv[d * 40 + c];
    float ak = Wk[d * 40 + c];
    #pragma unroll
    for (int u = 0; u < 32; ++u) {
      av = fmaf(Wv[d * 40 + 8 + u], Wh[u * 4 + c], av);
      ak = fmaf(Wk[d * 40 + 8 + u], Wh[u * 4 + c], ak);
    }
    wp[512 + t] = av;
    wp[640 + t] = Wv[d * 40 + 4 + c];
    wp[768 + t] = ak;
    wp[896 + t] = Wk[d * 40 + 4 + c];
  }
  #pragma unroll
  for (int i = 0; i < 16; ++i) w2b[t * 16 + i] = f2bf(W2[t * 16 + i]);
  for (int i = 0; i < 64; ++i) wqb[t * 64 + i] = f2bf(Wq[t * 64 + i]);
  __syncthreads();
  // w1b[ch][32]: k0-3 = g1*W1r, k4-7 = g1*W1c, k8 = b1, rest 0
  for (int idx = t; idx < 2048; idx += 256) {
    int ch = idx >> 5, kk = idx & 31;
    float v = 0.f;
    if (kk < 4) v = wp[ch * 4 + kk];
    else if (kk < 8) v = wp[256 + ch * 4 + (kk - 4)];
    else if (kk == 8) v = b1[ch];
    w1b[idx] = f2bf(v);
  }
}

// ---------------- KNN v4: ballot radix-select, wave-per-center --------------
__global__ __launch_bounds__(256) void k_knn(const float4* __restrict__ xv,
                                             ushort* __restrict__ knn,
                                             float4* __restrict__ outx) {
  __shared__ float4 sx[NPTS];
  __shared__ float ssq[NPTS];
  __shared__ uint s_sk[4][64];
  __shared__ ushort s_sj[4][64];

  int t = threadIdx.x;
  int b = blockIdx.x >> 4, grp = blockIdx.x & 15;
  for (int j = t; j < NPTS; j += 256) {
    float4 p = xv[b * NPTS + j];
    sx[j] = p;
    ssq[j] = p.x * p.x + p.y * p.y + p.z * p.z + p.w * p.w;
    if (grp == 0) outx[b * NPTS + j] = p;  // folded k_copy (out0 = x)
  }
  __syncthreads();

  int w = t >> 6, l = t & 63;

  #pragma unroll 1
  for (int i = 0; i < 16; ++i) {
    int cloc = grp * 64 + w * 16 + i;
    int gid20 = (b * NPTS + cloc) * KNBR;
    float4 c = sx[cloc];
    uint u[16];
    uint mn = 0xFFFFFFFFu;
    #pragma unroll
    for (int s = 0; s < 16; ++s) {
      int j = s * 64 + l;
      float4 q = sx[j];
      float dot = c.x * q.x;
      dot = fmaf(c.y, q.y, dot);
      dot = fmaf(c.z, q.z, dot);
      dot = fmaf(c.w, q.w, dot);
      float key = fmaf(-2.f, dot, ssq[j]);
      uint uu = __float_as_uint(key);
      uu = ((int)uu < 0) ? ~uu : (uu | 0x80000000u);
      u[s] = uu;
      mn = min(mn, uu);
    }

    uint T0 = 0;
    #pragma unroll
    for (int bit = 31; bit >= 0; --bit) {
      uint cand = T0 | (1u << bit);
      if (__popcll(__ballot(mn < cand)) < 20) T0 = cand;
    }

    int scnt = 0;
    #pragma unroll
    for (int s = 0; s < 16; ++s) scnt += (int)__popcll(__ballot(u[s] <= T0));

    if (scnt <= 64) {
      int base = 0;
      #pragma unroll
      for (int s = 0; s < 16; ++s) {
        unsigned long long mask = __ballot(u[s] <= T0);
        if (u[s] <= T0) {
          int off = base + mbcnt64(mask);
          s_sk[w][off] = u[s];
          s_sj[w][off] = (ushort)(s * 64 + l);
        }
        base += (int)__popcll(mask);
      }
      asm volatile("s_waitcnt lgkmcnt(0)" ::: "memory");
      __builtin_amdgcn_sched_barrier(0);
      uint uk = (l < scnt) ? s_sk[w][l] : 0xFFFFFFFFu;
      uint uj = (l < scnt) ? (uint)s_sj[w][l] : 0xFFFFu;

      uint u20 = 0;
      #pragma unroll
      for (int bit = 31; bit >= 0; --bit) {
        uint cand = u20 | (1u << bit);
        if (__popcll(__ballot(uk < cand)) < 20) u20 = cand;
      }
      int m = (int)__popcll(__ballot(uk < u20));
      int r = 20 - m;
      uint jr = 0;
      #pragma unroll
      for (int bit = 10; bit >= 0; --bit) {
        uint cand = jr | (1u << bit);
        if (__popcll(__ballot((uk == u20) && (uj < cand))) < r) jr = cand;
      }
      bool sel = (uk < u20) || ((uk == u20) && (uj <= jr));
      unsigned long long smask = __ballot(sel);
      int off = mbcnt64(smask);
      if (sel) knn[gid20 + off] = (ushort)uj;
    } else {
      uint u20 = 0;
      #pragma unroll 1
      for (int bit = 31; bit >= 0; --bit) {
        uint cand = u20 | (1u << bit);
        int cnt = 0;
        #pragma unroll
        for (int s = 0; s < 16; ++s)
          cnt += (int)__popcll(__ballot(u[s] < cand));
        if (cnt < 20) u20 = cand;
      }
      int base = 0;
      #pragma unroll
      for (int s = 0; s < 16; ++s) {
        unsigned long long mask = __ballot(u[s] < u20);
        if (u[s] < u20) knn[gid20 + base + mbcnt64(mask)] = (ushort)(s * 64 + l);
        base += (int)__popcll(mask);
      }
      int r = 20 - base;
      #pragma unroll
      for (int s = 0; s < 16; ++s) {
        unsigned long long mask = __ballot(u[s] == u20);
        int pos = mbcnt64(mask);
        int cntm = (int)__popcll(mask);
        int take = (r < cntm) ? r : cntm;
        if ((u[s] == u20) && (pos < take))
          knn[gid20 + base + pos] = (ushort)(s * 64 + l);
        base += take;
        r -= take;
      }
    }
  }
}

// ---------------- fq v3: h1 AND W2 both on MFMA -----------------------------
// h1 = relu(A_h1 · [rel;ctr;1]) via 16x16x32 bf16 MFMA with K=9 (zero-pad).
// A_h1 lives in 16 VGPRs (w1b) -> no per-column weight LDS reads.
__global__ __launch_bounds__(256) void k_fq(
    const float4* __restrict__ xv, const ushort* __restrict__ knn,
    const ushort* __restrict__ w1b, const ushort* __restrict__ w2b,
    const float* __restrict__ g2, const float* __restrict__ b2,
    float* __restrict__ fq) {
  __shared__ ushort s_h1[320 * 64];            // 40960 B
  __shared__ __align__(16) ushort s_knn[320];  // 640 B
  __shared__ __align__(16) char s_relp[5120];  // [4 waves][80 cols][16 B]

  int t = threadIdx.x;
  int gid0 = blockIdx.x * 16;
  int bbase = (gid0 >> 10) << 10;

  if (t < 160) ((uint*)s_knn)[t] = ((const uint*)(knn + (size_t)gid0 * KNBR))[t];
  __syncthreads();

  int w = t >> 6, l = t & 63;
  int g = l >> 4, l16 = l & 15;

  // ---- h1 phase (MFMA) ----
  {
    s16x8 ah[4];
    #pragma unroll
    for (int m = 0; m < 4; ++m)
      ah[m] = *(const s16x8*)(w1b + (m * 16 + l16) * 32 + g * 8);

    // pack [rel, ctr] for this wave's 80 cols
    #pragma unroll
    for (int it = 0; it < 2; ++it) {
      int j = it * 64 + l;
      if (j < 80) {
        int cc = w * 80 + j;
        int kk = cc >> 4, p = cc & 15;
        int nb = (int)s_knn[p * KNBR + kk];
        float4 nx = xv[bbase + nb];
        float4 ct = xv[gid0 + p];
        uint4 pk;
        pk.x = pkbf(nx.x - ct.x, nx.y - ct.y);
        pk.y = pkbf(nx.z - ct.z, nx.w - ct.w);
        pk.z = pkbf(ct.x, ct.y);
        pk.w = pkbf(ct.z, ct.w);
        *(uint4*)(s_relp + cc * 16) = pk;
      }
    }

    s16x8 bz = {0, 0, 0, 0, 0, 0, 0, 0};
    s16x8 bone = bz;
    bone[0] = (short)0x3F80;  // bf16(1.0) at K-row 8
    #pragma unroll
    for (int q = 0; q < 5; ++q) {
      int col = w * 80 + q * 16 + l16;
      s16x8 bf;
      if (g == 0) bf = *(const s16x8*)(s_relp + col * 16);
      else bf = (g == 1) ? bone : bz;
      int swz = (col & 7) << 4;
      #pragma unroll
      for (int m = 0; m < 4; ++m) {
        f32x4 acc = {0.f, 0.f, 0.f, 0.f};
        acc = __builtin_amdgcn_mfma_f32_16x16x32_bf16(ah[m], bf, acc, 0, 0, 0);
        uint2 hv;
        hv.x = pkbf(fmaxf(acc[0], 0.f), fmaxf(acc[1], 0.f));
        hv.y = pkbf(fmaxf(acc[2], 0.f), fmaxf(acc[3], 0.f));
        int byteoff = col * 128 + (m * 16 + g * 4) * 2;
        *(uint2*)((char*)s_h1 + (byteoff ^ swz)) = hv;
      }
    }
  }
  __syncthreads();

  // ---- W2 MFMA phase: wave w owns rows w*16..w*16+15, all 20 k-tiles ----
  {
    int row0 = w * 16 + g * 4;
    s16x8 af0 = *(const s16x8*)(w2b + (w * 16 + l16) * 64 + g * 8);
    s16x8 af1 = *(const s16x8*)(w2b + (w * 16 + l16) * 64 + 32 + g * 8);
    float4 g2v = *(const float4*)(g2 + row0);
    float4 b2v = *(const float4*)(b2 + row0);
    float mx0 = 0.f, mx1 = 0.f, mx2 = 0.f, mx3 = 0.f;  // post-relu >= 0
    #pragma unroll 4
    for (int kt = 0; kt < 20; ++kt) {
      int col = kt * 16 + l16;
      int rowbyte = col * 128;
      int swz = (col & 7) << 4;
      s16x8 bf0 = *(const s16x8*)((char*)s_h1 + ((rowbyte + g * 16) ^ swz));
      s16x8 bf1 = *(const s16x8*)((char*)s_h1 + ((rowbyte + 64 + g * 16) ^ swz));
      f32x4 acc = {0.f, 0.f, 0.f, 0.f};
      acc = __builtin_amdgcn_mfma_f32_16x16x32_bf16(af0, bf0, acc, 0, 0, 0);
      acc = __builtin_amdgcn_mfma_f32_16x16x32_bf16(af1, bf1, acc, 0, 0, 0);
      mx0 = fmaxf(mx0, fmaxf(fmaf(g2v.x, acc[0], b2v.x), 0.f));
      mx1 = fmaxf(mx1, fmaxf(fmaf(g2v.y, acc[1], b2v.y), 0.f));
      mx2 = fmaxf(mx2, fmaxf(fmaf(g2v.z, acc[2], b2v.z), 0.f));
      mx3 = fmaxf(mx3, fmaxf(fmaf(g2v.w, acc[3], b2v.w), 0.f));
    }
    float4 o4 = make_float4(mx0, mx1, mx2, mx3);
    *(float4*)(fq + (size_t)(gid0 + l16) * 64 + row0) = o4;
  }
}

// ---------------- attention: v-in-regs, fused scale, 4 barriers -------------
__global__ __launch_bounds__(256) void k_attn(
    const float4* __restrict__ xv, const ushort* __restrict__ knn,
    const float* __restrict__ fqg, const float* __restrict__ wp,
    const ushort* __restrict__ wqb, const float* __restrict__ gq,
    const float* __restrict__ bq, const float* __restrict__ gv,
    const float* __restrict__ bv, float* __restrict__ o1) {
  __shared__ __align__(16) float s_w[512];
  __shared__ float4 s_ctr[8];
  __shared__ __align__(16) float s_fq[8 * 68];
  __shared__ float s_gq[256];
  __shared__ float s_bq[256];
  __shared__ float4 s_rel[160];
  __shared__ float s_q[8 * 264];   // [p][h*33+d]
  __shared__ float s_e[8 * 660];   // [p][k*33+d], softmax-scaled
  __shared__ float s_a[8 * 164];   // [p][h*20+k]
  float* s_out = s_e;

  int t = threadIdx.x;
  int gbase = blockIdx.x * 8;
  int b = gbase >> 10;
  int n0 = gbase & 1023;

  if (t < 8) s_ctr[t] = xv[b * NPTS + n0 + t];
  for (int idx = t; idx < 512; idx += 256) {
    int p = idx >> 6, o = idx & 63;
    s_fq[p * 68 + o] = fqg[(gbase + p) * CH + o];
    s_w[idx] = wp[512 + idx];
  }
  s_gq[t] = gq[t];
  s_bq[t] = bq[t];
  {
    int p = t >> 5, kk_ = t & 31;
    if (kk_ < KNBR) {
      int nb = knn[(gbase + p) * KNBR + kk_];
      float4 nx = xv[b * NPTS + nb];
      float4 ct = xv[b * NPTS + n0 + p];
      s_rel[p * KNBR + kk_] =
          make_float4(nx.x - ct.x, nx.y - ct.y, nx.z - ct.z, nx.w - ct.w);
    }
  }
  int w = t >> 6, l = t & 63;
  int lane16 = l & 15, g = l >> 4;
  s16x8 af[4][2];
  #pragma unroll
  for (int mm = 0; mm < 4; ++mm) {
    int row = w * 64 + mm * 16 + lane16;
    af[mm][0] = *(const s16x8*)(wqb + row * 64 + g * 8);
    af[mm][1] = *(const s16x8*)(wqb + row * 64 + 32 + g * 8);
  }
  __syncthreads();

  // ---- q-MFMA ----
  {
    int p8 = l & 7;
    s16x8 bf[2];
    #pragma unroll
    for (int ks = 0; ks < 2; ++ks) {
      const float4* fp = (const float4*)(s_fq + p8 * 68 + ks * 32 + g * 8);
      float4 f0 = fp[0], f1 = fp[1];
      union { uint4 u; s16x8 s; } cv;
      cv.u.x = pkbf(f0.x, f0.y);
      cv.u.y = pkbf(f0.z, f0.w);
      cv.u.z = pkbf(f1.x, f1.y);
      cv.u.w = pkbf(f1.z, f1.w);
      bf[ks] = cv.s;
    }
    bool active = (lane16 < 8);
    #pragma unroll
    for (int mm = 0; mm < 4; ++mm) {
      f32x4 acc = {0.f, 0.f, 0.f, 0.f};
      acc = __builtin_amdgcn_mfma_f32_16x16x32_bf16(af[mm][0], bf[0], acc, 0, 0, 0);
      acc = __builtin_amdgcn_mfma_f32_16x16x32_bf16(af[mm][1], bf[1], acc, 0, 0, 0);
      if (active) {
        #pragma unroll
        for (int r = 0; r < 4; ++r) {
          int row = w * 64 + mm * 16 + g * 4 + r;
          float val = fmaxf(fmaf(s_gq[row], acc[r], s_bq[row]), 0.f);
          s_q[lane16 * 264 + (row >> 5) * 33 + (row & 31)] = val;
        }
      }
    }
  }

  // ---- ev (e scaled in-reg, v stays in regs) ----
  float vv[KNBR];
  {
    int d = t & 31, p = t >> 5;
    float4 ct = s_ctr[p];
    float4 wr = *(const float4*)(s_w + 256 + d * 4);
    float4 wc = *(const float4*)(s_w + 384 + d * 4);
    float cb = fmaf(wc.x, ct.x, fmaf(wc.y, ct.y, fmaf(wc.z, ct.z, wc.w * ct.w)));
    float ev[KNBR];
    float sum = 0.f;
    #pragma unroll
    for (int k = 0; k < KNBR; ++k) {
      float4 r = s_rel[p * KNBR + k];
      float kkv = fmaf(wr.x, r.x, fmaf(wr.y, r.y, fmaf(wr.z, r.z, fmaf(wr.w, r.w, cb))));
      ev[k] = __expf(kkv);
      sum += ev[k];
    }
    float4 vr_ = *(const float4*)(s_w + 0 + d * 4);
    float4 vc_ = *(const float4*)(s_w + 128 + d * 4);
    float cbv = fmaf(vc_.x, ct.x, fmaf(vc_.y, ct.y, fmaf(vc_.z, ct.z, vc_.w * ct.w)));
    float gvd = gv[d], bvd = bv[d];
    #pragma unroll
    for (int k = 0; k < KNBR; ++k) {
      float4 r = s_rel[p * KNBR + k];
      float raw = fmaf(vr_.x, r.x, fmaf(vr_.y, r.y, fmaf(vr_.z, r.z, fmaf(vr_.w, r.w, cbv))));
      vv[k] = fmaf(gvd, raw, bvd);
    }
    float rs = 1.0f / sum;
    #pragma unroll
    for (int k = 0; k < KNBR; ++k) s_e[p * 660 + k * 33 + d] = ev[k] * rs;
  }
  __syncthreads();

  // ---- a-phase ----
  {
    int p = t >> 5, h = (t >> 2) & 7, kh = t & 3;
    float qr[32];
    #pragma unroll
    for (int d = 0; d < 32; ++d) qr[d] = s_q[p * 264 + h * 33 + d];
    #pragma unroll
    for (int i = 0; i < 5; ++i) {
      int k = kh * 5 + i;
      float acc = 0.f;
      #pragma unroll
      for (int d = 0; d < 32; ++d) acc = fmaf(qr[d], s_e[p * 660 + k * 33 + d], acc);
      s_a[p * 164 + h * 20 + k] = acc;
    }
  }
  __syncthreads();

  // ---- out-phase ----
  {
    int p = t >> 5, v = t & 31;
    #pragma unroll
    for (int h = 0; h < 8; ++h) {
      float acc = 0.f;
      #pragma unroll
      for (int k = 0; k < KNBR; ++k)
        acc = fmaf(s_a[p * 164 + h * 20 + k], vv[k], acc);
      s_out[(h * 32 + v) * 9 + p] = acc;
    }
  }
  __syncthreads();

  for (int idx = t; idx < 2048; idx += 256) {
    int hv = idx >> 3, pp = idx & 7;
    o1[b * 262144 + hv * 1024 + n0 + pp] = s_out[hv * 9 + pp];
  }
}

extern "C" void kernel_launch(void* const* d_in, const int* in_sizes, int n_in,
                              void* d_out, int out_size, void* d_ws, size_t ws_size,
                              hipStream_t stream) {
  const float* x = (const float*)d_in[0];
  const float* Wh = (const float*)d_in[1];
  const float* W1 = (const float*)d_in[2];
  const float* g1 = (const float*)d_in[3];
  const float* b1 = (const float*)d_in[4];
  const float* W2 = (const float*)d_in[5];
  const float* g2 = (const float*)d_in[6];
  const float* b2 = (const float*)d_in[7];
  const float* Wv = (const float*)d_in[8];
  const float* gv = (const float*)d_in[9];
  const float* bv = (const float*)d_in[10];
  const float* Wk = (const float*)d_in[11];
  const float* Wq = (const float*)d_in[12];
  const float* gq = (const float*)d_in[13];
  const float* bq = (const float*)d_in[14];
  float* out = (float*)d_out;

  ushort* knn = (ushort*)d_ws;
  float* fq = (float*)((char*)d_ws + 2621440);
  float* wp = (float*)((char*)d_ws + 19398656);
  ushort* w2b = (ushort*)((char*)d_ws + 19402752);
  ushort* wqb = (ushort*)((char*)d_ws + 19410944);
  ushort* w1b = (ushort*)((char*)d_ws + 19443712);

  hipLaunchKernelGGL(k_prep, dim3(1), dim3(256), 0, stream, Wh, W1, g1, b1, Wv, Wk,
                     W2, Wq, wp, w2b, wqb, w1b);
  hipLaunchKernelGGL(k_knn, dim3(1024), dim3(256), 0, stream, (const float4*)x, knn,
                     (float4*)out);
  hipLaunchKernelGGL(k_fq, dim3(4096), dim3(256), 0, stream, (const float4*)x, knn,
                     w1b, w2b, g2, b2, fq);
  hipLaunchKernelGGL(k_attn, dim3(8192), dim3(256), 0, stream, (const float4*)x, knn,
                     fq, wp, wqb, gq, bq, gv, bv, out + 262144);
}

// Round 9
// 207.933 us; speedup vs baseline: 21.3736x; 1.0054x over previous
//
#include <hip/hip_runtime.h>
#include <math.h>

#define NPTS 1024
#define KNBR 20
#define CH 64

// ws layout (bytes), proven budget: ws_size >= 22,032,384 (used in R1/R2)
// [0, 2621440)          : knn  ushort [65536][20]
// [2621440, 19398656)   : fq   float [65536][64]
// [19398656, 19402752)  : wp   float[1024]
// [19402752, 19410944)  : W2 bf16 [64][64]
// [19410944, 19443712)  : Wq bf16 [256][64]
// [19443712, 19447808)  : w1b bf16 [64][32]

typedef __attribute__((ext_vector_type(8))) short s16x8;
typedef __attribute__((ext_vector_type(4))) float f32x4;

static __device__ __forceinline__ ushort f2bf(float f) {
  uint u = __float_as_uint(f);
  uint r = (u + 0x7FFFu + ((u >> 16) & 1u)) >> 16;
  return (ushort)r;
}

// pack two floats to bf16x2 (round-half-up): low = a, high = b
static __device__ __forceinline__ uint pkbf(float a, float b) {
  uint ua = __float_as_uint(a) + 0x8000u;
  uint ub = __float_as_uint(b) + 0x8000u;
  return __builtin_amdgcn_perm(ub, ua, 0x07060302);
}

static __device__ __forceinline__ int mbcnt64(unsigned long long m) {
  return __builtin_amdgcn_mbcnt_hi((uint)(m >> 32),
                                   __builtin_amdgcn_mbcnt_lo((uint)m, 0));
}

__global__ __launch_bounds__(256) void k_prep(
    const float* __restrict__ Wh, const float* __restrict__ W1,
    const float* __restrict__ g1, const float* __restrict__ b1,
    const float* __restrict__ Wv, const float* __restrict__ Wk,
    const float* __restrict__ W2, const float* __restrict__ Wq,
    float* __restrict__ wp, ushort* __restrict__ w2b,
    ushort* __restrict__ wqb, ushort* __restrict__ w1b) {
  int t = threadIdx.x;
  {
    int o = t >> 2, c = t & 3;
    float acc = W1[o * 40 + c];
    #pragma unroll
    for (int v = 0; v < 32; ++v) acc = fmaf(W1[o * 40 + 8 + v], Wh[v * 4 + c], acc);
    float g = g1[o];
    wp[t] = g * acc;
    wp[256 + t] = g * W1[o * 40 + 4 + c];
  }
  if (t < 128) {
    int d = t >> 2, c = t & 3;
    float av = Wv[d * 40 + c];
    float ak = Wk[d * 40 + c];
    #pragma unroll
    for (int u = 0; u < 32; ++u) {
      av = fmaf(Wv[d * 40 + 8 + u], Wh[u * 4 + c], av);
      ak = fmaf(Wk[d * 40 + 8 + u], Wh[u * 4 + c], ak);
    }
    wp[512 + t] = av;
    wp[640 + t] = Wv[d * 40 + 4 + c];
    wp[768 + t] = ak;
    wp[896 + t] = Wk[d * 40 + 4 + c];
  }
  #pragma unroll
  for (int i = 0; i < 16; ++i) w2b[t * 16 + i] = f2bf(W2[t * 16 + i]);
  for (int i = 0; i < 64; ++i) wqb[t * 64 + i] = f2bf(Wq[t * 64 + i]);
  __syncthreads();
  for (int idx = t; idx < 2048; idx += 256) {
    int ch = idx >> 5, kk = idx & 31;
    float v = 0.f;
    if (kk < 4) v = wp[ch * 4 + kk];
    else if (kk < 8) v = wp[256 + ch * 4 + (kk - 4)];
    else if (kk == 8) v = b1[ch];
    w1b[idx] = f2bf(v);
  }
}

// ---------------- KNN: ballot radix-select; grid 2048 (8 centers/wave) ------
__global__ __launch_bounds__(256) void k_knn(const float4* __restrict__ xv,
                                             ushort* __restrict__ knn,
                                             float4* __restrict__ outx) {
  __shared__ float4 sx[NPTS];
  __shared__ float ssq[NPTS];
  __shared__ uint s_sk[4][64];
  __shared__ ushort s_sj[4][64];

  int t = threadIdx.x;
  int b = blockIdx.x >> 5, grp = blockIdx.x & 31;
  for (int j = t; j < NPTS; j += 256) {
    float4 p = xv[b * NPTS + j];
    sx[j] = p;
    ssq[j] = p.x * p.x + p.y * p.y + p.z * p.z + p.w * p.w;
    if (grp == 0) outx[b * NPTS + j] = p;  // folded k_copy (out0 = x)
  }
  __syncthreads();

  int w = t >> 6, l = t & 63;

  #pragma unroll 1
  for (int i = 0; i < 8; ++i) {
    int cloc = grp * 32 + w * 8 + i;
    int gid20 = (b * NPTS + cloc) * KNBR;
    float4 c = sx[cloc];
    uint u[16];
    uint mn = 0xFFFFFFFFu;
    #pragma unroll
    for (int s = 0; s < 16; ++s) {
      int j = s * 64 + l;
      float4 q = sx[j];
      float dot = c.x * q.x;
      dot = fmaf(c.y, q.y, dot);
      dot = fmaf(c.z, q.z, dot);
      dot = fmaf(c.w, q.w, dot);
      float key = fmaf(-2.f, dot, ssq[j]);
      uint uu = __float_as_uint(key);
      uu = ((int)uu < 0) ? ~uu : (uu | 0x80000000u);
      u[s] = uu;
      mn = min(mn, uu);
    }

    uint T0 = 0;
    #pragma unroll
    for (int bit = 31; bit >= 0; --bit) {
      uint cand = T0 | (1u << bit);
      if (__popcll(__ballot(mn < cand)) < 20) T0 = cand;
    }

    int scnt = 0;
    #pragma unroll
    for (int s = 0; s < 16; ++s) scnt += (int)__popcll(__ballot(u[s] <= T0));

    if (scnt <= 64) {
      int base = 0;
      #pragma unroll
      for (int s = 0; s < 16; ++s) {
        unsigned long long mask = __ballot(u[s] <= T0);
        if (u[s] <= T0) {
          int off = base + mbcnt64(mask);
          s_sk[w][off] = u[s];
          s_sj[w][off] = (ushort)(s * 64 + l);
        }
        base += (int)__popcll(mask);
      }
      asm volatile("s_waitcnt lgkmcnt(0)" ::: "memory");
      __builtin_amdgcn_sched_barrier(0);
      uint uk = (l < scnt) ? s_sk[w][l] : 0xFFFFFFFFu;
      uint uj = (l < scnt) ? (uint)s_sj[w][l] : 0xFFFFu;

      uint u20 = 0;
      #pragma unroll
      for (int bit = 31; bit >= 0; --bit) {
        uint cand = u20 | (1u << bit);
        if (__popcll(__ballot(uk < cand)) < 20) u20 = cand;
      }
      int m = (int)__popcll(__ballot(uk < u20));
      int r = 20 - m;
      uint jr = 0;
      #pragma unroll
      for (int bit = 10; bit >= 0; --bit) {
        uint cand = jr | (1u << bit);
        if (__popcll(__ballot((uk == u20) && (uj < cand))) < r) jr = cand;
      }
      bool sel = (uk < u20) || ((uk == u20) && (uj <= jr));
      unsigned long long smask = __ballot(sel);
      int off = mbcnt64(smask);
      if (sel) knn[gid20 + off] = (ushort)uj;
    } else {
      uint u20 = 0;
      #pragma unroll 1
      for (int bit = 31; bit >= 0; --bit) {
        uint cand = u20 | (1u << bit);
        int cnt = 0;
        #pragma unroll
        for (int s = 0; s < 16; ++s)
          cnt += (int)__popcll(__ballot(u[s] < cand));
        if (cnt < 20) u20 = cand;
      }
      int base = 0;
      #pragma unroll
      for (int s = 0; s < 16; ++s) {
        unsigned long long mask = __ballot(u[s] < u20);
        if (u[s] < u20) knn[gid20 + base + mbcnt64(mask)] = (ushort)(s * 64 + l);
        base += (int)__popcll(mask);
      }
      int r = 20 - base;
      #pragma unroll
      for (int s = 0; s < 16; ++s) {
        unsigned long long mask = __ballot(u[s] == u20);
        int pos = mbcnt64(mask);
        int cntm = (int)__popcll(mask);
        int take = (r < cntm) ? r : cntm;
        if ((u[s] == u20) && (pos < take))
          knn[gid20 + base + pos] = (ushort)(s * 64 + l);
        base += take;
        r -= take;
      }
    }
  }
}

// ---------------- fq v3: h1 AND W2 both on MFMA (unchanged) -----------------
__global__ __launch_bounds__(256) void k_fq(
    const float4* __restrict__ xv, const ushort* __restrict__ knn,
    const ushort* __restrict__ w1b, const ushort* __restrict__ w2b,
    const float* __restrict__ g2, const float* __restrict__ b2,
    float* __restrict__ fq) {
  __shared__ ushort s_h1[320 * 64];
  __shared__ __align__(16) ushort s_knn[320];
  __shared__ __align__(16) char s_relp[5120];

  int t = threadIdx.x;
  int gid0 = blockIdx.x * 16;
  int bbase = (gid0 >> 10) << 10;

  if (t < 160) ((uint*)s_knn)[t] = ((const uint*)(knn + (size_t)gid0 * KNBR))[t];
  __syncthreads();

  int w = t >> 6, l = t & 63;
  int g = l >> 4, l16 = l & 15;

  {
    s16x8 ah[4];
    #pragma unroll
    for (int m = 0; m < 4; ++m)
      ah[m] = *(const s16x8*)(w1b + (m * 16 + l16) * 32 + g * 8);

    #pragma unroll
    for (int it = 0; it < 2; ++it) {
      int j = it * 64 + l;
      if (j < 80) {
        int cc = w * 80 + j;
        int kk = cc >> 4, p = cc & 15;
        int nb = (int)s_knn[p * KNBR + kk];
        float4 nx = xv[bbase + nb];
        float4 ct = xv[gid0 + p];
        uint4 pk;
        pk.x = pkbf(nx.x - ct.x, nx.y - ct.y);
        pk.y = pkbf(nx.z - ct.z, nx.w - ct.w);
        pk.z = pkbf(ct.x, ct.y);
        pk.w = pkbf(ct.z, ct.w);
        *(uint4*)(s_relp + cc * 16) = pk;
      }
    }

    s16x8 bz = {0, 0, 0, 0, 0, 0, 0, 0};
    s16x8 bone = bz;
    bone[0] = (short)0x3F80;
    #pragma unroll
    for (int q = 0; q < 5; ++q) {
      int col = w * 80 + q * 16 + l16;
      s16x8 bf;
      if (g == 0) bf = *(const s16x8*)(s_relp + col * 16);
      else bf = (g == 1) ? bone : bz;
      int swz = (col & 7) << 4;
      #pragma unroll
      for (int m = 0; m < 4; ++m) {
        f32x4 acc = {0.f, 0.f, 0.f, 0.f};
        acc = __builtin_amdgcn_mfma_f32_16x16x32_bf16(ah[m], bf, acc, 0, 0, 0);
        uint2 hv;
        hv.x = pkbf(fmaxf(acc[0], 0.f), fmaxf(acc[1], 0.f));
        hv.y = pkbf(fmaxf(acc[2], 0.f), fmaxf(acc[3], 0.f));
        int byteoff = col * 128 + (m * 16 + g * 4) * 2;
        *(uint2*)((char*)s_h1 + (byteoff ^ swz)) = hv;
      }
    }
  }
  __syncthreads();

  {
    int row0 = w * 16 + g * 4;
    s16x8 af0 = *(const s16x8*)(w2b + (w * 16 + l16) * 64 + g * 8);
    s16x8 af1 = *(const s16x8*)(w2b + (w * 16 + l16) * 64 + 32 + g * 8);
    float4 g2v = *(const float4*)(g2 + row0);
    float4 b2v = *(const float4*)(b2 + row0);
    float mx0 = 0.f, mx1 = 0.f, mx2 = 0.f, mx3 = 0.f;
    #pragma unroll 4
    for (int kt = 0; kt < 20; ++kt) {
      int col = kt * 16 + l16;
      int rowbyte = col * 128;
      int swz = (col & 7) << 4;
      s16x8 bf0 = *(const s16x8*)((char*)s_h1 + ((rowbyte + g * 16) ^ swz));
      s16x8 bf1 = *(const s16x8*)((char*)s_h1 + ((rowbyte + 64 + g * 16) ^ swz));
      f32x4 acc = {0.f, 0.f, 0.f, 0.f};
      acc = __builtin_amdgcn_mfma_f32_16x16x32_bf16(af0, bf0, acc, 0, 0, 0);
      acc = __builtin_amdgcn_mfma_f32_16x16x32_bf16(af1, bf1, acc, 0, 0, 0);
      mx0 = fmaxf(mx0, fmaxf(fmaf(g2v.x, acc[0], b2v.x), 0.f));
      mx1 = fmaxf(mx1, fmaxf(fmaf(g2v.y, acc[1], b2v.y), 0.f));
      mx2 = fmaxf(mx2, fmaxf(fmaf(g2v.z, acc[2], b2v.z), 0.f));
      mx3 = fmaxf(mx3, fmaxf(fmaf(g2v.w, acc[3], b2v.w), 0.f));
    }
    float4 o4 = make_float4(mx0, mx1, mx2, mx3);
    *(float4*)(fq + (size_t)(gid0 + l16) * 64 + row0) = o4;
  }
}

// ---------------- attention v3: q, a, out ALL on MFMA -----------------------
// wave w owns points {2w, 2w+1}. bf16 LDS tiles, 40-ushort strides.
__global__ __launch_bounds__(256) void k_attn(
    const float4* __restrict__ xv, const ushort* __restrict__ knn,
    const float* __restrict__ fqg, const float* __restrict__ wp,
    const ushort* __restrict__ wqb, const float* __restrict__ gq,
    const float* __restrict__ bq, const float* __restrict__ gv,
    const float* __restrict__ bv, float* __restrict__ o1) {
  __shared__ float4 s_ctr[8];
  __shared__ float4 s_rel[160];
  __shared__ __align__(16) ushort s_qb[8 * 328];      // [p]*328 + h*40 + d
  __shared__ __align__(16) ushort s_eb[8 * 20 * 40];  // [p][k][d]
  __shared__ __align__(16) ushort s_vb[8 * 32 * 40];  // [p][v][k]
  __shared__ __align__(16) ushort s_ab[8][8][40];     // [p][h][k]
  float* s_out = (float*)s_eb;                        // alias after a-MFMA

  int t = threadIdx.x;
  int gbase = blockIdx.x * 8;
  int b = gbase >> 10;
  int n0 = gbase & 1023;
  int w = t >> 6, l = t & 63;
  int lane16 = l & 15, g = l >> 4;

  // ---- stage ----
  if (t < 8) s_ctr[t] = xv[b * NPTS + n0 + t];
  {
    int p = t >> 5, kk_ = t & 31;
    if (kk_ < KNBR) {
      int nb = knn[(gbase + p) * KNBR + kk_];
      float4 nx = xv[b * NPTS + nb];
      float4 ct = xv[b * NPTS + n0 + p];
      s_rel[p * KNBR + kk_] =
          make_float4(nx.x - ct.x, nx.y - ct.y, nx.z - ct.z, nx.w - ct.w);
    }
  }
  s16x8 af[4][2];
  #pragma unroll
  for (int mm = 0; mm < 4; ++mm) {
    int row = w * 64 + mm * 16 + lane16;
    af[mm][0] = *(const s16x8*)(wqb + row * 64 + g * 8);
    af[mm][1] = *(const s16x8*)(wqb + row * 64 + 32 + g * 8);
  }
  __syncthreads();

  // ---- q-MFMA -> s_qb bf16 ----
  {
    int p8 = l & 7;
    const float4* fqp = (const float4*)(fqg + (size_t)(gbase + p8) * CH);
    s16x8 bf[2];
    #pragma unroll
    for (int ks = 0; ks < 2; ++ks) {
      float4 f0 = fqp[ks * 8 + g * 2];
      float4 f1 = fqp[ks * 8 + g * 2 + 1];
      union { uint4 u; s16x8 s; } cv;
      cv.u.x = pkbf(f0.x, f0.y);
      cv.u.y = pkbf(f0.z, f0.w);
      cv.u.z = pkbf(f1.x, f1.y);
      cv.u.w = pkbf(f1.z, f1.w);
      bf[ks] = cv.s;
    }
    bool active = (lane16 < 8);
    #pragma unroll
    for (int mm = 0; mm < 4; ++mm) {
      f32x4 acc = {0.f, 0.f, 0.f, 0.f};
      acc = __builtin_amdgcn_mfma_f32_16x16x32_bf16(af[mm][0], bf[0], acc, 0, 0, 0);
      acc = __builtin_amdgcn_mfma_f32_16x16x32_bf16(af[mm][1], bf[1], acc, 0, 0, 0);
      if (active) {
        int rbase = w * 64 + mm * 16 + g * 4;
        int h = rbase >> 5, d0 = rbase & 31;
        float4 gqv = *(const float4*)(gq + rbase);
        float4 bqv = *(const float4*)(bq + rbase);
        float v0 = fmaxf(fmaf(gqv.x, acc[0], bqv.x), 0.f);
        float v1 = fmaxf(fmaf(gqv.y, acc[1], bqv.y), 0.f);
        float v2 = fmaxf(fmaf(gqv.z, acc[2], bqv.z), 0.f);
        float v3 = fmaxf(fmaf(gqv.w, acc[3], bqv.w), 0.f);
        uint2 u2;
        u2.x = pkbf(v0, v1);
        u2.y = pkbf(v2, v3);
        *(uint2*)(s_qb + lane16 * 328 + h * 40 + d0) = u2;
      }
    }
  }

  // ---- ev-phase: thread (p,d); e' and vv -> bf16 LDS ----
  {
    int d = t & 31, p = t >> 5;
    float4 ct = s_ctr[p];
    float4 wr = *(const float4*)(wp + 512 + 256 + d * 4);  // Wkr
    float4 wc = *(const float4*)(wp + 512 + 384 + d * 4);  // Wkc
    float cb = fmaf(wc.x, ct.x, fmaf(wc.y, ct.y, fmaf(wc.z, ct.z, wc.w * ct.w)));
    float ev[KNBR];
    float sum = 0.f;
    #pragma unroll
    for (int k = 0; k < KNBR; ++k) {
      float4 r = s_rel[p * KNBR + k];
      float kkv = fmaf(wr.x, r.x, fmaf(wr.y, r.y, fmaf(wr.z, r.z, fmaf(wr.w, r.w, cb))));
      ev[k] = __expf(kkv);
      sum += ev[k];
    }
    float4 vr_ = *(const float4*)(wp + 512 + 0 + d * 4);    // Wvr
    float4 vc_ = *(const float4*)(wp + 512 + 128 + d * 4);  // Wvc
    float cbv = fmaf(vc_.x, ct.x, fmaf(vc_.y, ct.y, fmaf(vc_.z, ct.z, vc_.w * ct.w)));
    float gvd = gv[d], bvd = bv[d];
    float vv[KNBR];
    #pragma unroll
    for (int k = 0; k < KNBR; ++k) {
      float4 r = s_rel[p * KNBR + k];
      float raw = fmaf(vr_.x, r.x, fmaf(vr_.y, r.y, fmaf(vr_.z, r.z, fmaf(vr_.w, r.w, cbv))));
      vv[k] = fmaf(gvd, raw, bvd);
    }
    float rs = 1.0f / sum;
    #pragma unroll
    for (int k = 0; k < KNBR; ++k)
      s_eb[(p * KNBR + k) * 40 + d] = f2bf(ev[k] * rs);
    uint* vrow = (uint*)(s_vb + (p * 32 + d) * 40);
    #pragma unroll
    for (int k2 = 0; k2 < 10; ++k2) vrow[k2] = pkbf(vv[k2 * 2], vv[k2 * 2 + 1]);
    #pragma unroll
    for (int k2 = 10; k2 < 16; ++k2) vrow[k2] = 0u;  // zero-pad k 20..31
  }
  __syncthreads();

  // ---- a-MFMA: a[h,k] = sum_d q[h,d] e'[k,d]; 2 points x 2 k-tiles ----
  #pragma unroll
  for (int pi2 = 0; pi2 < 2; ++pi2) {
    int pi = 2 * w + pi2;
    s16x8 qa = *(const s16x8*)(s_qb + pi * 328 + (lane16 & 7) * 40 + g * 8);
    #pragma unroll
    for (int tile = 0; tile < 2; ++tile) {
      int k = tile * 16 + lane16;
      int kc = (k < KNBR) ? k : (KNBR - 1);
      s16x8 eb = *(const s16x8*)(s_eb + (pi * KNBR + kc) * 40 + g * 8);
      f32x4 acc = {0.f, 0.f, 0.f, 0.f};
      acc = __builtin_amdgcn_mfma_f32_16x16x32_bf16(qa, eb, acc, 0, 0, 0);
      if (g < 2) {
        if (k < KNBR) {
          #pragma unroll
          for (int r = 0; r < 4; ++r)
            s_ab[pi][g * 4 + r][k] = f2bf(acc[r]);
        } else {
          #pragma unroll
          for (int r = 0; r < 4; ++r) s_ab[pi][g * 4 + r][k] = 0;  // k 20..31
        }
      }
    }
  }
  __syncthreads();

  // ---- out-MFMA: out[h,v] = sum_k a[h,k] vv[k,v]; 2 points x 2 v-tiles ----
  #pragma unroll
  for (int pi2 = 0; pi2 < 2; ++pi2) {
    int pi = 2 * w + pi2;
    s16x8 aa = *(const s16x8*)(&s_ab[pi][lane16 & 7][g * 8]);
    #pragma unroll
    for (int vt = 0; vt < 2; ++vt) {
      int v = vt * 16 + lane16;
      s16x8 vb = *(const s16x8*)(s_vb + (pi * 32 + v) * 40 + g * 8);
      f32x4 acc = {0.f, 0.f, 0.f, 0.f};
      acc = __builtin_amdgcn_mfma_f32_16x16x32_bf16(aa, vb, acc, 0, 0, 0);
      if (g < 2) {
        #pragma unroll
        for (int r = 0; r < 4; ++r) {
          int h = g * 4 + r;
          s_out[(h * 32 + v) * 9 + pi] = acc[r];
        }
      }
    }
  }
  __syncthreads();

  for (int idx = t; idx < 2048; idx += 256) {
    int hv = idx >> 3, pp = idx & 7;
    o1[b * 262144 + hv * 1024 + n0 + pp] = s_out[hv * 9 + pp];
  }
}

extern "C" void kernel_launch(void* const* d_in, const int* in_sizes, int n_in,
                              void* d_out, int out_size, void* d_ws, size_t ws_size,
                              hipStream_t stream) {
  const float* x = (const float*)d_in[0];
  const float* Wh = (const float*)d_in[1];
  const float* W1 = (const float*)d_in[2];
  const float* g1 = (const float*)d_in[3];
  const float* b1 = (const float*)d_in[4];
  const float* W2 = (const float*)d_in[5];
  const float* g2 = (const float*)d_in[6];
  const float* b2 = (const float*)d_in[7];
  const float* Wv = (const float*)d_in[8];
  const float* gv = (const float*)d_in[9];
  const float* bv = (const float*)d_in[10];
  const float* Wk = (const float*)d_in[11];
  const float* Wq = (const float*)d_in[12];
  const float* gq = (const float*)d_in[13];
  const float* bq = (const float*)d_in[14];
  float* out = (float*)d_out;

  ushort* knn = (ushort*)d_ws;
  float* fq = (float*)((char*)d_ws + 2621440);
  float* wp = (float*)((char*)d_ws + 19398656);
  ushort* w2b = (ushort*)((char*)d_ws + 19402752);
  ushort* wqb = (ushort*)((char*)d_ws + 19410944);
  ushort* w1b = (ushort*)((char*)d_ws + 19443712);

  hipLaunchKernelGGL(k_prep, dim3(1), dim3(256), 0, stream, Wh, W1, g1, b1, Wv, Wk,
                     W2, Wq, wp, w2b, wqb, w1b);
  hipLaunchKernelGGL(k_knn, dim3(2048), dim3(256), 0, stream, (const float4*)x, knn,
                     (float4*)out);
  hipLaunchKernelGGL(k_fq, dim3(4096), dim3(256), 0, stream, (const float4*)x, knn,
                     w1b, w2b, g2, b2, fq);
  hipLaunchKernelGGL(k_attn, dim3(8192), dim3(256), 0, stream, (const float4*)x, knn,
                     fq, wp, wqb, gq, bq, gv, bv, out + 262144);
}

// Round 10
// 202.394 us; speedup vs baseline: 21.9586x; 1.0274x over previous
//
#include <hip/hip_runtime.h>
#include <math.h>

#define NPTS 1024
#define KNBR 20
#define CH 64

// ws layout (bytes), proven budget: ws_size >= 22,032,384 (used in R1/R2)
// [0, 2621440)          : knn  ushort [65536][20]
// [2621440, 19398656)   : fq   float [65536][64]
// [19398656, 19402752)  : wp   float[1024]
// [19402752, 19410944)  : W2 bf16 [64][64]
// [19410944, 19443712)  : Wq bf16 [256][64]
// [19443712, 19447808)  : w1b bf16 [64][32]

typedef __attribute__((ext_vector_type(8))) short s16x8;
typedef __attribute__((ext_vector_type(4))) float f32x4;

static __device__ __forceinline__ ushort f2bf(float f) {
  uint u = __float_as_uint(f);
  uint r = (u + 0x7FFFu + ((u >> 16) & 1u)) >> 16;
  return (ushort)r;
}

// pack two floats to bf16x2 (round-half-up): low = a, high = b
static __device__ __forceinline__ uint pkbf(float a, float b) {
  uint ua = __float_as_uint(a) + 0x8000u;
  uint ub = __float_as_uint(b) + 0x8000u;
  return __builtin_amdgcn_perm(ub, ua, 0x07060302);
}

static __device__ __forceinline__ int mbcnt64(unsigned long long m) {
  return __builtin_amdgcn_mbcnt_hi((uint)(m >> 32),
                                   __builtin_amdgcn_mbcnt_lo((uint)m, 0));
}

__global__ __launch_bounds__(256) void k_prep(
    const float* __restrict__ Wh, const float* __restrict__ W1,
    const float* __restrict__ g1, const float* __restrict__ b1,
    const float* __restrict__ Wv, const float* __restrict__ Wk,
    const float* __restrict__ W2, const float* __restrict__ Wq,
    float* __restrict__ wp, ushort* __restrict__ w2b,
    ushort* __restrict__ wqb, ushort* __restrict__ w1b) {
  int t = threadIdx.x;
  {
    int o = t >> 2, c = t & 3;
    float acc = W1[o * 40 + c];
    #pragma unroll
    for (int v = 0; v < 32; ++v) acc = fmaf(W1[o * 40 + 8 + v], Wh[v * 4 + c], acc);
    float g = g1[o];
    wp[t] = g * acc;
    wp[256 + t] = g * W1[o * 40 + 4 + c];
  }
  if (t < 128) {
    int d = t >> 2, c = t & 3;
    float av = Wv[d * 40 + c];
    float ak = Wk[d * 40 + c];
    #pragma unroll
    for (int u = 0; u < 32; ++u) {
      av = fmaf(Wv[d * 40 + 8 + u], Wh[u * 4 + c], av);
      ak = fmaf(Wk[d * 40 + 8 + u], Wh[u * 4 + c], ak);
    }
    wp[512 + t] = av;
    wp[640 + t] = Wv[d * 40 + 4 + c];
    wp[768 + t] = ak;
    wp[896 + t] = Wk[d * 40 + 4 + c];
  }
  #pragma unroll
  for (int i = 0; i < 16; ++i) w2b[t * 16 + i] = f2bf(W2[t * 16 + i]);
  for (int i = 0; i < 64; ++i) wqb[t * 64 + i] = f2bf(Wq[t * 64 + i]);
  __syncthreads();
  for (int idx = t; idx < 2048; idx += 256) {
    int ch = idx >> 5, kk = idx & 31;
    float v = 0.f;
    if (kk < 4) v = wp[ch * 4 + kk];
    else if (kk < 8) v = wp[256 + ch * 4 + (kk - 4)];
    else if (kk == 8) v = b1[ch];
    w1b[idx] = f2bf(v);
  }
}

// ---------------- KNN: ballot radix-select; grid 2048 -----------------------
__global__ __launch_bounds__(256) void k_knn(const float4* __restrict__ xv,
                                             ushort* __restrict__ knn,
                                             float4* __restrict__ outx) {
  __shared__ float4 sx[NPTS];
  __shared__ float ssq[NPTS];
  __shared__ uint s_sk[4][64];
  __shared__ ushort s_sj[4][64];

  int t = threadIdx.x;
  int b = blockIdx.x >> 5, grp = blockIdx.x & 31;
  for (int j = t; j < NPTS; j += 256) {
    float4 p = xv[b * NPTS + j];
    sx[j] = p;
    ssq[j] = p.x * p.x + p.y * p.y + p.z * p.z + p.w * p.w;
    if (grp == 0) outx[b * NPTS + j] = p;  // folded k_copy (out0 = x)
  }
  __syncthreads();

  int w = t >> 6, l = t & 63;

  #pragma unroll 1
  for (int i = 0; i < 8; ++i) {
    int cloc = grp * 32 + w * 8 + i;
    int gid20 = (b * NPTS + cloc) * KNBR;
    float4 c = sx[cloc];
    uint u[16];
    uint mn = 0xFFFFFFFFu;
    #pragma unroll
    for (int s = 0; s < 16; ++s) {
      int j = s * 64 + l;
      float4 q = sx[j];
      float dot = c.x * q.x;
      dot = fmaf(c.y, q.y, dot);
      dot = fmaf(c.z, q.z, dot);
      dot = fmaf(c.w, q.w, dot);
      float key = fmaf(-2.f, dot, ssq[j]);
      uint uu = __float_as_uint(key);
      uu = ((int)uu < 0) ? ~uu : (uu | 0x80000000u);
      u[s] = uu;
      mn = min(mn, uu);
    }

    uint T0 = 0;
    #pragma unroll
    for (int bit = 31; bit >= 0; --bit) {
      uint cand = T0 | (1u << bit);
      if (__popcll(__ballot(mn < cand)) < 20) T0 = cand;
    }

    int scnt = 0;
    #pragma unroll
    for (int s = 0; s < 16; ++s) scnt += (int)__popcll(__ballot(u[s] <= T0));

    if (scnt <= 64) {
      int base = 0;
      #pragma unroll
      for (int s = 0; s < 16; ++s) {
        unsigned long long mask = __ballot(u[s] <= T0);
        if (u[s] <= T0) {
          int off = base + mbcnt64(mask);
          s_sk[w][off] = u[s];
          s_sj[w][off] = (ushort)(s * 64 + l);
        }
        base += (int)__popcll(mask);
      }
      asm volatile("s_waitcnt lgkmcnt(0)" ::: "memory");
      __builtin_amdgcn_sched_barrier(0);
      uint uk = (l < scnt) ? s_sk[w][l] : 0xFFFFFFFFu;
      uint uj = (l < scnt) ? (uint)s_sj[w][l] : 0xFFFFu;

      uint u20 = 0;
      #pragma unroll
      for (int bit = 31; bit >= 0; --bit) {
        uint cand = u20 | (1u << bit);
        if (__popcll(__ballot(uk < cand)) < 20) u20 = cand;
      }
      int m = (int)__popcll(__ballot(uk < u20));
      int r = 20 - m;
      uint jr = 0;
      #pragma unroll
      for (int bit = 10; bit >= 0; --bit) {
        uint cand = jr | (1u << bit);
        if (__popcll(__ballot((uk == u20) && (uj < cand))) < r) jr = cand;
      }
      bool sel = (uk < u20) || ((uk == u20) && (uj <= jr));
      unsigned long long smask = __ballot(sel);
      int off = mbcnt64(smask);
      if (sel) knn[gid20 + off] = (ushort)uj;
    } else {
      uint u20 = 0;
      #pragma unroll 1
      for (int bit = 31; bit >= 0; --bit) {
        uint cand = u20 | (1u << bit);
        int cnt = 0;
        #pragma unroll
        for (int s = 0; s < 16; ++s)
          cnt += (int)__popcll(__ballot(u[s] < cand));
        if (cnt < 20) u20 = cand;
      }
      int base = 0;
      #pragma unroll
      for (int s = 0; s < 16; ++s) {
        unsigned long long mask = __ballot(u[s] < u20);
        if (u[s] < u20) knn[gid20 + base + mbcnt64(mask)] = (ushort)(s * 64 + l);
        base += (int)__popcll(mask);
      }
      int r = 20 - base;
      #pragma unroll
      for (int s = 0; s < 16; ++s) {
        unsigned long long mask = __ballot(u[s] == u20);
        int pos = mbcnt64(mask);
        int cntm = (int)__popcll(mask);
        int take = (r < cntm) ? r : cntm;
        if ((u[s] == u20) && (pos < take))
          knn[gid20 + base + pos] = (ushort)(s * 64 + l);
        base += take;
        r -= take;
      }
    }
  }
}

// ---------------- fq v3: h1 AND W2 both on MFMA (unchanged) -----------------
__global__ __launch_bounds__(256) void k_fq(
    const float4* __restrict__ xv, const ushort* __restrict__ knn,
    const ushort* __restrict__ w1b, const ushort* __restrict__ w2b,
    const float* __restrict__ g2, const float* __restrict__ b2,
    float* __restrict__ fq) {
  __shared__ ushort s_h1[320 * 64];
  __shared__ __align__(16) ushort s_knn[320];
  __shared__ __align__(16) char s_relp[5120];

  int t = threadIdx.x;
  int gid0 = blockIdx.x * 16;
  int bbase = (gid0 >> 10) << 10;

  if (t < 160) ((uint*)s_knn)[t] = ((const uint*)(knn + (size_t)gid0 * KNBR))[t];
  __syncthreads();

  int w = t >> 6, l = t & 63;
  int g = l >> 4, l16 = l & 15;

  {
    s16x8 ah[4];
    #pragma unroll
    for (int m = 0; m < 4; ++m)
      ah[m] = *(const s16x8*)(w1b + (m * 16 + l16) * 32 + g * 8);

    #pragma unroll
    for (int it = 0; it < 2; ++it) {
      int j = it * 64 + l;
      if (j < 80) {
        int cc = w * 80 + j;
        int kk = cc >> 4, p = cc & 15;
        int nb = (int)s_knn[p * KNBR + kk];
        float4 nx = xv[bbase + nb];
        float4 ct = xv[gid0 + p];
        uint4 pk;
        pk.x = pkbf(nx.x - ct.x, nx.y - ct.y);
        pk.y = pkbf(nx.z - ct.z, nx.w - ct.w);
        pk.z = pkbf(ct.x, ct.y);
        pk.w = pkbf(ct.z, ct.w);
        *(uint4*)(s_relp + cc * 16) = pk;
      }
    }

    s16x8 bz = {0, 0, 0, 0, 0, 0, 0, 0};
    s16x8 bone = bz;
    bone[0] = (short)0x3F80;
    #pragma unroll
    for (int q = 0; q < 5; ++q) {
      int col = w * 80 + q * 16 + l16;
      s16x8 bf;
      if (g == 0) bf = *(const s16x8*)(s_relp + col * 16);
      else bf = (g == 1) ? bone : bz;
      int swz = (col & 7) << 4;
      #pragma unroll
      for (int m = 0; m < 4; ++m) {
        f32x4 acc = {0.f, 0.f, 0.f, 0.f};
        acc = __builtin_amdgcn_mfma_f32_16x16x32_bf16(ah[m], bf, acc, 0, 0, 0);
        uint2 hv;
        hv.x = pkbf(fmaxf(acc[0], 0.f), fmaxf(acc[1], 0.f));
        hv.y = pkbf(fmaxf(acc[2], 0.f), fmaxf(acc[3], 0.f));
        int byteoff = col * 128 + (m * 16 + g * 4) * 2;
        *(uint2*)((char*)s_h1 + (byteoff ^ swz)) = hv;
      }
    }
  }
  __syncthreads();

  {
    int row0 = w * 16 + g * 4;
    s16x8 af0 = *(const s16x8*)(w2b + (w * 16 + l16) * 64 + g * 8);
    s16x8 af1 = *(const s16x8*)(w2b + (w * 16 + l16) * 64 + 32 + g * 8);
    float4 g2v = *(const float4*)(g2 + row0);
    float4 b2v = *(const float4*)(b2 + row0);
    float mx0 = 0.f, mx1 = 0.f, mx2 = 0.f, mx3 = 0.f;
    #pragma unroll 4
    for (int kt = 0; kt < 20; ++kt) {
      int col = kt * 16 + l16;
      int rowbyte = col * 128;
      int swz = (col & 7) << 4;
      s16x8 bf0 = *(const s16x8*)((char*)s_h1 + ((rowbyte + g * 16) ^ swz));
      s16x8 bf1 = *(const s16x8*)((char*)s_h1 + ((rowbyte + 64 + g * 16) ^ swz));
      f32x4 acc = {0.f, 0.f, 0.f, 0.f};
      acc = __builtin_amdgcn_mfma_f32_16x16x32_bf16(af0, bf0, acc, 0, 0, 0);
      acc = __builtin_amdgcn_mfma_f32_16x16x32_bf16(af1, bf1, acc, 0, 0, 0);
      mx0 = fmaxf(mx0, fmaxf(fmaf(g2v.x, acc[0], b2v.x), 0.f));
      mx1 = fmaxf(mx1, fmaxf(fmaf(g2v.y, acc[1], b2v.y), 0.f));
      mx2 = fmaxf(mx2, fmaxf(fmaf(g2v.z, acc[2], b2v.z), 0.f));
      mx3 = fmaxf(mx3, fmaxf(fmaf(g2v.w, acc[3], b2v.w), 0.f));
    }
    float4 o4 = make_float4(mx0, mx1, mx2, mx3);
    *(float4*)(fq + (size_t)(gid0 + l16) * 64 + row0) = o4;
  }
}

// ---------------- attention v4: s_vb deleted -> vv via ds_bpermute ----------
// LDS ~25.9KB -> 6 blocks/CU by LDS. MFMA layouts unchanged from R9 (verified).
__global__ __launch_bounds__(256) void k_attn(
    const float4* __restrict__ xv, const ushort* __restrict__ knn,
    const float* __restrict__ fqg, const float* __restrict__ wp,
    const ushort* __restrict__ wqb, const float* __restrict__ gq,
    const float* __restrict__ bq, const float* __restrict__ gv,
    const float* __restrict__ bv, float* __restrict__ o1) {
  __shared__ float4 s_ctr[8];
  __shared__ float4 s_rel[160];
  __shared__ __align__(16) ushort s_qb[8 * 328];      // [p]*328 + h*40 + d
  __shared__ __align__(16) ushort s_eb[8 * 20 * 40];  // [p][k][d]
  __shared__ __align__(16) ushort s_ab[8][8][40];     // [p][h][k]
  float* s_out = (float*)s_eb;                        // alias after a-MFMA

  int t = threadIdx.x;
  int gbase = blockIdx.x * 8;
  int b = gbase >> 10;
  int n0 = gbase & 1023;
  int w = t >> 6, l = t & 63;
  int lane16 = l & 15, g = l >> 4;

  // ---- stage ----
  if (t < 8) s_ctr[t] = xv[b * NPTS + n0 + t];
  {
    int p = t >> 5, kk_ = t & 31;
    if (kk_ < KNBR) {
      int nb = knn[(gbase + p) * KNBR + kk_];
      float4 nx = xv[b * NPTS + nb];
      float4 ct = xv[b * NPTS + n0 + p];
      s_rel[p * KNBR + kk_] =
          make_float4(nx.x - ct.x, nx.y - ct.y, nx.z - ct.z, nx.w - ct.w);
    }
  }
  s16x8 af[4][2];
  #pragma unroll
  for (int mm = 0; mm < 4; ++mm) {
    int row = w * 64 + mm * 16 + lane16;
    af[mm][0] = *(const s16x8*)(wqb + row * 64 + g * 8);
    af[mm][1] = *(const s16x8*)(wqb + row * 64 + 32 + g * 8);
  }
  __syncthreads();

  // ---- q-MFMA -> s_qb bf16 ----
  {
    int p8 = l & 7;
    const float4* fqp = (const float4*)(fqg + (size_t)(gbase + p8) * CH);
    s16x8 bf[2];
    #pragma unroll
    for (int ks = 0; ks < 2; ++ks) {
      float4 f0 = fqp[ks * 8 + g * 2];
      float4 f1 = fqp[ks * 8 + g * 2 + 1];
      union { uint4 u; s16x8 s; } cv;
      cv.u.x = pkbf(f0.x, f0.y);
      cv.u.y = pkbf(f0.z, f0.w);
      cv.u.z = pkbf(f1.x, f1.y);
      cv.u.w = pkbf(f1.z, f1.w);
      bf[ks] = cv.s;
    }
    bool active = (lane16 < 8);
    #pragma unroll
    for (int mm = 0; mm < 4; ++mm) {
      f32x4 acc = {0.f, 0.f, 0.f, 0.f};
      acc = __builtin_amdgcn_mfma_f32_16x16x32_bf16(af[mm][0], bf[0], acc, 0, 0, 0);
      acc = __builtin_amdgcn_mfma_f32_16x16x32_bf16(af[mm][1], bf[1], acc, 0, 0, 0);
      if (active) {
        int rbase = w * 64 + mm * 16 + g * 4;
        int h = rbase >> 5, d0 = rbase & 31;
        float4 gqv = *(const float4*)(gq + rbase);
        float4 bqv = *(const float4*)(bq + rbase);
        float v0 = fmaxf(fmaf(gqv.x, acc[0], bqv.x), 0.f);
        float v1 = fmaxf(fmaf(gqv.y, acc[1], bqv.y), 0.f);
        float v2 = fmaxf(fmaf(gqv.z, acc[2], bqv.z), 0.f);
        float v3 = fmaxf(fmaf(gqv.w, acc[3], bqv.w), 0.f);
        uint2 u2;
        u2.x = pkbf(v0, v1);
        u2.y = pkbf(v2, v3);
        *(uint2*)(s_qb + lane16 * 328 + h * 40 + d0) = u2;
      }
    }
  }

  // ---- ev-phase: thread (p,d); e' -> bf16 LDS, vv -> 10 packed regs ----
  uint vp[10];
  {
    int d = t & 31, p = t >> 5;
    float4 ct = s_ctr[p];
    float4 wr = *(const float4*)(wp + 512 + 256 + d * 4);  // Wkr
    float4 wc = *(const float4*)(wp + 512 + 384 + d * 4);  // Wkc
    float cb = fmaf(wc.x, ct.x, fmaf(wc.y, ct.y, fmaf(wc.z, ct.z, wc.w * ct.w)));
    float ev[KNBR];
    float sum = 0.f;
    #pragma unroll
    for (int k = 0; k < KNBR; ++k) {
      float4 r = s_rel[p * KNBR + k];
      float kkv = fmaf(wr.x, r.x, fmaf(wr.y, r.y, fmaf(wr.z, r.z, fmaf(wr.w, r.w, cb))));
      ev[k] = __expf(kkv);
      sum += ev[k];
    }
    float4 vr_ = *(const float4*)(wp + 512 + 0 + d * 4);    // Wvr
    float4 vc_ = *(const float4*)(wp + 512 + 128 + d * 4);  // Wvc
    float cbv = fmaf(vc_.x, ct.x, fmaf(vc_.y, ct.y, fmaf(vc_.z, ct.z, vc_.w * ct.w)));
    float gvd = gv[d], bvd = bv[d];
    float vv[KNBR];
    #pragma unroll
    for (int k = 0; k < KNBR; ++k) {
      float4 r = s_rel[p * KNBR + k];
      float raw = fmaf(vr_.x, r.x, fmaf(vr_.y, r.y, fmaf(vr_.z, r.z, fmaf(vr_.w, r.w, cbv))));
      vv[k] = fmaf(gvd, raw, bvd);
    }
    float rs = 1.0f / sum;
    #pragma unroll
    for (int k = 0; k < KNBR; ++k)
      s_eb[(p * KNBR + k) * 40 + d] = f2bf(ev[k] * rs);
    #pragma unroll
    for (int k2 = 0; k2 < 10; ++k2) vp[k2] = pkbf(vv[k2 * 2], vv[k2 * 2 + 1]);
  }
  __syncthreads();

  // ---- a-MFMA: a[h,k] = sum_d q[h,d] e'[k,d]; 2 points x 2 k-tiles ----
  #pragma unroll
  for (int pi2 = 0; pi2 < 2; ++pi2) {
    int pi = 2 * w + pi2;
    s16x8 qa = *(const s16x8*)(s_qb + pi * 328 + (lane16 & 7) * 40 + g * 8);
    #pragma unroll
    for (int tile = 0; tile < 2; ++tile) {
      int k = tile * 16 + lane16;
      int kc = (k < KNBR) ? k : (KNBR - 1);
      s16x8 eb = *(const s16x8*)(s_eb + (pi * KNBR + kc) * 40 + g * 8);
      f32x4 acc = {0.f, 0.f, 0.f, 0.f};
      acc = __builtin_amdgcn_mfma_f32_16x16x32_bf16(qa, eb, acc, 0, 0, 0);
      if (g < 2) {
        if (k < KNBR) {
          #pragma unroll
          for (int r = 0; r < 4; ++r)
            s_ab[pi][g * 4 + r][k] = f2bf(acc[r]);
        } else {
          #pragma unroll
          for (int r = 0; r < 4; ++r) s_ab[pi][g * 4 + r][k] = 0;  // k 20..31
        }
      }
    }
  }
  __syncthreads();

  // ---- out-MFMA: B-frag vv gathered from lane regs via ds_bpermute ----
  // source lane for col v of point pi: (pi&1)*32 + v; holds vp[k/2] pairs.
  #pragma unroll
  for (int pi2 = 0; pi2 < 2; ++pi2) {
    int pi = 2 * w + pi2;
    s16x8 aa = *(const s16x8*)(&s_ab[pi][lane16 & 7][g * 8]);
    #pragma unroll
    for (int vt = 0; vt < 2; ++vt) {
      int srcl4 = ((pi2 * 32 + vt * 16 + lane16) << 2);
      uint bu[4];
      #pragma unroll
      for (int i = 0; i < 4; ++i) {
        uint t0 = (uint)__builtin_amdgcn_ds_bpermute(srcl4, (int)vp[i]);
        uint t1 = (uint)__builtin_amdgcn_ds_bpermute(srcl4, (int)vp[4 + i]);
        uint t2 = (i < 2)
                      ? (uint)__builtin_amdgcn_ds_bpermute(srcl4, (int)vp[8 + i])
                      : 0u;
        bu[i] = (g == 0) ? t0 : (g == 1) ? t1 : (g == 2) ? t2 : 0u;
      }
      union { uint4 u; s16x8 s; } bb;
      bb.u.x = bu[0]; bb.u.y = bu[1]; bb.u.z = bu[2]; bb.u.w = bu[3];
      f32x4 acc = {0.f, 0.f, 0.f, 0.f};
      acc = __builtin_amdgcn_mfma_f32_16x16x32_bf16(aa, bb.s, acc, 0, 0, 0);
      if (g < 2) {
        int v = vt * 16 + lane16;
        #pragma unroll
        for (int r = 0; r < 4; ++r) {
          int h = g * 4 + r;
          s_out[(h * 32 + v) * 9 + pi] = acc[r];
        }
      }
    }
  }
  __syncthreads();

  for (int idx = t; idx < 2048; idx += 256) {
    int hv = idx >> 3, pp = idx & 7;
    o1[b * 262144 + hv * 1024 + n0 + pp] = s_out[hv * 9 + pp];
  }
}

extern "C" void kernel_launch(void* const* d_in, const int* in_sizes, int n_in,
                              void* d_out, int out_size, void* d_ws, size_t ws_size,
                              hipStream_t stream) {
  const float* x = (const float*)d_in[0];
  const float* Wh = (const float*)d_in[1];
  const float* W1 = (const float*)d_in[2];
  const float* g1 = (const float*)d_in[3];
  const float* b1 = (const float*)d_in[4];
  const float* W2 = (const float*)d_in[5];
  const float* g2 = (const float*)d_in[6];
  const float* b2 = (const float*)d_in[7];
  const float* Wv = (const float*)d_in[8];
  const float* gv = (const float*)d_in[9];
  const float* bv = (const float*)d_in[10];
  const float* Wk = (const float*)d_in[11];
  const float* Wq = (const float*)d_in[12];
  const float* gq = (const float*)d_in[13];
  const float* bq = (const float*)d_in[14];
  float* out = (float*)d_out;

  ushort* knn = (ushort*)d_ws;
  float* fq = (float*)((char*)d_ws + 2621440);
  float* wp = (float*)((char*)d_ws + 19398656);
  ushort* w2b = (ushort*)((char*)d_ws + 19402752);
  ushort* wqb = (ushort*)((char*)d_ws + 19410944);
  ushort* w1b = (ushort*)((char*)d_ws + 19443712);

  hipLaunchKernelGGL(k_prep, dim3(1), dim3(256), 0, stream, Wh, W1, g1, b1, Wv, Wk,
                     W2, Wq, wp, w2b, wqb, w1b);
  hipLaunchKernelGGL(k_knn, dim3(2048), dim3(256), 0, stream, (const float4*)x, knn,
                     (float4*)out);
  hipLaunchKernelGGL(k_fq, dim3(4096), dim3(256), 0, stream, (const float4*)x, knn,
                     w1b, w2b, g2, b2, fq);
  hipLaunchKernelGGL(k_attn, dim3(8192), dim3(256), 0, stream, (const float4*)x, knn,
                     fq, wp, wqb, gq, bq, gv, bv, out + 262144);
}

// Round 11
// 169.213 us; speedup vs baseline: 26.2644x; 1.1961x over previous
//
#include <hip/hip_runtime.h>
#include <math.h>

#define NPTS 1024
#define KNBR 20
#define CH 64

// ws layout (bytes): knn ushort [65536][20] @0; wp float[1024] @19398656;
// w2b @19402752; wqb @19410944; w1b @19443712 (fq region now unused)

typedef __attribute__((ext_vector_type(8))) short s16x8;
typedef __attribute__((ext_vector_type(4))) float f32x4;

static __device__ __forceinline__ ushort f2bf(float f) {
  uint u = __float_as_uint(f);
  uint r = (u + 0x7FFFu + ((u >> 16) & 1u)) >> 16;
  return (ushort)r;
}

static __device__ __forceinline__ uint pkbf(float a, float b) {
  uint ua = __float_as_uint(a) + 0x8000u;
  uint ub = __float_as_uint(b) + 0x8000u;
  return __builtin_amdgcn_perm(ub, ua, 0x07060302);
}

static __device__ __forceinline__ int mbcnt64(unsigned long long m) {
  return __builtin_amdgcn_mbcnt_hi((uint)(m >> 32),
                                   __builtin_amdgcn_mbcnt_lo((uint)m, 0));
}

__global__ __launch_bounds__(256) void k_prep(
    const float* __restrict__ Wh, const float* __restrict__ W1,
    const float* __restrict__ g1, const float* __restrict__ b1,
    const float* __restrict__ Wv, const float* __restrict__ Wk,
    const float* __restrict__ W2, const float* __restrict__ Wq,
    float* __restrict__ wp, ushort* __restrict__ w2b,
    ushort* __restrict__ wqb, ushort* __restrict__ w1b) {
  int t = threadIdx.x;
  {
    int o = t >> 2, c = t & 3;
    float acc = W1[o * 40 + c];
    #pragma unroll
    for (int v = 0; v < 32; ++v) acc = fmaf(W1[o * 40 + 8 + v], Wh[v * 4 + c], acc);
    float g = g1[o];
    wp[t] = g * acc;
    wp[256 + t] = g * W1[o * 40 + 4 + c];
  }
  if (t < 128) {
    int d = t >> 2, c = t & 3;
    float av = Wv[d * 40 + c];
    float ak = Wk[d * 40 + c];
    #pragma unroll
    for (int u = 0; u < 32; ++u) {
      av = fmaf(Wv[d * 40 + 8 + u], Wh[u * 4 + c], av);
      ak = fmaf(Wk[d * 40 + 8 + u], Wh[u * 4 + c], ak);
    }
    wp[512 + t] = av;
    wp[640 + t] = Wv[d * 40 + 4 + c];
    wp[768 + t] = ak;
    wp[896 + t] = Wk[d * 40 + 4 + c];
  }
  #pragma unroll
  for (int i = 0; i < 16; ++i) w2b[t * 16 + i] = f2bf(W2[t * 16 + i]);
  for (int i = 0; i < 64; ++i) wqb[t * 64 + i] = f2bf(Wq[t * 64 + i]);
  __syncthreads();
  for (int idx = t; idx < 2048; idx += 256) {
    int ch = idx >> 5, kk = idx & 31;
    float v = 0.f;
    if (kk < 4) v = wp[ch * 4 + kk];
    else if (kk < 8) v = wp[256 + ch * 4 + (kk - 4)];
    else if (kk == 8) v = b1[ch];
    w1b[idx] = f2bf(v);
  }
}

// ---------------- KNN: ballot radix-select; grid 2048 (unchanged) -----------
__global__ __launch_bounds__(256) void k_knn(const float4* __restrict__ xv,
                                             ushort* __restrict__ knn,
                                             float4* __restrict__ outx) {
  __shared__ float4 sx[NPTS];
  __shared__ float ssq[NPTS];
  __shared__ uint s_sk[4][64];
  __shared__ ushort s_sj[4][64];

  int t = threadIdx.x;
  int b = blockIdx.x >> 5, grp = blockIdx.x & 31;
  for (int j = t; j < NPTS; j += 256) {
    float4 p = xv[b * NPTS + j];
    sx[j] = p;
    ssq[j] = p.x * p.x + p.y * p.y + p.z * p.z + p.w * p.w;
    if (grp == 0) outx[b * NPTS + j] = p;  // folded k_copy (out0 = x)
  }
  __syncthreads();

  int w = t >> 6, l = t & 63;

  #pragma unroll 1
  for (int i = 0; i < 8; ++i) {
    int cloc = grp * 32 + w * 8 + i;
    int gid20 = (b * NPTS + cloc) * KNBR;
    float4 c = sx[cloc];
    uint u[16];
    uint mn = 0xFFFFFFFFu;
    #pragma unroll
    for (int s = 0; s < 16; ++s) {
      int j = s * 64 + l;
      float4 q = sx[j];
      float dot = c.x * q.x;
      dot = fmaf(c.y, q.y, dot);
      dot = fmaf(c.z, q.z, dot);
      dot = fmaf(c.w, q.w, dot);
      float key = fmaf(-2.f, dot, ssq[j]);
      uint uu = __float_as_uint(key);
      uu = ((int)uu < 0) ? ~uu : (uu | 0x80000000u);
      u[s] = uu;
      mn = min(mn, uu);
    }

    uint T0 = 0;
    #pragma unroll
    for (int bit = 31; bit >= 0; --bit) {
      uint cand = T0 | (1u << bit);
      if (__popcll(__ballot(mn < cand)) < 20) T0 = cand;
    }

    int scnt = 0;
    #pragma unroll
    for (int s = 0; s < 16; ++s) scnt += (int)__popcll(__ballot(u[s] <= T0));

    if (scnt <= 64) {
      int base = 0;
      #pragma unroll
      for (int s = 0; s < 16; ++s) {
        unsigned long long mask = __ballot(u[s] <= T0);
        if (u[s] <= T0) {
          int off = base + mbcnt64(mask);
          s_sk[w][off] = u[s];
          s_sj[w][off] = (ushort)(s * 64 + l);
        }
        base += (int)__popcll(mask);
      }
      asm volatile("s_waitcnt lgkmcnt(0)" ::: "memory");
      __builtin_amdgcn_sched_barrier(0);
      uint uk = (l < scnt) ? s_sk[w][l] : 0xFFFFFFFFu;
      uint uj = (l < scnt) ? (uint)s_sj[w][l] : 0xFFFFu;

      uint u20 = 0;
      #pragma unroll
      for (int bit = 31; bit >= 0; --bit) {
        uint cand = u20 | (1u << bit);
        if (__popcll(__ballot(uk < cand)) < 20) u20 = cand;
      }
      int m = (int)__popcll(__ballot(uk < u20));
      int r = 20 - m;
      uint jr = 0;
      #pragma unroll
      for (int bit = 10; bit >= 0; --bit) {
        uint cand = jr | (1u << bit);
        if (__popcll(__ballot((uk == u20) && (uj < cand))) < r) jr = cand;
      }
      bool sel = (uk < u20) || ((uk == u20) && (uj <= jr));
      unsigned long long smask = __ballot(sel);
      int off = mbcnt64(smask);
      if (sel) knn[gid20 + off] = (ushort)uj;
    } else {
      uint u20 = 0;
      #pragma unroll 1
      for (int bit = 31; bit >= 0; --bit) {
        uint cand = u20 | (1u << bit);
        int cnt = 0;
        #pragma unroll
        for (int s = 0; s < 16; ++s)
          cnt += (int)__popcll(__ballot(u[s] < cand));
        if (cnt < 20) u20 = cand;
      }
      int base = 0;
      #pragma unroll
      for (int s = 0; s < 16; ++s) {
        unsigned long long mask = __ballot(u[s] < u20);
        if (u[s] < u20) knn[gid20 + base + mbcnt64(mask)] = (ushort)(s * 64 + l);
        base += (int)__popcll(mask);
      }
      int r = 20 - base;
      #pragma unroll
      for (int s = 0; s < 16; ++s) {
        unsigned long long mask = __ballot(u[s] == u20);
        int pos = mbcnt64(mask);
        int cntm = (int)__popcll(mask);
        int take = (r < cntm) ? r : cntm;
        if ((u[s] == u20) && (pos < take))
          knn[gid20 + base + pos] = (ushort)(s * 64 + l);
        base += take;
        r -= take;
      }
    }
  }
}

// ---------------- fused fq+attn: block = 16 points, phase-aliased LDS -------
// smem map (bytes):
//  [0,40960)      s_h1 (phases 1-2) | phase>=3: s_qb [0,10496) ushort,
//                 s_eb [10496,36096) ushort | phase>=5: s_out f32 @10496
//  [40960,46080)  s_rel float4[16][20] (dead after ev) \
//  [46080,48384)  s_fqb ushort[16][72] (dead after qMFMA) } s_ab @[40960,51200)
//  [48384,48640)  s_ctr float4[16] (dead after ev)      /
__global__ __launch_bounds__(256) void k_fused(
    const float4* __restrict__ xv, const ushort* __restrict__ knn,
    const float* __restrict__ wp, const ushort* __restrict__ w1b,
    const ushort* __restrict__ w2b, const ushort* __restrict__ wqb,
    const float* __restrict__ g2, const float* __restrict__ b2,
    const float* __restrict__ gq, const float* __restrict__ bq,
    const float* __restrict__ gv, const float* __restrict__ bv,
    float* __restrict__ o1) {
  __shared__ __align__(16) char smem[51200];
  char* s_h1 = smem;
  ushort* s_qb = (ushort*)smem;
  ushort* s_eb = (ushort*)(smem + 10496);
  float* s_out = (float*)(smem + 10496);
  float4* s_rel = (float4*)(smem + 40960);
  char* s_fqb = smem + 46080;
  float4* s_ctr = (float4*)(smem + 48384);
  ushort* s_ab = (ushort*)(smem + 40960);

  int t = threadIdx.x;
  int gid0 = blockIdx.x * 16;
  int bbase = (gid0 >> 10) << 10;
  int b = gid0 >> 10;
  int n0 = gid0 & 1023;
  int w = t >> 6, l = t & 63;
  int g = l >> 4, lane16 = l & 15;

  // ---- stage: ctr + rel ----
  if (t < 16) s_ctr[t] = xv[gid0 + t];
  #pragma unroll
  for (int it2 = 0; it2 < 2; ++it2) {
    int idx = t + it2 * 256;
    if (idx < 320) {
      int p = (int)(((uint)idx * 3277u) >> 16);
      int k = idx - p * 20;
      int nb = (int)knn[(size_t)(gid0 + p) * KNBR + k];
      float4 nx = xv[bbase + nb];
      float4 ct = xv[gid0 + p];
      s_rel[p * 20 + k] =
          make_float4(nx.x - ct.x, nx.y - ct.y, nx.z - ct.z, nx.w - ct.w);
    }
  }
  __syncthreads();

  // ---- h1-MFMA: col cc = kk*16 + p; wave w covers cols w*80..w*80+79 ----
  {
    s16x8 ah[4];
    #pragma unroll
    for (int m = 0; m < 4; ++m)
      ah[m] = *(const s16x8*)(w1b + (m * 16 + lane16) * 32 + g * 8);
    s16x8 bz = {0, 0, 0, 0, 0, 0, 0, 0};
    s16x8 bone = bz;
    bone[0] = (short)0x3F80;  // bf16(1.0) at K-slot 8
    #pragma unroll
    for (int q = 0; q < 5; ++q) {
      int col = w * 80 + q * 16 + lane16;  // p = lane16, kk = 5w + q
      s16x8 bf;
      if (g == 0) {
        float4 r = s_rel[lane16 * 20 + 5 * w + q];
        float4 ct = s_ctr[lane16];
        union { uint4 u; s16x8 s; } cv;
        cv.u.x = pkbf(r.x, r.y);
        cv.u.y = pkbf(r.z, r.w);
        cv.u.z = pkbf(ct.x, ct.y);
        cv.u.w = pkbf(ct.z, ct.w);
        bf = cv.s;
      } else {
        bf = (g == 1) ? bone : bz;
      }
      int swz = (col & 7) << 4;
      #pragma unroll
      for (int m = 0; m < 4; ++m) {
        f32x4 acc = {0.f, 0.f, 0.f, 0.f};
        acc = __builtin_amdgcn_mfma_f32_16x16x32_bf16(ah[m], bf, acc, 0, 0, 0);
        uint2 hv;
        hv.x = pkbf(fmaxf(acc[0], 0.f), fmaxf(acc[1], 0.f));
        hv.y = pkbf(fmaxf(acc[2], 0.f), fmaxf(acc[3], 0.f));
        int byteoff = col * 128 + (m * 16 + g * 4) * 2;
        *(uint2*)(s_h1 + (byteoff ^ swz)) = hv;
      }
    }
  }
  __syncthreads();

  // ---- W2-MFMA + maxpool -> s_fqb bf16 [16 pts][72 stride] ----
  {
    int row0 = w * 16 + g * 4;
    s16x8 af0 = *(const s16x8*)(w2b + (w * 16 + lane16) * 64 + g * 8);
    s16x8 af1 = *(const s16x8*)(w2b + (w * 16 + lane16) * 64 + 32 + g * 8);
    float4 g2v = *(const float4*)(g2 + row0);
    float4 b2v = *(const float4*)(b2 + row0);
    float mx0 = 0.f, mx1 = 0.f, mx2 = 0.f, mx3 = 0.f;
    #pragma unroll 4
    for (int kt = 0; kt < 20; ++kt) {
      int col = kt * 16 + lane16;
      int rowbyte = col * 128;
      int swz = (col & 7) << 4;
      s16x8 bf0 = *(const s16x8*)(s_h1 + ((rowbyte + g * 16) ^ swz));
      s16x8 bf1 = *(const s16x8*)(s_h1 + ((rowbyte + 64 + g * 16) ^ swz));
      f32x4 acc = {0.f, 0.f, 0.f, 0.f};
      acc = __builtin_amdgcn_mfma_f32_16x16x32_bf16(af0, bf0, acc, 0, 0, 0);
      acc = __builtin_amdgcn_mfma_f32_16x16x32_bf16(af1, bf1, acc, 0, 0, 0);
      mx0 = fmaxf(mx0, fmaxf(fmaf(g2v.x, acc[0], b2v.x), 0.f));
      mx1 = fmaxf(mx1, fmaxf(fmaf(g2v.y, acc[1], b2v.y), 0.f));
      mx2 = fmaxf(mx2, fmaxf(fmaf(g2v.z, acc[2], b2v.z), 0.f));
      mx3 = fmaxf(mx3, fmaxf(fmaf(g2v.w, acc[3], b2v.w), 0.f));
    }
    uint2 u2;
    u2.x = pkbf(mx0, mx1);
    u2.y = pkbf(mx2, mx3);
    *(uint2*)(s_fqb + lane16 * 144 + row0 * 2) = u2;
  }
  __syncthreads();

  // ---- q-MFMA (16 cols, full tile) -> s_qb; then ev -> s_eb + vv regs ----
  {
    s16x8 af[4][2];
    #pragma unroll
    for (int mm = 0; mm < 4; ++mm) {
      int row = w * 64 + mm * 16 + lane16;
      af[mm][0] = *(const s16x8*)(wqb + row * 64 + g * 8);
      af[mm][1] = *(const s16x8*)(wqb + row * 64 + 32 + g * 8);
    }
    s16x8 bf0 = *(const s16x8*)(s_fqb + lane16 * 144 + 0 * 64 + g * 16);
    s16x8 bf1 = *(const s16x8*)(s_fqb + lane16 * 144 + 1 * 64 + g * 16);
    #pragma unroll
    for (int mm = 0; mm < 4; ++mm) {
      f32x4 acc = {0.f, 0.f, 0.f, 0.f};
      acc = __builtin_amdgcn_mfma_f32_16x16x32_bf16(af[mm][0], bf0, acc, 0, 0, 0);
      acc = __builtin_amdgcn_mfma_f32_16x16x32_bf16(af[mm][1], bf1, acc, 0, 0, 0);
      int rbase = w * 64 + mm * 16 + g * 4;
      int h = rbase >> 5, d0 = rbase & 31;
      float4 gqv = *(const float4*)(gq + rbase);
      float4 bqv = *(const float4*)(bq + rbase);
      float v0 = fmaxf(fmaf(gqv.x, acc[0], bqv.x), 0.f);
      float v1 = fmaxf(fmaf(gqv.y, acc[1], bqv.y), 0.f);
      float v2 = fmaxf(fmaf(gqv.z, acc[2], bqv.z), 0.f);
      float v3 = fmaxf(fmaf(gqv.w, acc[3], bqv.w), 0.f);
      uint2 u2;
      u2.x = pkbf(v0, v1);
      u2.y = pkbf(v2, v3);
      *(uint2*)(s_qb + lane16 * 328 + h * 40 + d0) = u2;
    }
  }

  uint vp[2][10];
  {
    int d = t & 31, phalf = t >> 5;
    float4 wr = *(const float4*)(wp + 512 + 256 + d * 4);  // Wkr
    float4 wc = *(const float4*)(wp + 512 + 384 + d * 4);  // Wkc
    float4 vr_ = *(const float4*)(wp + 512 + 0 + d * 4);   // Wvr
    float4 vc_ = *(const float4*)(wp + 512 + 128 + d * 4); // Wvc
    float gvd = gv[d], bvd = bv[d];
    #pragma unroll
    for (int i = 0; i < 2; ++i) {
      int p = phalf + 8 * i;
      float4 ct = s_ctr[p];
      float cb = fmaf(wc.x, ct.x, fmaf(wc.y, ct.y, fmaf(wc.z, ct.z, wc.w * ct.w)));
      float ev[KNBR];
      float sum = 0.f;
      #pragma unroll
      for (int k = 0; k < KNBR; ++k) {
        float4 r = s_rel[p * 20 + k];
        float kkv =
            fmaf(wr.x, r.x, fmaf(wr.y, r.y, fmaf(wr.z, r.z, fmaf(wr.w, r.w, cb))));
        ev[k] = __expf(kkv);
        sum += ev[k];
      }
      float cbv = fmaf(vc_.x, ct.x, fmaf(vc_.y, ct.y, fmaf(vc_.z, ct.z, vc_.w * ct.w)));
      float vv[KNBR];
      #pragma unroll
      for (int k = 0; k < KNBR; ++k) {
        float4 r = s_rel[p * 20 + k];
        float raw =
            fmaf(vr_.x, r.x, fmaf(vr_.y, r.y, fmaf(vr_.z, r.z, fmaf(vr_.w, r.w, cbv))));
        vv[k] = fmaf(gvd, raw, bvd);
      }
      float rs = 1.0f / sum;
      #pragma unroll
      for (int k = 0; k < KNBR; ++k)
        s_eb[(p * 20 + k) * 40 + d] = f2bf(ev[k] * rs);
      #pragma unroll
      for (int k2 = 0; k2 < 10; ++k2) vp[i][k2] = pkbf(vv[k2 * 2], vv[k2 * 2 + 1]);
    }
  }
  __syncthreads();

  // ---- a-MFMA: wave w owns points {2w, 2w+1, 2w+8, 2w+9} ----
  #pragma unroll
  for (int pi2 = 0; pi2 < 4; ++pi2) {
    int plo = pi2 & 1, ii = pi2 >> 1;
    int pi = 2 * w + plo + 8 * ii;
    s16x8 qa = *(const s16x8*)(s_qb + pi * 328 + (lane16 & 7) * 40 + g * 8);
    #pragma unroll
    for (int tile = 0; tile < 2; ++tile) {
      int k = tile * 16 + lane16;
      int kc = (k < KNBR) ? k : (KNBR - 1);
      s16x8 eb = *(const s16x8*)(s_eb + (pi * 20 + kc) * 40 + g * 8);
      f32x4 acc = {0.f, 0.f, 0.f, 0.f};
      acc = __builtin_amdgcn_mfma_f32_16x16x32_bf16(qa, eb, acc, 0, 0, 0);
      if (g < 2) {
        if (k < KNBR) {
          #pragma unroll
          for (int r = 0; r < 4; ++r)
            s_ab[pi * 320 + (g * 4 + r) * 40 + k] = f2bf(acc[r]);
        } else {
          #pragma unroll
          for (int r = 0; r < 4; ++r) s_ab[pi * 320 + (g * 4 + r) * 40 + k] = 0;
        }
      }
    }
  }
  __syncthreads();

  // ---- out-MFMA: B-frag vv via intra-wave ds_bpermute ----
  #pragma unroll
  for (int pi2 = 0; pi2 < 4; ++pi2) {
    int plo = pi2 & 1, ii = pi2 >> 1;
    int pi = 2 * w + plo + 8 * ii;
    s16x8 aa = *(const s16x8*)(s_ab + pi * 320 + (lane16 & 7) * 40 + g * 8);
    #pragma unroll
    for (int vt = 0; vt < 2; ++vt) {
      int srcl4 = ((plo * 32 + vt * 16 + lane16) << 2);
      uint bu[4];
      #pragma unroll
      for (int i = 0; i < 4; ++i) {
        uint t0 = (uint)__builtin_amdgcn_ds_bpermute(srcl4, (int)vp[ii][i]);
        uint t1 = (uint)__builtin_amdgcn_ds_bpermute(srcl4, (int)vp[ii][4 + i]);
        uint t2 = (i < 2)
                      ? (uint)__builtin_amdgcn_ds_bpermute(srcl4, (int)vp[ii][8 + i])
                      : 0u;
        bu[i] = (g == 0) ? t0 : (g == 1) ? t1 : (g == 2) ? t2 : 0u;
      }
      union { uint4 u; s16x8 s; } bb;
      bb.u.x = bu[0]; bb.u.y = bu[1]; bb.u.z = bu[2]; bb.u.w = bu[3];
      f32x4 acc = {0.f, 0.f, 0.f, 0.f};
      acc = __builtin_amdgcn_mfma_f32_16x16x32_bf16(aa, bb.s, acc, 0, 0, 0);
      if (g < 2) {
        int v = vt * 16 + lane16;
        #pragma unroll
        for (int r = 0; r < 4; ++r) {
          int h = g * 4 + r;
          s_out[(h * 32 + v) * 17 + pi] = acc[r];
        }
      }
    }
  }
  __syncthreads();

  // ---- epilogue: 16 consecutive floats per 16-lane group (64B segments) ----
  #pragma unroll
  for (int e = 0; e < 16; ++e) {
    int idx = t + e * 256;
    int hv = idx >> 4, pp = idx & 15;
    o1[b * 262144 + hv * 1024 + n0 + pp] = s_out[hv * 17 + pp];
  }
}

extern "C" void kernel_launch(void* const* d_in, const int* in_sizes, int n_in,
                              void* d_out, int out_size, void* d_ws, size_t ws_size,
                              hipStream_t stream) {
  const float* x = (const float*)d_in[0];
  const float* Wh = (const float*)d_in[1];
  const float* W1 = (const float*)d_in[2];
  const float* g1 = (const float*)d_in[3];
  const float* b1 = (const float*)d_in[4];
  const float* W2 = (const float*)d_in[5];
  const float* g2 = (const float*)d_in[6];
  const float* b2 = (const float*)d_in[7];
  const float* Wv = (const float*)d_in[8];
  const float* gv = (const float*)d_in[9];
  const float* bv = (const float*)d_in[10];
  const float* Wk = (const float*)d_in[11];
  const float* Wq = (const float*)d_in[12];
  const float* gq = (const float*)d_in[13];
  const float* bq = (const float*)d_in[14];
  float* out = (float*)d_out;

  ushort* knn = (ushort*)d_ws;
  float* wp = (float*)((char*)d_ws + 19398656);
  ushort* w2b = (ushort*)((char*)d_ws + 19402752);
  ushort* wqb = (ushort*)((char*)d_ws + 19410944);
  ushort* w1b = (ushort*)((char*)d_ws + 19443712);

  hipLaunchKernelGGL(k_prep, dim3(1), dim3(256), 0, stream, Wh, W1, g1, b1, Wv, Wk,
                     W2, Wq, wp, w2b, wqb, w1b);
  hipLaunchKernelGGL(k_knn, dim3(2048), dim3(256), 0, stream, (const float4*)x, knn,
                     (float4*)out);
  hipLaunchKernelGGL(k_fused, dim3(4096), dim3(256), 0, stream, (const float4*)x,
                     knn, wp, w1b, w2b, wqb, g2, b2, gq, bq, gv, bv, out + 262144);
}